// Round 1
// baseline (34139.679 us; speedup 1.0000x reference)
//
#include <hip/hip_runtime.h>
#include <hip/hip_bf16.h>
#include <math.h>

// TFT: B=32, T=512, V=16, D=256, H=4, L=2.  BT = 16384.
// Round 0: correctness-first fp32 implementation.
//  - generic LDS-tiled fp32 GEMM (64x64 tile, BK=16, 4x4/thread) with:
//      AMODE 1: A generated on the fly as embedded = x*emb_w+emb_b (never materialized)
//      BMODE 1: B given transposed ([N,K] row-major), for W^T GEMMs
//  - attention computed only for query t=T-1 (everything downstream is position-wise)
//  - LSTM recurrence: 1 block/batch, 1024 threads (1/gate), state in LDS, whh from L2

#define BT 16384
#define TT 512
#define BB 32
#define VV 16
#define DD 256

__device__ __forceinline__ float sigmoidf_(float x) { return 1.f / (1.f + expf(-x)); }
__device__ __forceinline__ float eluf_(float x)     { return x > 0.f ? x : expm1f(x); }

// block-wide sum over 256 threads; leaves `red` reusable afterwards
__device__ __forceinline__ float block_sum256(float v, float* red) {
  int j = threadIdx.x;
  red[j] = v; __syncthreads();
  #pragma unroll
  for (int st = 128; st > 0; st >>= 1) {
    if (j < st) red[j] += red[j + st];
    __syncthreads();
  }
  float r = red[0];
  __syncthreads();
  return r;
}

// ---------------- generic GEMM ----------------
// C[M,N] = act( A[M,K] @ B[K,N] + bias )
// AMODE 0: A row-major with lda.  AMODE 1: A=x-like ptr, a = A[m*lda + (k>>8)]*embw[k]+embb[k]
// BMODE 0: B [K,N] row-major ldb.  BMODE 1: B [N,K] row-major ldb (i.e. computes A@B^T)
// ACT 0: none, 1: ELU
template<int AMODE, int BMODE, int ACT>
__global__ __launch_bounds__(256) void gemm_k(
    const float* __restrict__ A, int lda,
    const float* __restrict__ B, int ldb,
    const float* __restrict__ bias,
    float* __restrict__ C, int ldc,
    int M, int N, int K,
    const float* __restrict__ embw, const float* __restrict__ embb) {
  __shared__ float As[16][68];
  __shared__ float Bs[16][68];
  int tid = threadIdx.x;
  int tx = tid & 15, ty = tid >> 4;
  int m0 = blockIdx.y * 64, n0 = blockIdx.x * 64;
  float acc[4][4];
  #pragma unroll
  for (int i = 0; i < 4; i++)
    #pragma unroll
    for (int j = 0; j < 4; j++) acc[i][j] = 0.f;

  for (int k0 = 0; k0 < K; k0 += 16) {
    #pragma unroll
    for (int i = 0; i < 4; i++) {
      int idx = tid + i * 256;
      int r = idx >> 4, cc = idx & 15;
      int gm = m0 + r, gk = k0 + cc;
      float a = 0.f;
      if (gm < M && gk < K) {
        if (AMODE == 0) a = A[(size_t)gm * lda + gk];
        else            a = A[(size_t)gm * lda + (gk >> 8)] * embw[gk] + embb[gk];
      }
      As[cc][r] = a;
    }
    #pragma unroll
    for (int i = 0; i < 4; i++) {
      int idx = tid + i * 256;
      if (BMODE == 0) {
        int r = idx >> 6, cc = idx & 63;
        int gk = k0 + r, gn = n0 + cc;
        Bs[r][cc] = (gk < K && gn < N) ? B[(size_t)gk * ldb + gn] : 0.f;
      } else {
        int kk = idx & 15, nn = idx >> 4;
        int gk = k0 + kk, gn = n0 + nn;
        Bs[kk][nn] = (gk < K && gn < N) ? B[(size_t)gn * ldb + gk] : 0.f;
      }
    }
    __syncthreads();
    #pragma unroll
    for (int kk = 0; kk < 16; kk++) {
      float4 av = *(const float4*)&As[kk][ty * 4];
      float4 bv = *(const float4*)&Bs[kk][tx * 4];
      float am[4] = {av.x, av.y, av.z, av.w};
      float bm[4] = {bv.x, bv.y, bv.z, bv.w};
      #pragma unroll
      for (int i = 0; i < 4; i++)
        #pragma unroll
        for (int j = 0; j < 4; j++) acc[i][j] += am[i] * bm[j];
    }
    __syncthreads();
  }
  #pragma unroll
  for (int i = 0; i < 4; i++) {
    int gm = m0 + ty * 4 + i;
    if (gm >= M) continue;
    #pragma unroll
    for (int j = 0; j < 4; j++) {
      int gn = n0 + tx * 4 + j;
      if (gn >= N) continue;
      float v = acc[i][j] + (bias ? bias[gn] : 0.f);
      if (ACT == 1) v = eluf_(v);
      C[(size_t)gm * ldc + gn] = v;
    }
  }
}

// ---------------- selection GRN finish: GLU + skip + LN(16) + softmax -> weights ----------------
__global__ void sel_finish_k(const float* __restrict__ selG, const float* __restrict__ selSkip,
                             const float* __restrict__ lng, const float* __restrict__ lnb,
                             float* __restrict__ wout, int M) {
  int m = blockIdx.x * 256 + threadIdx.x;
  if (m >= M) return;
  float s[16];
  float mean = 0.f;
  #pragma unroll
  for (int i = 0; i < 16; i++) {
    float h1 = selG[m * 32 + i], h2 = selG[m * 32 + 16 + i];
    float val = h1 * sigmoidf_(h2) + selSkip[m * 16 + i];
    s[i] = val; mean += val;
  }
  mean *= (1.f / 16.f);
  float var = 0.f;
  #pragma unroll
  for (int i = 0; i < 16; i++) { float d = s[i] - mean; var += d * d; }
  var *= (1.f / 16.f);
  float inv = rsqrtf(var + 1e-5f);
  float mx = -1e30f;
  #pragma unroll
  for (int i = 0; i < 16; i++) { s[i] = (s[i] - mean) * inv * lng[i] + lnb[i]; mx = fmaxf(mx, s[i]); }
  float sum = 0.f;
  #pragma unroll
  for (int i = 0; i < 16; i++) { s[i] = expf(s[i] - mx); sum += s[i]; }
  float isum = 1.f / sum;
  #pragma unroll
  for (int i = 0; i < 16; i++) wout[m * 16 + i] = s[i] * isum;
}

// ---------------- var-GRN epilogue: GLU + embedded-skip + LN(256) + weighted accumulate ----------------
__global__ __launch_bounds__(256) void var_epi_k(
    const float* __restrict__ G, const float* __restrict__ x, int v,
    const float* __restrict__ embw, const float* __restrict__ embb,
    const float* __restrict__ lng, const float* __restrict__ lnb,
    const float* __restrict__ wts, float* __restrict__ vsn, int first) {
  int m = blockIdx.x, j = threadIdx.x;
  __shared__ float red[256];
  float g1 = G[(size_t)m * 512 + j], g2 = G[(size_t)m * 512 + 256 + j];
  float e  = x[m * VV + v] * embw[j] + embb[j];
  float s  = g1 * sigmoidf_(g2) + e;
  float mean = block_sum256(s, red) * (1.f / 256.f);
  float d = s - mean;
  float var = block_sum256(d * d, red) * (1.f / 256.f);
  float o = d * rsqrtf(var + 1e-5f) * lng[j] + lnb[j];
  float w = wts[m * VV + v];
  size_t oi = (size_t)m * 256 + j;
  if (first) vsn[oi] = w * o; else vsn[oi] += w * o;
}

// ---------------- generic GRN epilogue: GLU + skip + LN(256) ----------------
__global__ __launch_bounds__(256) void grn_epi_k(
    const float* __restrict__ G, const float* __restrict__ skip,
    const float* __restrict__ lng, const float* __restrict__ lnb,
    float* __restrict__ out) {
  int m = blockIdx.x, j = threadIdx.x;
  __shared__ float red[256];
  float g1 = G[(size_t)m * 512 + j], g2 = G[(size_t)m * 512 + 256 + j];
  float s = g1 * sigmoidf_(g2) + skip[(size_t)m * 256 + j];
  float mean = block_sum256(s, red) * (1.f / 256.f);
  float d = s - mean;
  float var = block_sum256(d * d, red) * (1.f / 256.f);
  out[(size_t)m * 256 + j] = d * rsqrtf(var + 1e-5f) * lng[j] + lnb[j];
}

// ---------------- elementwise ----------------
__global__ void add2_k(const float* __restrict__ a, const float* __restrict__ b,
                       float* __restrict__ c, int n) {
  int i = blockIdx.x * 256 + threadIdx.x;
  if (i < n) c[i] = a[i] + b[i];
}

__global__ void cbias_k(const float* __restrict__ a, const float* __restrict__ b,
                        float* __restrict__ c, int n) {
  int i = blockIdx.x * 256 + threadIdx.x;
  if (i < n) c[i] = a[i] + b[i];
}

// ---------------- LSTM recurrence: 1 block per batch, 1024 threads (1 per gate) ----------------
__global__ __launch_bounds__(1024) void lstm_recur_k(
    const float* __restrict__ xi,   // [B,T,1024] (xW^T + bih + bhh)
    const float* __restrict__ whh,  // [1024,256]
    float* __restrict__ hout,       // [B,T,256]
    int T) {
  int b = blockIdx.x;
  int j = threadIdx.x;
  __shared__ float hp[256];
  __shared__ float gates[1024];
  float c = 0.f;
  if (j < 256) hp[j] = 0.f;
  __syncthreads();
  const float* wr = whh + (size_t)j * 256;
  for (int t = 0; t < T; t++) {
    float acc = xi[((size_t)(b * T + t)) * 1024 + j];
    #pragma unroll 8
    for (int k = 0; k < 256; k += 4) {
      float4 w4 = *(const float4*)(wr + k);
      acc += hp[k] * w4.x + hp[k + 1] * w4.y + hp[k + 2] * w4.z + hp[k + 3] * w4.w;
    }
    gates[j] = acc;
    __syncthreads();
    if (j < 256) {
      float i_ = gates[j], f_ = gates[256 + j], g_ = gates[512 + j], o_ = gates[768 + j];
      c = sigmoidf_(f_) * c + sigmoidf_(i_) * tanhf(g_);
      float h = sigmoidf_(o_) * tanhf(c);
      hp[j] = h;
      hout[((size_t)(b * T + t)) * 256 + j] = h;
    }
    __syncthreads();
  }
}

// ---------------- attention, decode-style (only query t = T-1) ----------------
__global__ __launch_bounds__(256) void attn_decode_k(const float* __restrict__ qkv, // [B,T,768]
                                                     float* __restrict__ o,         // [B,256]
                                                     int T) {
  int bh = blockIdx.x; int b = bh >> 2, h = bh & 3;
  int tid = threadIdx.x;
  __shared__ float q[64];
  __shared__ float p[512];
  __shared__ float red[256];
  if (tid < 64) q[tid] = qkv[((size_t)(b * T + T - 1)) * 768 + h * 64 + tid];
  __syncthreads();
  for (int t = tid; t < 512; t += 256) {
    const float* kv = qkv + ((size_t)(b * T + t)) * 768 + 256 + h * 64;
    float s = 0.f;
    #pragma unroll 16
    for (int d = 0; d < 64; d++) s += q[d] * kv[d];
    p[t] = s * 0.125f;   // 1/sqrt(64)
  }
  __syncthreads();
  red[tid] = fmaxf(p[tid], p[tid + 256]); __syncthreads();
  for (int st = 128; st > 0; st >>= 1) { if (tid < st) red[tid] = fmaxf(red[tid], red[tid + st]); __syncthreads(); }
  float mx = red[0]; __syncthreads();
  float e0 = expf(p[tid] - mx), e1 = expf(p[tid + 256] - mx);
  red[tid] = e0 + e1; __syncthreads();
  for (int st = 128; st > 0; st >>= 1) { if (tid < st) red[tid] += red[tid + st]; __syncthreads(); }
  float inv = 1.f / red[0];
  __syncthreads();
  p[tid] = e0; p[tid + 256] = e1;
  __syncthreads();
  int d = tid & 63, grp = tid >> 6;
  float acc = 0.f;
  for (int t = grp * 128; t < grp * 128 + 128; t++)
    acc += p[t] * qkv[((size_t)(b * T + t)) * 768 + 512 + h * 64 + d];
  red[tid] = acc; __syncthreads();
  if (grp == 0)
    o[(b * 4 + h) * 64 + d] = (red[tid] + red[tid + 64] + red[tid + 128] + red[tid + 192]) * inv;
}

// ---------------- attn out-proj + residual + LN (only t=T-1) ----------------
__global__ __launch_bounds__(256) void attn_proj_ln_k(
    const float* __restrict__ attnO, const float* __restrict__ W, const float* __restrict__ bias,
    const float* __restrict__ lstmF, const float* __restrict__ lng, const float* __restrict__ lnb,
    float* __restrict__ out, int T) {
  int bb = blockIdx.x, j = threadIdx.x;
  __shared__ float a[256];
  __shared__ float red[256];
  a[j] = attnO[bb * 256 + j];
  __syncthreads();
  float acc = bias[j];
  const float* wr = W + (size_t)j * 256;   // o @ W^T
  #pragma unroll 8
  for (int k = 0; k < 256; k += 4) {
    float4 w4 = *(const float4*)(wr + k);
    acc += a[k] * w4.x + a[k + 1] * w4.y + a[k + 2] * w4.z + a[k + 3] * w4.w;
  }
  float s = acc + lstmF[((size_t)(bb * T + T - 1)) * 256 + j];
  float mean = block_sum256(s, red) * (1.f / 256.f);
  float d = s - mean;
  float var = block_sum256(d * d, red) * (1.f / 256.f);
  out[bb * 256 + j] = d * rsqrtf(var + 1e-5f) * lng[j] + lnb[j];
}

// ---------------- final two GRNs (pa then fg), per-row, only t=T-1 ----------------
__global__ __launch_bounds__(256) void final_grns_k(
    const float* __restrict__ ain,
    const float* __restrict__ paw1, const float* __restrict__ pab1,
    const float* __restrict__ paw2, const float* __restrict__ pab2,
    const float* __restrict__ palg, const float* __restrict__ palb,
    const float* __restrict__ fgw1, const float* __restrict__ fgb1,
    const float* __restrict__ fgw2, const float* __restrict__ fgb2,
    const float* __restrict__ fglg, const float* __restrict__ fglb,
    float* __restrict__ out) {
  int bb = blockIdx.x, j = threadIdx.x;
  __shared__ float a[256];
  __shared__ float hbuf[1024];
  __shared__ float red[256];
  a[j] = ain[bb * 256 + j];
  __syncthreads();
  // pa fc1 : [256] @ [256,256]
  float acc = pab1[j];
  for (int k = 0; k < 256; k++) acc += a[k] * paw1[k * 256 + j];
  hbuf[j] = eluf_(acc);
  __syncthreads();
  // pa fc2 : [256] @ [256,512], GLU + skip
  float g1 = pab2[j], g2 = pab2[256 + j];
  for (int k = 0; k < 256; k++) { float hv = hbuf[k]; g1 += hv * paw2[k * 512 + j]; g2 += hv * paw2[k * 512 + 256 + j]; }
  float s = g1 * sigmoidf_(g2) + a[j];
  float mean = block_sum256(s, red) * (1.f / 256.f);
  float d = s - mean;
  float var = block_sum256(d * d, red) * (1.f / 256.f);
  float af = d * rsqrtf(var + 1e-5f) * palg[j] + palb[j];
  __syncthreads();
  a[j] = af;
  __syncthreads();
  // fg fc1 : [256] @ [256,1024]
  float hh[4];
  #pragma unroll
  for (int q = 0; q < 4; q++) {
    int jj = j + q * 256;
    float ac = fgb1[jj];
    for (int k = 0; k < 256; k++) ac += a[k] * fgw1[k * 1024 + jj];
    hh[q] = eluf_(ac);
  }
  __syncthreads();
  #pragma unroll
  for (int q = 0; q < 4; q++) hbuf[j + q * 256] = hh[q];
  __syncthreads();
  // fg fc2 : [1024] @ [1024,512], GLU + skip
  float G1 = fgb2[j], G2 = fgb2[256 + j];
  for (int k = 0; k < 1024; k++) { float hv = hbuf[k]; G1 += hv * fgw2[k * 512 + j]; G2 += hv * fgw2[k * 512 + 256 + j]; }
  float s2 = G1 * sigmoidf_(G2) + a[j];
  mean = block_sum256(s2, red) * (1.f / 256.f);
  d = s2 - mean;
  var = block_sum256(d * d, red) * (1.f / 256.f);
  out[bb * 256 + j] = d * rsqrtf(var + 1e-5f) * fglg[j] + fglb[j];
}

extern "C" void kernel_launch(void* const* d_in, const int* in_sizes, int n_in,
                              void* d_out, int out_size, void* d_ws, size_t ws_size,
                              hipStream_t stream) {
  const float* x          = (const float*)d_in[0];
  const float* emb_w      = (const float*)d_in[1];
  const float* emb_b      = (const float*)d_in[2];
  const float* vg_fc1_w   = (const float*)d_in[3];
  const float* vg_fc1_b   = (const float*)d_in[4];
  const float* vg_fc2_w   = (const float*)d_in[5];
  const float* vg_fc2_b   = (const float*)d_in[6];
  const float* vg_ln_g    = (const float*)d_in[7];
  const float* vg_ln_b    = (const float*)d_in[8];
  const float* sel_fc1_w  = (const float*)d_in[9];
  const float* sel_fc1_b  = (const float*)d_in[10];
  const float* sel_fc2_w  = (const float*)d_in[11];
  const float* sel_fc2_b  = (const float*)d_in[12];
  const float* sel_skip_w = (const float*)d_in[13];
  const float* sel_skip_b = (const float*)d_in[14];
  const float* sel_ln_g   = (const float*)d_in[15];
  const float* sel_ln_b   = (const float*)d_in[16];
  const float* lstm_wih   = (const float*)d_in[17];
  const float* lstm_whh   = (const float*)d_in[18];
  const float* lstm_bih   = (const float*)d_in[19];
  const float* lstm_bhh   = (const float*)d_in[20];
  const float* pl_fc1_w   = (const float*)d_in[21];
  const float* pl_fc1_b   = (const float*)d_in[22];
  const float* pl_fc2_w   = (const float*)d_in[23];
  const float* pl_fc2_b   = (const float*)d_in[24];
  const float* pl_ln_g    = (const float*)d_in[25];
  const float* pl_ln_b    = (const float*)d_in[26];
  const float* attn_in_w  = (const float*)d_in[27];
  const float* attn_in_b  = (const float*)d_in[28];
  const float* attn_out_w = (const float*)d_in[29];
  const float* attn_out_b = (const float*)d_in[30];
  const float* attn_ln_g  = (const float*)d_in[31];
  const float* attn_ln_b  = (const float*)d_in[32];
  const float* pa_fc1_w   = (const float*)d_in[33];
  const float* pa_fc1_b   = (const float*)d_in[34];
  const float* pa_fc2_w   = (const float*)d_in[35];
  const float* pa_fc2_b   = (const float*)d_in[36];
  const float* pa_ln_g    = (const float*)d_in[37];
  const float* pa_ln_b    = (const float*)d_in[38];
  const float* fg_fc1_w   = (const float*)d_in[39];
  const float* fg_fc1_b   = (const float*)d_in[40];
  const float* fg_fc2_w   = (const float*)d_in[41];
  const float* fg_fc2_b   = (const float*)d_in[42];
  const float* fg_ln_g    = (const float*)d_in[43];
  const float* fg_ln_b    = (const float*)d_in[44];

  float* out      = (float*)d_out;            // [32,256] then weights [32,512,16]
  float* out_wts  = out + BB * DD;            // second output slice

  // ---- workspace layout (floats), ~205 MB ----
  float* ws     = (float*)d_ws;
  const size_t MT = BT;
  float* bufA    = ws;                        // MT*256  (selH / varH / plH)
  float* bufG    = bufA   + MT * 256;         // MT*512  (fc2 outputs)
  float* vsn     = bufG   + MT * 512;         // MT*256
  float* big     = vsn    + MT * 256;         // MT*1024 (xi / qkv)
  float* hseq1   = big    + MT * 1024;        // MT*256
  float* hseq2   = hseq1  + MT * 256;         // MT*256
  float* plA     = hseq2  + MT * 256;         // MT*256
  float* lstmF   = plA    + MT * 256;         // MT*256
  float* selSkip = lstmF  + MT * 256;         // MT*16
  float* selG    = selSkip+ MT * 16;          // MT*32
  float* cbias   = selG   + MT * 32;          // 2048
  float* attnO   = cbias  + 2048;             // 8192
  float* attnLN  = attnO  + 8192;             // 8192
  (void)ws_size; (void)in_sizes; (void)n_in; (void)out_size;

  dim3 blk(256);

  // ---- selection GRN -> softmax weights (written straight to output slice) ----
  // fc1: embedded_flat [BT,4096] @ sel_fc1_w [4096,256], ELU
  gemm_k<1,0,1><<<dim3(4, 256), blk, 0, stream>>>(x, VV, sel_fc1_w, 256, sel_fc1_b,
                                                  bufA, 256, MT, 256, 4096, emb_w, emb_b);
  // skip: embedded_flat @ sel_skip_w [4096,16]
  gemm_k<1,0,0><<<dim3(1, 256), blk, 0, stream>>>(x, VV, sel_skip_w, 16, sel_skip_b,
                                                  selSkip, 16, MT, 16, 4096, emb_w, emb_b);
  // fc2: [BT,256] @ [256,32]
  gemm_k<0,0,0><<<dim3(1, 256), blk, 0, stream>>>(bufA, 256, sel_fc2_w, 32, sel_fc2_b,
                                                  selG, 32, MT, 32, 256, nullptr, nullptr);
  sel_finish_k<<<64, blk, 0, stream>>>(selG, selSkip, sel_ln_g, sel_ln_b, out_wts, MT);

  // ---- per-variable GRNs + weighted sum into vsn ----
  for (int v = 0; v < VV; v++) {
    gemm_k<1,0,1><<<dim3(4, 256), blk, 0, stream>>>(x + v, VV,
        vg_fc1_w + (size_t)v * 256 * 256, 256, vg_fc1_b + v * 256,
        bufA, 256, MT, 256, 256, emb_w + v * 256, emb_b + v * 256);
    gemm_k<0,0,0><<<dim3(8, 256), blk, 0, stream>>>(bufA, 256,
        vg_fc2_w + (size_t)v * 256 * 512, 512, vg_fc2_b + v * 512,
        bufG, 512, MT, 512, 256, nullptr, nullptr);
    var_epi_k<<<MT, blk, 0, stream>>>(bufG, x, v, emb_w + v * 256, emb_b + v * 256,
        vg_ln_g + v * 256, vg_ln_b + v * 256, out_wts, vsn, v == 0 ? 1 : 0);
  }

  // ---- LSTM (2 layers) ----
  cbias_k<<<8, blk, 0, stream>>>(lstm_bih, lstm_bhh, cbias, 2048);
  // layer 0
  gemm_k<0,1,0><<<dim3(16, 256), blk, 0, stream>>>(vsn, 256, lstm_wih, 256, cbias,
                                                   big, 1024, MT, 1024, 256, nullptr, nullptr);
  lstm_recur_k<<<BB, 1024, 0, stream>>>(big, lstm_whh, hseq1, TT);
  // layer 1
  gemm_k<0,1,0><<<dim3(16, 256), blk, 0, stream>>>(hseq1, 256, lstm_wih + 1024 * 256, 256,
                                                   cbias + 1024, big, 1024, MT, 1024, 256, nullptr, nullptr);
  lstm_recur_k<<<BB, 1024, 0, stream>>>(big, lstm_whh + 1024 * 256, hseq2, TT);

  // ---- post-LSTM gated residual (pl GRN) ----
  add2_k<<<MT, blk, 0, stream>>>(hseq2, vsn, plA, MT * 256);
  gemm_k<0,0,1><<<dim3(4, 256), blk, 0, stream>>>(plA, 256, pl_fc1_w, 256, pl_fc1_b,
                                                  bufA, 256, MT, 256, 256, nullptr, nullptr);
  gemm_k<0,0,0><<<dim3(8, 256), blk, 0, stream>>>(bufA, 256, pl_fc2_w, 512, pl_fc2_b,
                                                  bufG, 512, MT, 512, 256, nullptr, nullptr);
  grn_epi_k<<<MT, blk, 0, stream>>>(bufG, plA, pl_ln_g, pl_ln_b, lstmF);

  // ---- attention (decode at t=T-1 only) ----
  gemm_k<0,1,0><<<dim3(12, 256), blk, 0, stream>>>(lstmF, 256, attn_in_w, 256, attn_in_b,
                                                   big, 768, MT, 768, 256, nullptr, nullptr);
  attn_decode_k<<<BB * 4, blk, 0, stream>>>(big, attnO, TT);
  attn_proj_ln_k<<<BB, blk, 0, stream>>>(attnO, attn_out_w, attn_out_b, lstmF,
                                         attn_ln_g, attn_ln_b, attnLN, TT);

  // ---- pa GRN + fg GRN (t=T-1 only) -> first output slice ----
  final_grns_k<<<BB, blk, 0, stream>>>(attnLN,
      pa_fc1_w, pa_fc1_b, pa_fc2_w, pa_fc2_b, pa_ln_g, pa_ln_b,
      fg_fc1_w, fg_fc1_b, fg_fc2_w, fg_fc2_b, fg_ln_g, fg_ln_b,
      out);
}

// Round 3
// 17047.054 us; speedup vs baseline: 2.0027x; 2.0027x over previous
//
#include <hip/hip_runtime.h>
#include <hip/hip_bf16.h>
#include <math.h>

// TFT: B=32, T=512, V=16, D=256, H=4, L=2.  BT = 16384.
// Round 2 (fix): bf16 MFMA GEMMs (weights pre-transposed/converted to bf16 [N,K] in ws),
// embedded generated on the fly in A-staging, bf16 whh for the LSTM recurrence,
// attention decode-only at t=T-1.

#define BT 16384
#define TT 512
#define BB 32
#define VV 16
#define DD 256

typedef unsigned short ushort;
typedef __attribute__((ext_vector_type(8))) short short8;
typedef __attribute__((ext_vector_type(8))) unsigned short ushort8v;
typedef __attribute__((ext_vector_type(4))) float floatx4;

__device__ __forceinline__ float sigmoidf_(float x) { return 1.f / (1.f + expf(-x)); }
__device__ __forceinline__ float eluf_(float x)     { return x > 0.f ? x : expm1f(x); }
__device__ __forceinline__ ushort f2bf(float f) {
  unsigned int u = __float_as_uint(f);
  unsigned int r = u + 0x7fffu + ((u >> 16) & 1u);
  return (ushort)(r >> 16);
}
__device__ __forceinline__ float bf2f(ushort b) { return __uint_as_float(((unsigned int)b) << 16); }

// block-wide sum over 256 threads via wave shuffles + 4-slot LDS
__device__ __forceinline__ float bsum256(float v, float* red4) {
  #pragma unroll
  for (int m = 32; m > 0; m >>= 1) v += __shfl_xor(v, m, 64);
  int w = threadIdx.x >> 6;
  if ((threadIdx.x & 63) == 0) red4[w] = v;
  __syncthreads();
  float r = red4[0] + red4[1] + red4[2] + red4[3];
  __syncthreads();
  return r;
}

// legacy full-LDS reduction (used by tiny tail kernels)
__device__ __forceinline__ float block_sum256(float v, float* red) {
  int j = threadIdx.x;
  red[j] = v; __syncthreads();
  #pragma unroll
  for (int st = 128; st > 0; st >>= 1) {
    if (j < st) red[j] += red[j + st];
    __syncthreads();
  }
  float r = red[0];
  __syncthreads();
  return r;
}

// ---------------- weight prep ----------------
// transpose-convert: src fp32 [K,N] -> dst bf16 [N,K]; batched via z
__global__ void wtT_k(const float* __restrict__ src, ushort* __restrict__ dst,
                      int K, int N, long sStride, long dStride) {
  int b = blockIdx.z;
  src += (size_t)b * sStride; dst += (size_t)b * dStride;
  __shared__ float t[32][33];
  int k0 = blockIdx.y * 32, n0 = blockIdx.x * 32;
  int tx = threadIdx.x & 31, ty = threadIdx.x >> 5;
  #pragma unroll
  for (int i = 0; i < 32; i += 8) {
    int k = k0 + ty + i, n = n0 + tx;
    t[ty + i][tx] = (k < K && n < N) ? src[(size_t)k * N + n] : 0.f;
  }
  __syncthreads();
  #pragma unroll
  for (int i = 0; i < 32; i += 8) {
    int n = n0 + ty + i, k = k0 + tx;
    if (n < N && k < K) dst[(size_t)n * K + k] = f2bf(t[tx][ty + i]);
  }
}

// elementwise fp32 -> bf16
__global__ void cvt_k(const float* __restrict__ src, ushort* __restrict__ dst, int n) {
  int i = blockIdx.x * 256 + threadIdx.x;
  if (i < n) dst[i] = f2bf(src[i]);
}

// ---------------- bf16 MFMA GEMM ----------------
// C[M,N] = act(A[M,K] @ B^T + bias), B is bf16 [N,K] row-major.
// ADT: 0 = A fp32 row-major lda; 1 = A bf16 row-major lda;
//      2 = embedded on the fly: a = x[gm*lda + xbase + z + (k>>8)]*embw[z*256+k] + embb[z*256+k]
// ACT: 0 none, 1 ELU.  CDT: 0 fp32 C, 1 bf16 C.
// Tile: 128x128, BK=32, 256 threads (4 waves, 2x2 of 64x64), mfma_f32_16x16x32_bf16.
template<int ADT, int ACT, int CDT>
__global__ __launch_bounds__(256) void mgemm_k(
    const void* __restrict__ Aall, int lda, long aStride,
    const ushort* __restrict__ Ball, long bStride,
    const float* __restrict__ biasAll, long biasStride,
    void* __restrict__ Call, int ldc, long cStride,
    int K, int Nvalid,
    const float* __restrict__ embw, const float* __restrict__ embb, int xbase) {
  int z = blockIdx.z;
  const ushort* B = Ball + (size_t)z * bStride;
  const float* bias = biasAll ? biasAll + (size_t)z * biasStride : nullptr;
  int m0 = blockIdx.y * 128, n0 = blockIdx.x * 128;
  __shared__ ushort As[128][40];
  __shared__ ushort Bs[128][40];
  int tid = threadIdx.x;
  int r = tid >> 1, half = tid & 1;
  int wave = tid >> 6, lane = tid & 63;
  int wm = (wave >> 1) * 64, wn = (wave & 1) * 64;
  int lm = lane & 15, lq = lane >> 4;
  floatx4 acc[4][4];
  #pragma unroll
  for (int i = 0; i < 4; i++)
    #pragma unroll
    for (int j = 0; j < 4; j++) acc[i][j] = (floatx4)0.f;

  for (int k0 = 0; k0 < K; k0 += 32) {
    int kk = k0 + half * 16;
    // ---- stage A row r, 16 elems at kk ----
    {
      int gm = m0 + r;
      ushort tmp[16];
      if (ADT == 0) {
        const float* Af = (const float*)Aall + (size_t)z * aStride + (size_t)gm * lda + kk;
        #pragma unroll
        for (int q = 0; q < 4; q++) {
          float4 f = ((const float4*)Af)[q];
          tmp[q * 4 + 0] = f2bf(f.x); tmp[q * 4 + 1] = f2bf(f.y);
          tmp[q * 4 + 2] = f2bf(f.z); tmp[q * 4 + 3] = f2bf(f.w);
        }
      } else if (ADT == 1) {
        const ushort* Ab = (const ushort*)Aall + (size_t)z * aStride + (size_t)gm * lda + kk;
        *(ushort8v*)&tmp[0] = *(const ushort8v*)(Ab);
        *(ushort8v*)&tmp[8] = *(const ushort8v*)(Ab + 8);
      } else {
        const float* xp = (const float*)Aall;
        float xv = xp[(size_t)gm * lda + xbase + z + (kk >> 8)];
        const float4* ew = (const float4*)(embw + (size_t)z * 256 + kk);
        const float4* eb = (const float4*)(embb + (size_t)z * 256 + kk);
        #pragma unroll
        for (int q = 0; q < 4; q++) {
          float4 w4 = ew[q], b4 = eb[q];
          tmp[q * 4 + 0] = f2bf(xv * w4.x + b4.x); tmp[q * 4 + 1] = f2bf(xv * w4.y + b4.y);
          tmp[q * 4 + 2] = f2bf(xv * w4.z + b4.z); tmp[q * 4 + 3] = f2bf(xv * w4.w + b4.w);
        }
      }
      *(ushort8v*)&As[r][half * 16]     = *(ushort8v*)&tmp[0];
      *(ushort8v*)&As[r][half * 16 + 8] = *(ushort8v*)&tmp[8];
    }
    // ---- stage B row r (output col n0+r), 16 elems at kk ----
    {
      int gn = n0 + r;
      ushort tmp[16];
      if (gn < Nvalid) {
        const ushort* Bp = B + (size_t)gn * K + kk;
        *(ushort8v*)&tmp[0] = *(const ushort8v*)(Bp);
        *(ushort8v*)&tmp[8] = *(const ushort8v*)(Bp + 8);
      } else {
        #pragma unroll
        for (int q = 0; q < 16; q++) tmp[q] = 0;
      }
      *(ushort8v*)&Bs[r][half * 16]     = *(ushort8v*)&tmp[0];
      *(ushort8v*)&Bs[r][half * 16 + 8] = *(ushort8v*)&tmp[8];
    }
    __syncthreads();
    short8 fa[4], fb[4];
    #pragma unroll
    for (int i = 0; i < 4; i++) fa[i] = *(const short8*)&As[wm + i * 16 + lm][lq * 8];
    #pragma unroll
    for (int j = 0; j < 4; j++) fb[j] = *(const short8*)&Bs[wn + j * 16 + lm][lq * 8];
    #pragma unroll
    for (int i = 0; i < 4; i++)
      #pragma unroll
      for (int j = 0; j < 4; j++)
        acc[i][j] = __builtin_amdgcn_mfma_f32_16x16x32_bf16(fa[i], fb[j], acc[i][j], 0, 0, 0);
    __syncthreads();
  }
  // ---- epilogue: C/D layout col=lane&15, row=(lane>>4)*4+reg ----
  #pragma unroll
  for (int j = 0; j < 4; j++) {
    int gn = n0 + wn + j * 16 + lm;
    if (gn >= Nvalid) continue;
    float bv = bias ? bias[gn] : 0.f;
    #pragma unroll
    for (int i = 0; i < 4; i++) {
      #pragma unroll
      for (int rg = 0; rg < 4; rg++) {
        int gm = m0 + wm + i * 16 + lq * 4 + rg;
        float v = acc[i][j][rg] + bv;
        if (ACT == 1) v = eluf_(v);
        if (CDT == 0) ((float*)Call + (size_t)z * cStride)[(size_t)gm * ldc + gn] = v;
        else ((ushort*)Call + (size_t)z * cStride)[(size_t)gm * ldc + gn] = f2bf(v);
      }
    }
  }
}

// ---------------- selection GRN finish: GLU + skip + LN(16) + softmax ----------------
__global__ void sel_finish_k(const float* __restrict__ selG, const float* __restrict__ selSkip,
                             const float* __restrict__ lng, const float* __restrict__ lnb,
                             float* __restrict__ wout, int M) {
  int m = blockIdx.x * 256 + threadIdx.x;
  if (m >= M) return;
  float s[16];
  float mean = 0.f;
  #pragma unroll
  for (int i = 0; i < 16; i++) {
    float h1 = selG[m * 32 + i], h2 = selG[m * 32 + 16 + i];
    float val = h1 * sigmoidf_(h2) + selSkip[m * 16 + i];
    s[i] = val; mean += val;
  }
  mean *= (1.f / 16.f);
  float var = 0.f;
  #pragma unroll
  for (int i = 0; i < 16; i++) { float d = s[i] - mean; var += d * d; }
  var *= (1.f / 16.f);
  float inv = rsqrtf(var + 1e-5f);
  float mx = -1e30f;
  #pragma unroll
  for (int i = 0; i < 16; i++) { s[i] = (s[i] - mean) * inv * lng[i] + lnb[i]; mx = fmaxf(mx, s[i]); }
  float sum = 0.f;
  #pragma unroll
  for (int i = 0; i < 16; i++) { s[i] = expf(s[i] - mx); sum += s[i]; }
  float isum = 1.f / sum;
  #pragma unroll
  for (int i = 0; i < 16; i++) wout[m * 16 + i] = s[i] * isum;
}

// ---------------- var-GRN epilogue, 4 variables per launch ----------------
__global__ __launch_bounds__(256) void var_epi4_k(
    const ushort* __restrict__ G16,     // [4][BT][512] bf16
    const float* __restrict__ x, int vbase,
    const float* __restrict__ embw, const float* __restrict__ embb,  // + vbase*256
    const float* __restrict__ lng, const float* __restrict__ lnb,    // + vbase*256
    const float* __restrict__ wts, float* __restrict__ vsn, int first) {
  int m = blockIdx.x, j = threadIdx.x;
  __shared__ float red4[4];
  float accv = 0.f;
  #pragma unroll
  for (int z = 0; z < 4; z++) {
    int v = vbase + z;
    const ushort* Gp = G16 + ((size_t)z * BT + m) * 512;
    float g1 = bf2f(Gp[j]), g2 = bf2f(Gp[256 + j]);
    float e = x[m * VV + v] * embw[z * 256 + j] + embb[z * 256 + j];
    float s = g1 * sigmoidf_(g2) + e;
    float mean = bsum256(s, red4) * (1.f / 256.f);
    float d = s - mean;
    float var = bsum256(d * d, red4) * (1.f / 256.f);
    float o = d * rsqrtf(var + 1e-5f) * lng[z * 256 + j] + lnb[z * 256 + j];
    accv += wts[m * VV + v] * o;
  }
  size_t oi = (size_t)m * 256 + j;
  if (first) vsn[oi] = accv; else vsn[oi] += accv;
}

// ---------------- generic GRN epilogue (bf16 G): GLU + skip + LN(256) ----------------
__global__ __launch_bounds__(256) void grn_epi_k(
    const ushort* __restrict__ G, const float* __restrict__ skip,
    const float* __restrict__ lng, const float* __restrict__ lnb,
    float* __restrict__ out) {
  int m = blockIdx.x, j = threadIdx.x;
  __shared__ float red4[4];
  float g1 = bf2f(G[(size_t)m * 512 + j]), g2 = bf2f(G[(size_t)m * 512 + 256 + j]);
  float s = g1 * sigmoidf_(g2) + skip[(size_t)m * 256 + j];
  float mean = bsum256(s, red4) * (1.f / 256.f);
  float d = s - mean;
  float var = bsum256(d * d, red4) * (1.f / 256.f);
  out[(size_t)m * 256 + j] = d * rsqrtf(var + 1e-5f) * lng[j] + lnb[j];
}

// ---------------- elementwise ----------------
__global__ void add2_k(const float* __restrict__ a, const float* __restrict__ b,
                       float* __restrict__ c, int n) {
  int i = blockIdx.x * 256 + threadIdx.x;
  if (i < n) c[i] = a[i] + b[i];
}

// ---------------- LSTM recurrence: 1 block/batch, 1024 thr (1/gate), bf16 whh ----------------
__global__ __launch_bounds__(1024) void lstm_recur_k(
    const float* __restrict__ xi,     // [B,T,1024] = xW^T + bih + bhh
    const ushort* __restrict__ whh,   // [1024,256] bf16
    float* __restrict__ hout,         // [B,T,256]
    int T) {
  int b = blockIdx.x;
  int j = threadIdx.x;
  __shared__ float hp[256];
  __shared__ float gates[1024];
  float c = 0.f;
  if (j < 256) hp[j] = 0.f;
  __syncthreads();
  const ushort* wr = whh + (size_t)j * 256;
  for (int t = 0; t < T; t++) {
    float acc = xi[((size_t)(b * T + t)) * 1024 + j];
    #pragma unroll
    for (int k = 0; k < 256; k += 8) {
      ushort8v w8 = *(const ushort8v*)(wr + k);
      float4 ha = *(const float4*)&hp[k];
      float4 hb = *(const float4*)&hp[k + 4];
      acc += ha.x * bf2f(w8[0]) + ha.y * bf2f(w8[1]) + ha.z * bf2f(w8[2]) + ha.w * bf2f(w8[3])
           + hb.x * bf2f(w8[4]) + hb.y * bf2f(w8[5]) + hb.z * bf2f(w8[6]) + hb.w * bf2f(w8[7]);
    }
    gates[j] = acc;
    __syncthreads();
    if (j < 256) {
      float i_ = gates[j], f_ = gates[256 + j], g_ = gates[512 + j], o_ = gates[768 + j];
      c = sigmoidf_(f_) * c + sigmoidf_(i_) * tanhf(g_);
      float h = sigmoidf_(o_) * tanhf(c);
      hp[j] = h;
      hout[((size_t)(b * T + t)) * 256 + j] = h;
    }
    __syncthreads();
  }
}

// ---------------- attention, decode-style (only query t = T-1) ----------------
__global__ __launch_bounds__(256) void attn_decode_k(const float* __restrict__ qkv, // [B,T,768]
                                                     float* __restrict__ o,         // [B,256]
                                                     int T) {
  int bh = blockIdx.x; int b = bh >> 2, h = bh & 3;
  int tid = threadIdx.x;
  __shared__ float q[64];
  __shared__ float p[512];
  __shared__ float red[256];
  if (tid < 64) q[tid] = qkv[((size_t)(b * T + T - 1)) * 768 + h * 64 + tid];
  __syncthreads();
  for (int t = tid; t < 512; t += 256) {
    const float* kv = qkv + ((size_t)(b * T + t)) * 768 + 256 + h * 64;
    float s = 0.f;
    #pragma unroll 16
    for (int d = 0; d < 64; d++) s += q[d] * kv[d];
    p[t] = s * 0.125f;
  }
  __syncthreads();
  red[tid] = fmaxf(p[tid], p[tid + 256]); __syncthreads();
  for (int st = 128; st > 0; st >>= 1) { if (tid < st) red[tid] = fmaxf(red[tid], red[tid + st]); __syncthreads(); }
  float mx = red[0]; __syncthreads();
  float e0 = expf(p[tid] - mx), e1 = expf(p[tid + 256] - mx);
  red[tid] = e0 + e1; __syncthreads();
  for (int st = 128; st > 0; st >>= 1) { if (tid < st) red[tid] += red[tid + st]; __syncthreads(); }
  float inv = 1.f / red[0];
  __syncthreads();
  p[tid] = e0; p[tid + 256] = e1;
  __syncthreads();
  int d = tid & 63, grp = tid >> 6;
  float acc = 0.f;
  for (int t = grp * 128; t < grp * 128 + 128; t++)
    acc += p[t] * qkv[((size_t)(b * T + t)) * 768 + 512 + h * 64 + d];
  red[tid] = acc; __syncthreads();
  if (grp == 0)
    o[(b * 4 + h) * 64 + d] = (red[tid] + red[tid + 64] + red[tid + 128] + red[tid + 192]) * inv;
}

// ---------------- attn out-proj + residual + LN (only t=T-1) ----------------
__global__ __launch_bounds__(256) void attn_proj_ln_k(
    const float* __restrict__ attnO, const float* __restrict__ W, const float* __restrict__ bias,
    const float* __restrict__ lstmF, const float* __restrict__ lng, const float* __restrict__ lnb,
    float* __restrict__ out, int T) {
  int bb = blockIdx.x, j = threadIdx.x;
  __shared__ float a[256];
  __shared__ float red[256];
  a[j] = attnO[bb * 256 + j];
  __syncthreads();
  float acc = bias[j];
  const float* wr = W + (size_t)j * 256;
  #pragma unroll 8
  for (int k = 0; k < 256; k += 4) {
    float4 w4 = *(const float4*)(wr + k);
    acc += a[k] * w4.x + a[k + 1] * w4.y + a[k + 2] * w4.z + a[k + 3] * w4.w;
  }
  float s = acc + lstmF[((size_t)(bb * T + T - 1)) * 256 + j];
  float mean = block_sum256(s, red) * (1.f / 256.f);
  float d = s - mean;
  float var = block_sum256(d * d, red) * (1.f / 256.f);
  out[bb * 256 + j] = d * rsqrtf(var + 1e-5f) * lng[j] + lnb[j];
}

// ---------------- final two GRNs (pa then fg), only t=T-1 ----------------
__global__ __launch_bounds__(256) void final_grns_k(
    const float* __restrict__ ain,
    const float* __restrict__ paw1, const float* __restrict__ pab1,
    const float* __restrict__ paw2, const float* __restrict__ pab2,
    const float* __restrict__ palg, const float* __restrict__ palb,
    const float* __restrict__ fgw1, const float* __restrict__ fgb1,
    const float* __restrict__ fgw2, const float* __restrict__ fgb2,
    const float* __restrict__ fglg, const float* __restrict__ fglb,
    float* __restrict__ out) {
  int bb = blockIdx.x, j = threadIdx.x;
  __shared__ float a[256];
  __shared__ float hbuf[1024];
  __shared__ float red[256];
  a[j] = ain[bb * 256 + j];
  __syncthreads();
  float acc = pab1[j];
  for (int k = 0; k < 256; k++) acc += a[k] * paw1[k * 256 + j];
  hbuf[j] = eluf_(acc);
  __syncthreads();
  float g1 = pab2[j], g2 = pab2[256 + j];
  for (int k = 0; k < 256; k++) { float hv = hbuf[k]; g1 += hv * paw2[k * 512 + j]; g2 += hv * paw2[k * 512 + 256 + j]; }
  float s = g1 * sigmoidf_(g2) + a[j];
  float mean = block_sum256(s, red) * (1.f / 256.f);
  float d = s - mean;
  float var = block_sum256(d * d, red) * (1.f / 256.f);
  float af = d * rsqrtf(var + 1e-5f) * palg[j] + palb[j];
  __syncthreads();
  a[j] = af;
  __syncthreads();
  float hh[4];
  #pragma unroll
  for (int q = 0; q < 4; q++) {
    int jj = j + q * 256;
    float ac = fgb1[jj];
    for (int k = 0; k < 256; k++) ac += a[k] * fgw1[k * 1024 + jj];
    hh[q] = eluf_(ac);
  }
  __syncthreads();
  #pragma unroll
  for (int q = 0; q < 4; q++) hbuf[j + q * 256] = hh[q];
  __syncthreads();
  float G1 = fgb2[j], G2 = fgb2[256 + j];
  for (int k = 0; k < 1024; k++) { float hv = hbuf[k]; G1 += hv * fgw2[k * 512 + j]; G2 += hv * fgw2[k * 512 + 256 + j]; }
  float s2 = G1 * sigmoidf_(G2) + a[j];
  mean = block_sum256(s2, red) * (1.f / 256.f);
  d = s2 - mean;
  var = block_sum256(d * d, red) * (1.f / 256.f);
  out[bb * 256 + j] = d * rsqrtf(var + 1e-5f) * fglg[j] + fglb[j];
}

extern "C" void kernel_launch(void* const* d_in, const int* in_sizes, int n_in,
                              void* d_out, int out_size, void* d_ws, size_t ws_size,
                              hipStream_t stream) {
  const float* x          = (const float*)d_in[0];
  const float* emb_w      = (const float*)d_in[1];
  const float* emb_b      = (const float*)d_in[2];
  const float* vg_fc1_w   = (const float*)d_in[3];
  const float* vg_fc1_b   = (const float*)d_in[4];
  const float* vg_fc2_w   = (const float*)d_in[5];
  const float* vg_fc2_b   = (const float*)d_in[6];
  const float* vg_ln_g    = (const float*)d_in[7];
  const float* vg_ln_b    = (const float*)d_in[8];
  const float* sel_fc1_w  = (const float*)d_in[9];
  const float* sel_fc1_b  = (const float*)d_in[10];
  const float* sel_fc2_w  = (const float*)d_in[11];
  const float* sel_fc2_b  = (const float*)d_in[12];
  const float* sel_skip_w = (const float*)d_in[13];
  const float* sel_skip_b = (const float*)d_in[14];
  const float* sel_ln_g   = (const float*)d_in[15];
  const float* sel_ln_b   = (const float*)d_in[16];
  const float* lstm_wih   = (const float*)d_in[17];
  const float* lstm_whh   = (const float*)d_in[18];
  const float* lstm_bih   = (const float*)d_in[19];
  const float* lstm_bhh   = (const float*)d_in[20];
  const float* pl_fc1_w   = (const float*)d_in[21];
  const float* pl_fc1_b   = (const float*)d_in[22];
  const float* pl_fc2_w   = (const float*)d_in[23];
  const float* pl_fc2_b   = (const float*)d_in[24];
  const float* pl_ln_g    = (const float*)d_in[25];
  const float* pl_ln_b    = (const float*)d_in[26];
  const float* attn_in_w  = (const float*)d_in[27];
  const float* attn_in_b  = (const float*)d_in[28];
  const float* attn_out_w = (const float*)d_in[29];
  const float* attn_out_b = (const float*)d_in[30];
  const float* attn_ln_g  = (const float*)d_in[31];
  const float* attn_ln_b  = (const float*)d_in[32];
  const float* pa_fc1_w   = (const float*)d_in[33];
  const float* pa_fc1_b   = (const float*)d_in[34];
  const float* pa_fc2_w   = (const float*)d_in[35];
  const float* pa_fc2_b   = (const float*)d_in[36];
  const float* pa_ln_g    = (const float*)d_in[37];
  const float* pa_ln_b    = (const float*)d_in[38];
  const float* fg_fc1_w   = (const float*)d_in[39];
  const float* fg_fc1_b   = (const float*)d_in[40];
  const float* fg_fc2_w   = (const float*)d_in[41];
  const float* fg_fc2_b   = (const float*)d_in[42];
  const float* fg_ln_g    = (const float*)d_in[43];
  const float* fg_ln_b    = (const float*)d_in[44];
  (void)in_sizes; (void)n_in; (void)out_size; (void)ws_size;

  float* out     = (float*)d_out;
  float* out_wts = out + BB * DD;

  // ---- workspace layout ----
  char* p = (char*)d_ws;
  ushort* wt_sel_fc1  = (ushort*)p;                 p += 1048576 * 2;
  ushort* wt_sel_skip = (ushort*)p;                 p += 65536 * 2;
  ushort* wt_sel_fc2  = (ushort*)p;                 p += 8192 * 2;
  ushort* wt_var_fc1  = (ushort*)p;                 p += 1048576 * 2;
  ushort* wt_var_fc2  = (ushort*)p;                 p += 2097152 * 2;
  ushort* wt_wih      = (ushort*)p;                 p += 524288 * 2;
  ushort* wt_whh      = (ushort*)p;                 p += 524288 * 2;
  ushort* wt_pl_fc1   = (ushort*)p;                 p += 65536 * 2;
  ushort* wt_pl_fc2   = (ushort*)p;                 p += 131072 * 2;
  ushort* wt_attn     = (ushort*)p;                 p += 196608 * 2;
  ushort* selH        = (ushort*)p;                 p += (size_t)BT * 256 * 2;     // 8 MB
  float*  selSkip     = (float*)p;                  p += (size_t)BT * 16 * 4;      // 1 MB
  float*  selG        = (float*)p;                  p += (size_t)BT * 32 * 4;      // 2 MB
  float*  vsn         = (float*)p;                  p += (size_t)BT * 256 * 4;     // 16 MB
  float*  hseq1       = (float*)p;                  p += (size_t)BT * 256 * 4;     // 16 MB
  float*  hseq2       = (float*)p;                  p += (size_t)BT * 256 * 4;     // 16 MB
  float*  cbias       = (float*)p;                  p += 4096 * 4;
  float*  attnO       = (float*)p;                  p += 8192 * 4;
  float*  attnLN      = (float*)p;                  p += 8192 * 4;
  char*   R           = p;                          // shared 96 MB region
  ushort* bufA16 = (ushort*)R;                               // [4][BT][256] bf16 = 32 MB
  ushort* bufG16 = (ushort*)(R + (((size_t)32) << 20));      // [4][BT][512] bf16 = 64 MB
  float*  xi     = (float*)R;                                // [BT,1024] fp32 = 64 MB
  float*  plA    = (float*)R;                                // 16 MB
  ushort* plH    = (ushort*)(R + (((size_t)16) << 20));      // 8 MB
  ushort* plG    = (ushort*)(R + (((size_t)24) << 20));      // 16 MB
  float*  lstmF  = (float*)(R + (((size_t)48) << 20));       // 16 MB
  float*  qkv    = (float*)R;                                // [BT,768] fp32 = 48 MB

  dim3 blk(256);

  // ---- weight prep (bf16, [N,K]) ----
  wtT_k<<<dim3(8, 128, 1),  blk, 0, stream>>>(sel_fc1_w,  wt_sel_fc1,  4096, 256, 0, 0);
  wtT_k<<<dim3(1, 128, 1),  blk, 0, stream>>>(sel_skip_w, wt_sel_skip, 4096, 16,  0, 0);
  wtT_k<<<dim3(1, 8, 1),    blk, 0, stream>>>(sel_fc2_w,  wt_sel_fc2,  256,  32,  0, 0);
  wtT_k<<<dim3(8, 8, 16),   blk, 0, stream>>>(vg_fc1_w,   wt_var_fc1,  256,  256, 65536, 65536);
  wtT_k<<<dim3(16, 8, 16),  blk, 0, stream>>>(vg_fc2_w,   wt_var_fc2,  256,  512, 131072, 131072);
  wtT_k<<<dim3(8, 8, 1),    blk, 0, stream>>>(pl_fc1_w,   wt_pl_fc1,   256,  256, 0, 0);
  wtT_k<<<dim3(16, 8, 1),   blk, 0, stream>>>(pl_fc2_w,   wt_pl_fc2,   256,  512, 0, 0);
  cvt_k<<<2048, blk, 0, stream>>>(lstm_wih,  wt_wih, 524288);
  cvt_k<<<2048, blk, 0, stream>>>(lstm_whh,  wt_whh, 524288);
  cvt_k<<<768,  blk, 0, stream>>>(attn_in_w, wt_attn, 196608);
  add2_k<<<8, blk, 0, stream>>>(lstm_bih, lstm_bhh, cbias, 4096);

  // ---- selection GRN -> softmax weights ----
  mgemm_k<2,1,1><<<dim3(2, 128, 1), blk, 0, stream>>>(x, 16, 0, wt_sel_fc1, 0, sel_fc1_b, 0,
      selH, 256, 0, 4096, 256, emb_w, emb_b, 0);
  mgemm_k<2,0,0><<<dim3(1, 128, 1), blk, 0, stream>>>(x, 16, 0, wt_sel_skip, 0, sel_skip_b, 0,
      selSkip, 16, 0, 4096, 16, emb_w, emb_b, 0);
  mgemm_k<1,0,0><<<dim3(1, 128, 1), blk, 0, stream>>>(selH, 256, 0, wt_sel_fc2, 0, sel_fc2_b, 0,
      selG, 32, 0, 256, 32, nullptr, nullptr, 0);
  sel_finish_k<<<64, blk, 0, stream>>>(selG, selSkip, sel_ln_g, sel_ln_b, out_wts, BT);

  // ---- per-variable GRNs (groups of 4) + weighted sum into vsn ----
  for (int g = 0; g < 4; g++) {
    mgemm_k<2,1,1><<<dim3(2, 128, 4), blk, 0, stream>>>(x, 16, 0,
        wt_var_fc1 + (size_t)g * 4 * 65536, 65536, vg_fc1_b + g * 1024, 256,
        bufA16, 256, (long)BT * 256, 256, 256, emb_w + g * 1024, emb_b + g * 1024, g * 4);
    mgemm_k<1,0,1><<<dim3(4, 128, 4), blk, 0, stream>>>(bufA16, 256, (long)BT * 256,
        wt_var_fc2 + (size_t)g * 4 * 131072, 131072, vg_fc2_b + g * 2048, 512,
        bufG16, 512, (long)BT * 512, 256, 512, nullptr, nullptr, 0);
    var_epi4_k<<<BT, blk, 0, stream>>>(bufG16, x, g * 4, emb_w + g * 1024, emb_b + g * 1024,
        vg_ln_g + g * 1024, vg_ln_b + g * 1024, out_wts, vsn, g == 0 ? 1 : 0);
  }

  // ---- LSTM (2 layers) ----
  mgemm_k<0,0,0><<<dim3(8, 128, 1), blk, 0, stream>>>(vsn, 256, 0, wt_wih, 0, cbias, 0,
      xi, 1024, 0, 256, 1024, nullptr, nullptr, 0);
  lstm_recur_k<<<BB, 1024, 0, stream>>>(xi, wt_whh, hseq1, TT);
  mgemm_k<0,0,0><<<dim3(8, 128, 1), blk, 0, stream>>>(hseq1, 256, 0, wt_wih + 1024 * 256, 0,
      cbias + 1024, 0, xi, 1024, 0, 256, 1024, nullptr, nullptr, 0);
  lstm_recur_k<<<BB, 1024, 0, stream>>>(xi, wt_whh + 1024 * 256, hseq2, TT);

  // ---- post-LSTM gated residual (pl GRN) ----
  add2_k<<<BT, blk, 0, stream>>>(hseq2, vsn, plA, BT * 256);
  mgemm_k<0,1,1><<<dim3(2, 128, 1), blk, 0, stream>>>(plA, 256, 0, wt_pl_fc1, 0, pl_fc1_b, 0,
      plH, 256, 0, 256, 256, nullptr, nullptr, 0);
  mgemm_k<1,0,1><<<dim3(4, 128, 1), blk, 0, stream>>>(plH, 256, 0, wt_pl_fc2, 0, pl_fc2_b, 0,
      plG, 512, 0, 256, 512, nullptr, nullptr, 0);
  grn_epi_k<<<BT, blk, 0, stream>>>(plG, plA, pl_ln_g, pl_ln_b, lstmF);

  // ---- attention (decode at t=T-1 only) ----
  mgemm_k<0,0,0><<<dim3(6, 128, 1), blk, 0, stream>>>(lstmF, 256, 0, wt_attn, 0, attn_in_b, 0,
      qkv, 768, 0, 256, 768, nullptr, nullptr, 0);
  attn_decode_k<<<BB * 4, blk, 0, stream>>>(qkv, attnO, TT);
  attn_proj_ln_k<<<BB, blk, 0, stream>>>(attnO, attn_out_w, attn_out_b, lstmF,
                                         attn_ln_g, attn_ln_b, attnLN, TT);

  // ---- pa GRN + fg GRN (t=T-1 only) -> first output slice ----
  final_grns_k<<<BB, blk, 0, stream>>>(attnLN,
      pa_fc1_w, pa_fc1_b, pa_fc2_w, pa_fc2_b, pa_ln_g, pa_ln_b,
      fg_fc1_w, fg_fc1_b, fg_fc2_w, fg_fc2_b, fg_ln_g, fg_ln_b,
      out);
}

// Round 4
// 4702.756 us; speedup vs baseline: 7.2595x; 3.6249x over previous
//
#include <hip/hip_runtime.h>
#include <hip/hip_bf16.h>
#include <math.h>

// TFT: B=32, T=512, V=16, D=256, H=4, L=2.  BT = 16384.
// Round 4: LSTM recurrence rebuilt — whh packed as half2 (fp16) in lane-major
// layout; 72 dwords/thread pinned in VGPRs + 56 dwords/step streamed coalesced;
// v_dot2_f32_f16 inner product; fp16 h-state broadcast from LDS; xi prefetch.
// GEMMs: bf16 MFMA 128x128 (unchanged from R3). Attention decode-only at t=T-1.

#define BT 16384
#define TT 512
#define BB 32
#define VV 16
#define DD 256

typedef unsigned short ushort;
typedef unsigned int uint;
typedef __attribute__((ext_vector_type(8))) short short8;
typedef __attribute__((ext_vector_type(8))) unsigned short ushort8v;
typedef __attribute__((ext_vector_type(4))) float floatx4;
typedef __attribute__((ext_vector_type(2))) _Float16 half2v;

union HCV { ushort8v u; half2v h[4]; uint4 i4; };
union WCV { uint u; half2v h; };

__device__ __forceinline__ float sigmoidf_(float x) { return 1.f / (1.f + expf(-x)); }
__device__ __forceinline__ float eluf_(float x)     { return x > 0.f ? x : expm1f(x); }
__device__ __forceinline__ ushort f2bf(float f) {
  unsigned int u = __float_as_uint(f);
  unsigned int r = u + 0x7fffu + ((u >> 16) & 1u);
  return (ushort)(r >> 16);
}
__device__ __forceinline__ float bf2f(ushort b) { return __uint_as_float(((unsigned int)b) << 16); }

// block-wide sum over 256 threads via wave shuffles + 4-slot LDS
__device__ __forceinline__ float bsum256(float v, float* red4) {
  #pragma unroll
  for (int m = 32; m > 0; m >>= 1) v += __shfl_xor(v, m, 64);
  int w = threadIdx.x >> 6;
  if ((threadIdx.x & 63) == 0) red4[w] = v;
  __syncthreads();
  float r = red4[0] + red4[1] + red4[2] + red4[3];
  __syncthreads();
  return r;
}

__device__ __forceinline__ float block_sum256(float v, float* red) {
  int j = threadIdx.x;
  red[j] = v; __syncthreads();
  #pragma unroll
  for (int st = 128; st > 0; st >>= 1) {
    if (j < st) red[j] += red[j + st];
    __syncthreads();
  }
  float r = red[0];
  __syncthreads();
  return r;
}

// ---------------- weight prep ----------------
// transpose-convert: src fp32 [K,N] -> dst bf16 [N,K]; batched via z
__global__ void wtT_k(const float* __restrict__ src, ushort* __restrict__ dst,
                      int K, int N, long sStride, long dStride) {
  int b = blockIdx.z;
  src += (size_t)b * sStride; dst += (size_t)b * dStride;
  __shared__ float t[32][33];
  int k0 = blockIdx.y * 32, n0 = blockIdx.x * 32;
  int tx = threadIdx.x & 31, ty = threadIdx.x >> 5;
  #pragma unroll
  for (int i = 0; i < 32; i += 8) {
    int k = k0 + ty + i, n = n0 + tx;
    t[ty + i][tx] = (k < K && n < N) ? src[(size_t)k * N + n] : 0.f;
  }
  __syncthreads();
  #pragma unroll
  for (int i = 0; i < 32; i += 8) {
    int n = n0 + ty + i, k = k0 + tx;
    if (n < N && k < K) dst[(size_t)n * K + k] = f2bf(t[tx][ty + i]);
  }
}

// elementwise fp32 -> bf16
__global__ void cvt_k(const float* __restrict__ src, ushort* __restrict__ dst, int n) {
  int i = blockIdx.x * 256 + threadIdx.x;
  if (i < n) dst[i] = f2bf(src[i]);
}

// pack whh fp32 [2][1024][256] -> per-layer tiered fp16-pair layout (uint each):
//   k2 in [0,72):   REG tier   at  k2*1024 + j
//   k2 in [72,128): STREAM tier at 73728 + (((k2-72)>>2)*1024 + j)*4 + ((k2-72)&3)
// layer stride 131072 uints.
__global__ void whh_pack_k(const float* __restrict__ whh, uint* __restrict__ dst) {
  int gid = blockIdx.x * 256 + threadIdx.x;     // 2*131072 total
  int layer = gid >> 17;
  int rem = gid & 131071;
  int k2 = rem >> 10, j = rem & 1023;
  const float* src = whh + (size_t)layer * 262144 + (size_t)j * 256 + 2 * k2;
  _Float16 lo = (_Float16)src[0], hi = (_Float16)src[1];
  uint val = (uint)(*(ushort*)&lo) | ((uint)(*(ushort*)&hi) << 16);
  uint* d = dst + (size_t)layer * 131072;
  if (k2 < 72) d[k2 * 1024 + j] = val;
  else { int q = k2 - 72; d[73728 + (((q >> 2) * 1024 + j) << 2) + (q & 3)] = val; }
}

// ---------------- bf16 MFMA GEMM (unchanged from R3) ----------------
template<int ADT, int ACT, int CDT>
__global__ __launch_bounds__(256) void mgemm_k(
    const void* __restrict__ Aall, int lda, long aStride,
    const ushort* __restrict__ Ball, long bStride,
    const float* __restrict__ biasAll, long biasStride,
    void* __restrict__ Call, int ldc, long cStride,
    int K, int Nvalid,
    const float* __restrict__ embw, const float* __restrict__ embb, int xbase) {
  int z = blockIdx.z;
  const ushort* B = Ball + (size_t)z * bStride;
  const float* bias = biasAll ? biasAll + (size_t)z * biasStride : nullptr;
  int m0 = blockIdx.y * 128, n0 = blockIdx.x * 128;
  __shared__ ushort As[128][40];
  __shared__ ushort Bs[128][40];
  int tid = threadIdx.x;
  int r = tid >> 1, half = tid & 1;
  int wave = tid >> 6, lane = tid & 63;
  int wm = (wave >> 1) * 64, wn = (wave & 1) * 64;
  int lm = lane & 15, lq = lane >> 4;
  floatx4 acc[4][4];
  #pragma unroll
  for (int i = 0; i < 4; i++)
    #pragma unroll
    for (int j = 0; j < 4; j++) acc[i][j] = (floatx4)0.f;

  for (int k0 = 0; k0 < K; k0 += 32) {
    int kk = k0 + half * 16;
    {
      int gm = m0 + r;
      ushort tmp[16];
      if (ADT == 0) {
        const float* Af = (const float*)Aall + (size_t)z * aStride + (size_t)gm * lda + kk;
        #pragma unroll
        for (int q = 0; q < 4; q++) {
          float4 f = ((const float4*)Af)[q];
          tmp[q * 4 + 0] = f2bf(f.x); tmp[q * 4 + 1] = f2bf(f.y);
          tmp[q * 4 + 2] = f2bf(f.z); tmp[q * 4 + 3] = f2bf(f.w);
        }
      } else if (ADT == 1) {
        const ushort* Ab = (const ushort*)Aall + (size_t)z * aStride + (size_t)gm * lda + kk;
        *(ushort8v*)&tmp[0] = *(const ushort8v*)(Ab);
        *(ushort8v*)&tmp[8] = *(const ushort8v*)(Ab + 8);
      } else {
        const float* xp = (const float*)Aall;
        float xv = xp[(size_t)gm * lda + xbase + z + (kk >> 8)];
        const float4* ew = (const float4*)(embw + (size_t)z * 256 + kk);
        const float4* eb = (const float4*)(embb + (size_t)z * 256 + kk);
        #pragma unroll
        for (int q = 0; q < 4; q++) {
          float4 w4 = ew[q], b4 = eb[q];
          tmp[q * 4 + 0] = f2bf(xv * w4.x + b4.x); tmp[q * 4 + 1] = f2bf(xv * w4.y + b4.y);
          tmp[q * 4 + 2] = f2bf(xv * w4.z + b4.z); tmp[q * 4 + 3] = f2bf(xv * w4.w + b4.w);
        }
      }
      *(ushort8v*)&As[r][half * 16]     = *(ushort8v*)&tmp[0];
      *(ushort8v*)&As[r][half * 16 + 8] = *(ushort8v*)&tmp[8];
    }
    {
      int gn = n0 + r;
      ushort tmp[16];
      if (gn < Nvalid) {
        const ushort* Bp = B + (size_t)gn * K + kk;
        *(ushort8v*)&tmp[0] = *(const ushort8v*)(Bp);
        *(ushort8v*)&tmp[8] = *(const ushort8v*)(Bp + 8);
      } else {
        #pragma unroll
        for (int q = 0; q < 16; q++) tmp[q] = 0;
      }
      *(ushort8v*)&Bs[r][half * 16]     = *(ushort8v*)&tmp[0];
      *(ushort8v*)&Bs[r][half * 16 + 8] = *(ushort8v*)&tmp[8];
    }
    __syncthreads();
    short8 fa[4], fb[4];
    #pragma unroll
    for (int i = 0; i < 4; i++) fa[i] = *(const short8*)&As[wm + i * 16 + lm][lq * 8];
    #pragma unroll
    for (int j = 0; j < 4; j++) fb[j] = *(const short8*)&Bs[wn + j * 16 + lm][lq * 8];
    #pragma unroll
    for (int i = 0; i < 4; i++)
      #pragma unroll
      for (int j = 0; j < 4; j++)
        acc[i][j] = __builtin_amdgcn_mfma_f32_16x16x32_bf16(fa[i], fb[j], acc[i][j], 0, 0, 0);
    __syncthreads();
  }
  #pragma unroll
  for (int j = 0; j < 4; j++) {
    int gn = n0 + wn + j * 16 + lm;
    if (gn >= Nvalid) continue;
    float bv = bias ? bias[gn] : 0.f;
    #pragma unroll
    for (int i = 0; i < 4; i++) {
      #pragma unroll
      for (int rg = 0; rg < 4; rg++) {
        int gm = m0 + wm + i * 16 + lq * 4 + rg;
        float v = acc[i][j][rg] + bv;
        if (ACT == 1) v = eluf_(v);
        if (CDT == 0) ((float*)Call + (size_t)z * cStride)[(size_t)gm * ldc + gn] = v;
        else ((ushort*)Call + (size_t)z * cStride)[(size_t)gm * ldc + gn] = f2bf(v);
      }
    }
  }
}

// ---------------- selection GRN finish ----------------
__global__ void sel_finish_k(const float* __restrict__ selG, const float* __restrict__ selSkip,
                             const float* __restrict__ lng, const float* __restrict__ lnb,
                             float* __restrict__ wout, int M) {
  int m = blockIdx.x * 256 + threadIdx.x;
  if (m >= M) return;
  float s[16];
  float mean = 0.f;
  #pragma unroll
  for (int i = 0; i < 16; i++) {
    float h1 = selG[m * 32 + i], h2 = selG[m * 32 + 16 + i];
    float val = h1 * sigmoidf_(h2) + selSkip[m * 16 + i];
    s[i] = val; mean += val;
  }
  mean *= (1.f / 16.f);
  float var = 0.f;
  #pragma unroll
  for (int i = 0; i < 16; i++) { float d = s[i] - mean; var += d * d; }
  var *= (1.f / 16.f);
  float inv = rsqrtf(var + 1e-5f);
  float mx = -1e30f;
  #pragma unroll
  for (int i = 0; i < 16; i++) { s[i] = (s[i] - mean) * inv * lng[i] + lnb[i]; mx = fmaxf(mx, s[i]); }
  float sum = 0.f;
  #pragma unroll
  for (int i = 0; i < 16; i++) { s[i] = expf(s[i] - mx); sum += s[i]; }
  float isum = 1.f / sum;
  #pragma unroll
  for (int i = 0; i < 16; i++) wout[m * 16 + i] = s[i] * isum;
}

// ---------------- var-GRN epilogue, 4 variables per launch ----------------
__global__ __launch_bounds__(256) void var_epi4_k(
    const ushort* __restrict__ G16,
    const float* __restrict__ x, int vbase,
    const float* __restrict__ embw, const float* __restrict__ embb,
    const float* __restrict__ lng, const float* __restrict__ lnb,
    const float* __restrict__ wts, float* __restrict__ vsn, int first) {
  int m = blockIdx.x, j = threadIdx.x;
  __shared__ float red4[4];
  float accv = 0.f;
  #pragma unroll
  for (int z = 0; z < 4; z++) {
    int v = vbase + z;
    const ushort* Gp = G16 + ((size_t)z * BT + m) * 512;
    float g1 = bf2f(Gp[j]), g2 = bf2f(Gp[256 + j]);
    float e = x[m * VV + v] * embw[z * 256 + j] + embb[z * 256 + j];
    float s = g1 * sigmoidf_(g2) + e;
    float mean = bsum256(s, red4) * (1.f / 256.f);
    float d = s - mean;
    float var = bsum256(d * d, red4) * (1.f / 256.f);
    float o = d * rsqrtf(var + 1e-5f) * lng[z * 256 + j] + lnb[z * 256 + j];
    accv += wts[m * VV + v] * o;
  }
  size_t oi = (size_t)m * 256 + j;
  if (first) vsn[oi] = accv; else vsn[oi] += accv;
}

// ---------------- generic GRN epilogue ----------------
__global__ __launch_bounds__(256) void grn_epi_k(
    const ushort* __restrict__ G, const float* __restrict__ skip,
    const float* __restrict__ lng, const float* __restrict__ lnb,
    float* __restrict__ out) {
  int m = blockIdx.x, j = threadIdx.x;
  __shared__ float red4[4];
  float g1 = bf2f(G[(size_t)m * 512 + j]), g2 = bf2f(G[(size_t)m * 512 + 256 + j]);
  float s = g1 * sigmoidf_(g2) + skip[(size_t)m * 256 + j];
  float mean = bsum256(s, red4) * (1.f / 256.f);
  float d = s - mean;
  float var = bsum256(d * d, red4) * (1.f / 256.f);
  out[(size_t)m * 256 + j] = d * rsqrtf(var + 1e-5f) * lng[j] + lnb[j];
}

// ---------------- elementwise ----------------
__global__ void add2_k(const float* __restrict__ a, const float* __restrict__ b,
                       float* __restrict__ c, int n) {
  int i = blockIdx.x * 256 + threadIdx.x;
  if (i < n) c[i] = a[i] + b[i];
}

// ---------------- LSTM recurrence ----------------
// 1 block/batch, 1024 threads (1/gate-row). Weights: fp16 pairs as uint;
// 72 dwords pinned in VGPRs, 56 dwords (14 uint4 groups) streamed coalesced per
// step. h-state fp16 in LDS, broadcast b128 reads. xi prefetched 1 step ahead.
__global__ __launch_bounds__(1024, 4) void lstm_recur_k(
    const float* __restrict__ xi,     // [B,T,1024] = xW^T + bih + bhh
    const uint* __restrict__ wpk,     // packed layer (131072 uints)
    float* __restrict__ hout,         // [B,T,256]
    int T) {
  int b = blockIdx.x;
  int j = threadIdx.x;
  __shared__ __align__(16) ushort hp16[256];
  __shared__ float gates[1024];
  float c = 0.f;
  if (j < 256) hp16[j] = 0;
  uint wreg[72];
  #pragma unroll
  for (int k = 0; k < 72; k++) wreg[k] = wpk[k * 1024 + j];
  const uint4* stp = (const uint4*)(wpk + 73728) + j;
  const float* xr = xi + (size_t)b * T * 1024 + j;
  float xc = xr[0];
  __syncthreads();
  for (int t = 0; t < T; t++) {
    float xn = (t + 1 < T) ? xr[(size_t)(t + 1) * 1024] : 0.f;
    const ushort8v* hp8 = (const ushort8v*)hp16;
    float a0 = xc, a1 = 0.f, a2 = 0.f, a3 = 0.f;
    // REG tier: h-pair chunks 0..71 (groups 0..17)
    #pragma unroll
    for (int g = 0; g < 18; g++) {
      HCV ch; ch.u = hp8[g];
      WCV w0, w1, w2, w3;
      w0.u = wreg[4 * g + 0]; w1.u = wreg[4 * g + 1];
      w2.u = wreg[4 * g + 2]; w3.u = wreg[4 * g + 3];
      a0 = __builtin_amdgcn_fdot2(w0.h, ch.h[0], a0, false);
      a1 = __builtin_amdgcn_fdot2(w1.h, ch.h[1], a1, false);
      a2 = __builtin_amdgcn_fdot2(w2.h, ch.h[2], a2, false);
      a3 = __builtin_amdgcn_fdot2(w3.h, ch.h[3], a3, false);
    }
    // STREAM tier: chunks 72..127 (groups 18..31), coalesced uint4 loads
    #pragma unroll
    for (int g = 0; g < 14; g++) {
      HCV wv; wv.i4 = stp[g * 1024];
      HCV ch; ch.u = hp8[18 + g];
      a0 = __builtin_amdgcn_fdot2(wv.h[0], ch.h[0], a0, false);
      a1 = __builtin_amdgcn_fdot2(wv.h[1], ch.h[1], a1, false);
      a2 = __builtin_amdgcn_fdot2(wv.h[2], ch.h[2], a2, false);
      a3 = __builtin_amdgcn_fdot2(wv.h[3], ch.h[3], a3, false);
    }
    gates[j] = (a0 + a1) + (a2 + a3);
    __syncthreads();
    if (j < 256) {
      float i_ = gates[j], f_ = gates[256 + j], g_ = gates[512 + j], o_ = gates[768 + j];
      c = sigmoidf_(f_) * c + sigmoidf_(i_) * tanhf(g_);
      float h = sigmoidf_(o_) * tanhf(c);
      _Float16 hh = (_Float16)h;
      hp16[j] = *(ushort*)&hh;
      hout[((size_t)(b * T + t)) * 256 + j] = h;
    }
    xc = xn;
    __syncthreads();
  }
}

// ---------------- attention, decode-style (only query t = T-1) ----------------
__global__ __launch_bounds__(256) void attn_decode_k(const float* __restrict__ qkv,
                                                     float* __restrict__ o, int T) {
  int bh = blockIdx.x; int b = bh >> 2, h = bh & 3;
  int tid = threadIdx.x;
  __shared__ float q[64];
  __shared__ float p[512];
  __shared__ float red[256];
  if (tid < 64) q[tid] = qkv[((size_t)(b * T + T - 1)) * 768 + h * 64 + tid];
  __syncthreads();
  for (int t = tid; t < 512; t += 256) {
    const float* kv = qkv + ((size_t)(b * T + t)) * 768 + 256 + h * 64;
    float s = 0.f;
    #pragma unroll 16
    for (int d = 0; d < 64; d++) s += q[d] * kv[d];
    p[t] = s * 0.125f;
  }
  __syncthreads();
  red[tid] = fmaxf(p[tid], p[tid + 256]); __syncthreads();
  for (int st = 128; st > 0; st >>= 1) { if (tid < st) red[tid] = fmaxf(red[tid], red[tid + st]); __syncthreads(); }
  float mx = red[0]; __syncthreads();
  float e0 = expf(p[tid] - mx), e1 = expf(p[tid + 256] - mx);
  red[tid] = e0 + e1; __syncthreads();
  for (int st = 128; st > 0; st >>= 1) { if (tid < st) red[tid] += red[tid + st]; __syncthreads(); }
  float inv = 1.f / red[0];
  __syncthreads();
  p[tid] = e0; p[tid + 256] = e1;
  __syncthreads();
  int d = tid & 63, grp = tid >> 6;
  float acc = 0.f;
  for (int t = grp * 128; t < grp * 128 + 128; t++)
    acc += p[t] * qkv[((size_t)(b * T + t)) * 768 + 512 + h * 64 + d];
  red[tid] = acc; __syncthreads();
  if (grp == 0)
    o[(b * 4 + h) * 64 + d] = (red[tid] + red[tid + 64] + red[tid + 128] + red[tid + 192]) * inv;
}

// ---------------- attn out-proj + residual + LN (only t=T-1) ----------------
__global__ __launch_bounds__(256) void attn_proj_ln_k(
    const float* __restrict__ attnO, const float* __restrict__ W, const float* __restrict__ bias,
    const float* __restrict__ lstmF, const float* __restrict__ lng, const float* __restrict__ lnb,
    float* __restrict__ out, int T) {
  int bb = blockIdx.x, j = threadIdx.x;
  __shared__ float a[256];
  __shared__ float red[256];
  a[j] = attnO[bb * 256 + j];
  __syncthreads();
  float acc = bias[j];
  const float* wr = W + (size_t)j * 256;
  #pragma unroll 8
  for (int k = 0; k < 256; k += 4) {
    float4 w4 = *(const float4*)(wr + k);
    acc += a[k] * w4.x + a[k + 1] * w4.y + a[k + 2] * w4.z + a[k + 3] * w4.w;
  }
  float s = acc + lstmF[((size_t)(bb * T + T - 1)) * 256 + j];
  float mean = block_sum256(s, red) * (1.f / 256.f);
  float d = s - mean;
  float var = block_sum256(d * d, red) * (1.f / 256.f);
  out[bb * 256 + j] = d * rsqrtf(var + 1e-5f) * lng[j] + lnb[j];
}

// ---------------- final two GRNs (pa then fg), only t=T-1 ----------------
__global__ __launch_bounds__(256) void final_grns_k(
    const float* __restrict__ ain,
    const float* __restrict__ paw1, const float* __restrict__ pab1,
    const float* __restrict__ paw2, const float* __restrict__ pab2,
    const float* __restrict__ palg, const float* __restrict__ palb,
    const float* __restrict__ fgw1, const float* __restrict__ fgb1,
    const float* __restrict__ fgw2, const float* __restrict__ fgb2,
    const float* __restrict__ fglg, const float* __restrict__ fglb,
    float* __restrict__ out) {
  int bb = blockIdx.x, j = threadIdx.x;
  __shared__ float a[256];
  __shared__ float hbuf[1024];
  __shared__ float red[256];
  a[j] = ain[bb * 256 + j];
  __syncthreads();
  float acc = pab1[j];
  for (int k = 0; k < 256; k++) acc += a[k] * paw1[k * 256 + j];
  hbuf[j] = eluf_(acc);
  __syncthreads();
  float g1 = pab2[j], g2 = pab2[256 + j];
  for (int k = 0; k < 256; k++) { float hv = hbuf[k]; g1 += hv * paw2[k * 512 + j]; g2 += hv * paw2[k * 512 + 256 + j]; }
  float s = g1 * sigmoidf_(g2) + a[j];
  float mean = block_sum256(s, red) * (1.f / 256.f);
  float d = s - mean;
  float var = block_sum256(d * d, red) * (1.f / 256.f);
  float af = d * rsqrtf(var + 1e-5f) * palg[j] + palb[j];
  __syncthreads();
  a[j] = af;
  __syncthreads();
  float hh[4];
  #pragma unroll
  for (int q = 0; q < 4; q++) {
    int jj = j + q * 256;
    float ac = fgb1[jj];
    for (int k = 0; k < 256; k++) ac += a[k] * fgw1[k * 1024 + jj];
    hh[q] = eluf_(ac);
  }
  __syncthreads();
  #pragma unroll
  for (int q = 0; q < 4; q++) hbuf[j + q * 256] = hh[q];
  __syncthreads();
  float G1 = fgb2[j], G2 = fgb2[256 + j];
  for (int k = 0; k < 1024; k++) { float hv = hbuf[k]; G1 += hv * fgw2[k * 512 + j]; G2 += hv * fgw2[k * 512 + 256 + j]; }
  float s2 = G1 * sigmoidf_(G2) + a[j];
  mean = block_sum256(s2, red) * (1.f / 256.f);
  d = s2 - mean;
  var = block_sum256(d * d, red) * (1.f / 256.f);
  out[bb * 256 + j] = d * rsqrtf(var + 1e-5f) * fglg[j] + fglb[j];
}

extern "C" void kernel_launch(void* const* d_in, const int* in_sizes, int n_in,
                              void* d_out, int out_size, void* d_ws, size_t ws_size,
                              hipStream_t stream) {
  const float* x          = (const float*)d_in[0];
  const float* emb_w      = (const float*)d_in[1];
  const float* emb_b      = (const float*)d_in[2];
  const float* vg_fc1_w   = (const float*)d_in[3];
  const float* vg_fc1_b   = (const float*)d_in[4];
  const float* vg_fc2_w   = (const float*)d_in[5];
  const float* vg_fc2_b   = (const float*)d_in[6];
  const float* vg_ln_g    = (const float*)d_in[7];
  const float* vg_ln_b    = (const float*)d_in[8];
  const float* sel_fc1_w  = (const float*)d_in[9];
  const float* sel_fc1_b  = (const float*)d_in[10];
  const float* sel_fc2_w  = (const float*)d_in[11];
  const float* sel_fc2_b  = (const float*)d_in[12];
  const float* sel_skip_w = (const float*)d_in[13];
  const float* sel_skip_b = (const float*)d_in[14];
  const float* sel_ln_g   = (const float*)d_in[15];
  const float* sel_ln_b   = (const float*)d_in[16];
  const float* lstm_wih   = (const float*)d_in[17];
  const float* lstm_whh   = (const float*)d_in[18];
  const float* lstm_bih   = (const float*)d_in[19];
  const float* lstm_bhh   = (const float*)d_in[20];
  const float* pl_fc1_w   = (const float*)d_in[21];
  const float* pl_fc1_b   = (const float*)d_in[22];
  const float* pl_fc2_w   = (const float*)d_in[23];
  const float* pl_fc2_b   = (const float*)d_in[24];
  const float* pl_ln_g    = (const float*)d_in[25];
  const float* pl_ln_b    = (const float*)d_in[26];
  const float* attn_in_w  = (const float*)d_in[27];
  const float* attn_in_b  = (const float*)d_in[28];
  const float* attn_out_w = (const float*)d_in[29];
  const float* attn_out_b = (const float*)d_in[30];
  const float* attn_ln_g  = (const float*)d_in[31];
  const float* attn_ln_b  = (const float*)d_in[32];
  const float* pa_fc1_w   = (const float*)d_in[33];
  const float* pa_fc1_b   = (const float*)d_in[34];
  const float* pa_fc2_w   = (const float*)d_in[35];
  const float* pa_fc2_b   = (const float*)d_in[36];
  const float* pa_ln_g    = (const float*)d_in[37];
  const float* pa_ln_b    = (const float*)d_in[38];
  const float* fg_fc1_w   = (const float*)d_in[39];
  const float* fg_fc1_b   = (const float*)d_in[40];
  const float* fg_fc2_w   = (const float*)d_in[41];
  const float* fg_fc2_b   = (const float*)d_in[42];
  const float* fg_ln_g    = (const float*)d_in[43];
  const float* fg_ln_b    = (const float*)d_in[44];
  (void)in_sizes; (void)n_in; (void)out_size; (void)ws_size;

  float* out     = (float*)d_out;
  float* out_wts = out + BB * DD;

  // ---- workspace layout ----
  char* p = (char*)d_ws;
  ushort* wt_sel_fc1  = (ushort*)p;                 p += 1048576 * 2;
  ushort* wt_sel_skip = (ushort*)p;                 p += 65536 * 2;
  ushort* wt_sel_fc2  = (ushort*)p;                 p += 8192 * 2;
  ushort* wt_var_fc1  = (ushort*)p;                 p += 1048576 * 2;
  ushort* wt_var_fc2  = (ushort*)p;                 p += 2097152 * 2;
  ushort* wt_wih      = (ushort*)p;                 p += 524288 * 2;
  uint*   wt_whh_pk   = (uint*)p;                   p += 262144 * 4;   // packed fp16-pair whh
  ushort* wt_pl_fc1   = (ushort*)p;                 p += 65536 * 2;
  ushort* wt_pl_fc2   = (ushort*)p;                 p += 131072 * 2;
  ushort* wt_attn     = (ushort*)p;                 p += 196608 * 2;
  ushort* selH        = (ushort*)p;                 p += (size_t)BT * 256 * 2;
  float*  selSkip     = (float*)p;                  p += (size_t)BT * 16 * 4;
  float*  selG        = (float*)p;                  p += (size_t)BT * 32 * 4;
  float*  vsn         = (float*)p;                  p += (size_t)BT * 256 * 4;
  float*  hseq1       = (float*)p;                  p += (size_t)BT * 256 * 4;
  float*  hseq2       = (float*)p;                  p += (size_t)BT * 256 * 4;
  float*  cbias       = (float*)p;                  p += 4096 * 4;
  float*  attnO       = (float*)p;                  p += 8192 * 4;
  float*  attnLN      = (float*)p;                  p += 8192 * 4;
  char*   R           = p;
  ushort* bufA16 = (ushort*)R;
  ushort* bufG16 = (ushort*)(R + (((size_t)32) << 20));
  float*  xi     = (float*)R;
  float*  plA    = (float*)R;
  ushort* plH    = (ushort*)(R + (((size_t)16) << 20));
  ushort* plG    = (ushort*)(R + (((size_t)24) << 20));
  float*  lstmF  = (float*)(R + (((size_t)48) << 20));
  float*  qkv    = (float*)R;

  dim3 blk(256);

  // ---- weight prep ----
  wtT_k<<<dim3(8, 128, 1),  blk, 0, stream>>>(sel_fc1_w,  wt_sel_fc1,  4096, 256, 0, 0);
  wtT_k<<<dim3(1, 128, 1),  blk, 0, stream>>>(sel_skip_w, wt_sel_skip, 4096, 16,  0, 0);
  wtT_k<<<dim3(1, 8, 1),    blk, 0, stream>>>(sel_fc2_w,  wt_sel_fc2,  256,  32,  0, 0);
  wtT_k<<<dim3(8, 8, 16),   blk, 0, stream>>>(vg_fc1_w,   wt_var_fc1,  256,  256, 65536, 65536);
  wtT_k<<<dim3(16, 8, 16),  blk, 0, stream>>>(vg_fc2_w,   wt_var_fc2,  256,  512, 131072, 131072);
  wtT_k<<<dim3(8, 8, 1),    blk, 0, stream>>>(pl_fc1_w,   wt_pl_fc1,   256,  256, 0, 0);
  wtT_k<<<dim3(16, 8, 1),   blk, 0, stream>>>(pl_fc2_w,   wt_pl_fc2,   256,  512, 0, 0);
  cvt_k<<<2048, blk, 0, stream>>>(lstm_wih,  wt_wih, 524288);
  whh_pack_k<<<1024, blk, 0, stream>>>(lstm_whh, wt_whh_pk);
  cvt_k<<<768,  blk, 0, stream>>>(attn_in_w, wt_attn, 196608);
  add2_k<<<8, blk, 0, stream>>>(lstm_bih, lstm_bhh, cbias, 4096);

  // ---- selection GRN -> softmax weights ----
  mgemm_k<2,1,1><<<dim3(2, 128, 1), blk, 0, stream>>>(x, 16, 0, wt_sel_fc1, 0, sel_fc1_b, 0,
      selH, 256, 0, 4096, 256, emb_w, emb_b, 0);
  mgemm_k<2,0,0><<<dim3(1, 128, 1), blk, 0, stream>>>(x, 16, 0, wt_sel_skip, 0, sel_skip_b, 0,
      selSkip, 16, 0, 4096, 16, emb_w, emb_b, 0);
  mgemm_k<1,0,0><<<dim3(1, 128, 1), blk, 0, stream>>>(selH, 256, 0, wt_sel_fc2, 0, sel_fc2_b, 0,
      selG, 32, 0, 256, 32, nullptr, nullptr, 0);
  sel_finish_k<<<64, blk, 0, stream>>>(selG, selSkip, sel_ln_g, sel_ln_b, out_wts, BT);

  // ---- per-variable GRNs (groups of 4) + weighted sum into vsn ----
  for (int g = 0; g < 4; g++) {
    mgemm_k<2,1,1><<<dim3(2, 128, 4), blk, 0, stream>>>(x, 16, 0,
        wt_var_fc1 + (size_t)g * 4 * 65536, 65536, vg_fc1_b + g * 1024, 256,
        bufA16, 256, (long)BT * 256, 256, 256, emb_w + g * 1024, emb_b + g * 1024, g * 4);
    mgemm_k<1,0,1><<<dim3(4, 128, 4), blk, 0, stream>>>(bufA16, 256, (long)BT * 256,
        wt_var_fc2 + (size_t)g * 4 * 131072, 131072, vg_fc2_b + g * 2048, 512,
        bufG16, 512, (long)BT * 512, 256, 512, nullptr, nullptr, 0);
    var_epi4_k<<<BT, blk, 0, stream>>>(bufG16, x, g * 4, emb_w + g * 1024, emb_b + g * 1024,
        vg_ln_g + g * 1024, vg_ln_b + g * 1024, out_wts, vsn, g == 0 ? 1 : 0);
  }

  // ---- LSTM (2 layers) ----
  mgemm_k<0,0,0><<<dim3(8, 128, 1), blk, 0, stream>>>(vsn, 256, 0, wt_wih, 0, cbias, 0,
      xi, 1024, 0, 256, 1024, nullptr, nullptr, 0);
  lstm_recur_k<<<BB, 1024, 0, stream>>>(xi, wt_whh_pk, hseq1, TT);
  mgemm_k<0,0,0><<<dim3(8, 128, 1), blk, 0, stream>>>(hseq1, 256, 0, wt_wih + 1024 * 256, 0,
      cbias + 1024, 0, xi, 1024, 0, 256, 1024, nullptr, nullptr, 0);
  lstm_recur_k<<<BB, 1024, 0, stream>>>(xi, wt_whh_pk + 131072, hseq2, TT);

  // ---- post-LSTM gated residual (pl GRN) ----
  add2_k<<<BT, blk, 0, stream>>>(hseq2, vsn, plA, BT * 256);
  mgemm_k<0,1,1><<<dim3(2, 128, 1), blk, 0, stream>>>(plA, 256, 0, wt_pl_fc1, 0, pl_fc1_b, 0,
      plH, 256, 0, 256, 256, nullptr, nullptr, 0);
  mgemm_k<1,0,1><<<dim3(4, 128, 1), blk, 0, stream>>>(plH, 256, 0, wt_pl_fc2, 0, pl_fc2_b, 0,
      plG, 512, 0, 256, 512, nullptr, nullptr, 0);
  grn_epi_k<<<BT, blk, 0, stream>>>(plG, plA, pl_ln_g, pl_ln_b, lstmF);

  // ---- attention (decode at t=T-1 only) ----
  mgemm_k<0,0,0><<<dim3(6, 128, 1), blk, 0, stream>>>(lstmF, 256, 0, wt_attn, 0, attn_in_b, 0,
      qkv, 768, 0, 256, 768, nullptr, nullptr, 0);
  attn_decode_k<<<BB * 4, blk, 0, stream>>>(qkv, attnO, TT);
  attn_proj_ln_k<<<BB, blk, 0, stream>>>(attnO, attn_out_w, attn_out_b, lstmF,
                                         attn_ln_g, attn_ln_b, attnLN, TT);

  // ---- pa GRN + fg GRN (t=T-1 only) -> first output slice ----
  final_grns_k<<<BB, blk, 0, stream>>>(attnLN,
      pa_fc1_w, pa_fc1_b, pa_fc2_w, pa_fc2_b, pa_ln_g, pa_ln_b,
      fg_fc1_w, fg_fc1_b, fg_fc2_w, fg_fc2_b, fg_ln_g, fg_ln_b,
      out);
}

// Round 5
// 3822.626 us; speedup vs baseline: 8.9309x; 1.2302x over previous
//
#include <hip/hip_runtime.h>
#include <hip/hip_bf16.h>
#include <hip/hip_fp8.h>
#include <math.h>

// TFT: B=32, T=512, V=16, D=256, H=4, L=2.  BT = 16384.
// Round 5: LSTM recurrence via fp8 MFMA with whh fully register-resident.
//  - whh packed offline to e4m3 (scale x64) in MFMA B-fragment order (256 KB/layer)
//  - 16 blocks x 256 threads (2 batches/block), launch_bounds(256,1) -> 512-reg cap
//  - per wave: 128 long B-frags pinned in regs; per step: 8 LDS A-frag reads (h fp8,
//    scale x16), 128 mfma_f32_16x16x32_fp8_fp8, gate phase with xi prefetch
// GEMMs: bf16 MFMA 128x128 (unchanged). Attention decode-only at t=T-1.

#define BT 16384
#define TT 512
#define BB 32
#define VV 16
#define DD 256

typedef unsigned short ushort;
typedef unsigned int uint;
typedef unsigned long ulong_;
typedef __attribute__((ext_vector_type(8))) short short8;
typedef __attribute__((ext_vector_type(8))) unsigned short ushort8v;
typedef __attribute__((ext_vector_type(4))) float floatx4;

__device__ __forceinline__ float sigmoidf_(float x) { return 1.f / (1.f + expf(-x)); }
__device__ __forceinline__ float eluf_(float x)     { return x > 0.f ? x : expm1f(x); }
__device__ __forceinline__ ushort f2bf(float f) {
  unsigned int u = __float_as_uint(f);
  unsigned int r = u + 0x7fffu + ((u >> 16) & 1u);
  return (ushort)(r >> 16);
}
__device__ __forceinline__ float bf2f(ushort b) { return __uint_as_float(((unsigned int)b) << 16); }

// block-wide sum over 256 threads via wave shuffles + 4-slot LDS
__device__ __forceinline__ float bsum256(float v, float* red4) {
  #pragma unroll
  for (int m = 32; m > 0; m >>= 1) v += __shfl_xor(v, m, 64);
  int w = threadIdx.x >> 6;
  if ((threadIdx.x & 63) == 0) red4[w] = v;
  __syncthreads();
  float r = red4[0] + red4[1] + red4[2] + red4[3];
  __syncthreads();
  return r;
}

__device__ __forceinline__ float block_sum256(float v, float* red) {
  int j = threadIdx.x;
  red[j] = v; __syncthreads();
  #pragma unroll
  for (int st = 128; st > 0; st >>= 1) {
    if (j < st) red[j] += red[j + st];
    __syncthreads();
  }
  float r = red[0];
  __syncthreads();
  return r;
}

// ---------------- weight prep ----------------
// transpose-convert: src fp32 [K,N] -> dst bf16 [N,K]; batched via z
__global__ void wtT_k(const float* __restrict__ src, ushort* __restrict__ dst,
                      int K, int N, long sStride, long dStride) {
  int b = blockIdx.z;
  src += (size_t)b * sStride; dst += (size_t)b * dStride;
  __shared__ float t[32][33];
  int k0 = blockIdx.y * 32, n0 = blockIdx.x * 32;
  int tx = threadIdx.x & 31, ty = threadIdx.x >> 5;
  #pragma unroll
  for (int i = 0; i < 32; i += 8) {
    int k = k0 + ty + i, n = n0 + tx;
    t[ty + i][tx] = (k < K && n < N) ? src[(size_t)k * N + n] : 0.f;
  }
  __syncthreads();
  #pragma unroll
  for (int i = 0; i < 32; i += 8) {
    int n = n0 + ty + i, k = k0 + tx;
    if (n < N && k < K) dst[(size_t)n * K + k] = f2bf(t[tx][ty + i]);
  }
}

// elementwise fp32 -> bf16
__global__ void cvt_k(const float* __restrict__ src, ushort* __restrict__ dst, int n) {
  int i = blockIdx.x * 256 + threadIdx.x;
  if (i < n) dst[i] = f2bf(src[i]);
}

// pack whh fp32 [2][1024][256] -> fp8 e4m3 (x64 scale) in MFMA B-fragment order:
// byte offset = gid*8 where gid = layer*32768 + (nt*8+kt)*64 + lane; each thread
// emits 8 bytes = B[n = nt*16+(lane&15)][k = kt*32+(lane>>4)*8 .. +8].
__global__ void whh_pack8_k(const float* __restrict__ whh, unsigned char* __restrict__ dst) {
  int gid = blockIdx.x * 256 + threadIdx.x;   // 65536 total
  int layer = gid >> 15;
  int rem = gid & 32767;
  int lane = rem & 63;
  int ntkt = rem >> 6;
  int kt = ntkt & 7, nt = ntkt >> 3;
  int n = nt * 16 + (lane & 15);
  int k = kt * 32 + (lane >> 4) * 8;
  const float* src = whh + (size_t)layer * 262144 + (size_t)n * 256 + k;
  ulong_ pack = 0;
  #pragma unroll
  for (int b = 0; b < 8; b++) {
    __hip_fp8_e4m3 q(src[b] * 64.f);
    pack |= ((ulong_)q.__x) << (8 * b);
  }
  *(ulong_*)(dst + (size_t)gid * 8) = pack;
}

// ---------------- bf16 MFMA GEMM (unchanged) ----------------
template<int ADT, int ACT, int CDT>
__global__ __launch_bounds__(256) void mgemm_k(
    const void* __restrict__ Aall, int lda, long aStride,
    const ushort* __restrict__ Ball, long bStride,
    const float* __restrict__ biasAll, long biasStride,
    void* __restrict__ Call, int ldc, long cStride,
    int K, int Nvalid,
    const float* __restrict__ embw, const float* __restrict__ embb, int xbase) {
  int z = blockIdx.z;
  const ushort* B = Ball + (size_t)z * bStride;
  const float* bias = biasAll ? biasAll + (size_t)z * biasStride : nullptr;
  int m0 = blockIdx.y * 128, n0 = blockIdx.x * 128;
  __shared__ ushort As[128][40];
  __shared__ ushort Bs[128][40];
  int tid = threadIdx.x;
  int r = tid >> 1, half = tid & 1;
  int wave = tid >> 6, lane = tid & 63;
  int wm = (wave >> 1) * 64, wn = (wave & 1) * 64;
  int lm = lane & 15, lq = lane >> 4;
  floatx4 acc[4][4];
  #pragma unroll
  for (int i = 0; i < 4; i++)
    #pragma unroll
    for (int j = 0; j < 4; j++) acc[i][j] = (floatx4)0.f;

  for (int k0 = 0; k0 < K; k0 += 32) {
    int kk = k0 + half * 16;
    {
      int gm = m0 + r;
      ushort tmp[16];
      if (ADT == 0) {
        const float* Af = (const float*)Aall + (size_t)z * aStride + (size_t)gm * lda + kk;
        #pragma unroll
        for (int q = 0; q < 4; q++) {
          float4 f = ((const float4*)Af)[q];
          tmp[q * 4 + 0] = f2bf(f.x); tmp[q * 4 + 1] = f2bf(f.y);
          tmp[q * 4 + 2] = f2bf(f.z); tmp[q * 4 + 3] = f2bf(f.w);
        }
      } else if (ADT == 1) {
        const ushort* Ab = (const ushort*)Aall + (size_t)z * aStride + (size_t)gm * lda + kk;
        *(ushort8v*)&tmp[0] = *(const ushort8v*)(Ab);
        *(ushort8v*)&tmp[8] = *(const ushort8v*)(Ab + 8);
      } else {
        const float* xp = (const float*)Aall;
        float xv = xp[(size_t)gm * lda + xbase + z + (kk >> 8)];
        const float4* ew = (const float4*)(embw + (size_t)z * 256 + kk);
        const float4* eb = (const float4*)(embb + (size_t)z * 256 + kk);
        #pragma unroll
        for (int q = 0; q < 4; q++) {
          float4 w4 = ew[q], b4 = eb[q];
          tmp[q * 4 + 0] = f2bf(xv * w4.x + b4.x); tmp[q * 4 + 1] = f2bf(xv * w4.y + b4.y);
          tmp[q * 4 + 2] = f2bf(xv * w4.z + b4.z); tmp[q * 4 + 3] = f2bf(xv * w4.w + b4.w);
        }
      }
      *(ushort8v*)&As[r][half * 16]     = *(ushort8v*)&tmp[0];
      *(ushort8v*)&As[r][half * 16 + 8] = *(ushort8v*)&tmp[8];
    }
    {
      int gn = n0 + r;
      ushort tmp[16];
      if (gn < Nvalid) {
        const ushort* Bp = B + (size_t)gn * K + kk;
        *(ushort8v*)&tmp[0] = *(const ushort8v*)(Bp);
        *(ushort8v*)&tmp[8] = *(const ushort8v*)(Bp + 8);
      } else {
        #pragma unroll
        for (int q = 0; q < 16; q++) tmp[q] = 0;
      }
      *(ushort8v*)&Bs[r][half * 16]     = *(ushort8v*)&tmp[0];
      *(ushort8v*)&Bs[r][half * 16 + 8] = *(ushort8v*)&tmp[8];
    }
    __syncthreads();
    short8 fa[4], fb[4];
    #pragma unroll
    for (int i = 0; i < 4; i++) fa[i] = *(const short8*)&As[wm + i * 16 + lm][lq * 8];
    #pragma unroll
    for (int j = 0; j < 4; j++) fb[j] = *(const short8*)&Bs[wn + j * 16 + lm][lq * 8];
    #pragma unroll
    for (int i = 0; i < 4; i++)
      #pragma unroll
      for (int j = 0; j < 4; j++)
        acc[i][j] = __builtin_amdgcn_mfma_f32_16x16x32_bf16(fa[i], fb[j], acc[i][j], 0, 0, 0);
    __syncthreads();
  }
  #pragma unroll
  for (int j = 0; j < 4; j++) {
    int gn = n0 + wn + j * 16 + lm;
    if (gn >= Nvalid) continue;
    float bv = bias ? bias[gn] : 0.f;
    #pragma unroll
    for (int i = 0; i < 4; i++) {
      #pragma unroll
      for (int rg = 0; rg < 4; rg++) {
        int gm = m0 + wm + i * 16 + lq * 4 + rg;
        float v = acc[i][j][rg] + bv;
        if (ACT == 1) v = eluf_(v);
        if (CDT == 0) ((float*)Call + (size_t)z * cStride)[(size_t)gm * ldc + gn] = v;
        else ((ushort*)Call + (size_t)z * cStride)[(size_t)gm * ldc + gn] = f2bf(v);
      }
    }
  }
}

// ---------------- selection GRN finish ----------------
__global__ void sel_finish_k(const float* __restrict__ selG, const float* __restrict__ selSkip,
                             const float* __restrict__ lng, const float* __restrict__ lnb,
                             float* __restrict__ wout, int M) {
  int m = blockIdx.x * 256 + threadIdx.x;
  if (m >= M) return;
  float s[16];
  float mean = 0.f;
  #pragma unroll
  for (int i = 0; i < 16; i++) {
    float h1 = selG[m * 32 + i], h2 = selG[m * 32 + 16 + i];
    float val = h1 * sigmoidf_(h2) + selSkip[m * 16 + i];
    s[i] = val; mean += val;
  }
  mean *= (1.f / 16.f);
  float var = 0.f;
  #pragma unroll
  for (int i = 0; i < 16; i++) { float d = s[i] - mean; var += d * d; }
  var *= (1.f / 16.f);
  float inv = rsqrtf(var + 1e-5f);
  float mx = -1e30f;
  #pragma unroll
  for (int i = 0; i < 16; i++) { s[i] = (s[i] - mean) * inv * lng[i] + lnb[i]; mx = fmaxf(mx, s[i]); }
  float sum = 0.f;
  #pragma unroll
  for (int i = 0; i < 16; i++) { s[i] = expf(s[i] - mx); sum += s[i]; }
  float isum = 1.f / sum;
  #pragma unroll
  for (int i = 0; i < 16; i++) wout[m * 16 + i] = s[i] * isum;
}

// ---------------- var-GRN epilogue, 4 variables per launch ----------------
__global__ __launch_bounds__(256) void var_epi4_k(
    const ushort* __restrict__ G16,
    const float* __restrict__ x, int vbase,
    const float* __restrict__ embw, const float* __restrict__ embb,
    const float* __restrict__ lng, const float* __restrict__ lnb,
    const float* __restrict__ wts, float* __restrict__ vsn, int first) {
  int m = blockIdx.x, j = threadIdx.x;
  __shared__ float red4[4];
  float accv = 0.f;
  #pragma unroll
  for (int z = 0; z < 4; z++) {
    int v = vbase + z;
    const ushort* Gp = G16 + ((size_t)z * BT + m) * 512;
    float g1 = bf2f(Gp[j]), g2 = bf2f(Gp[256 + j]);
    float e = x[m * VV + v] * embw[z * 256 + j] + embb[z * 256 + j];
    float s = g1 * sigmoidf_(g2) + e;
    float mean = bsum256(s, red4) * (1.f / 256.f);
    float d = s - mean;
    float var = bsum256(d * d, red4) * (1.f / 256.f);
    float o = d * rsqrtf(var + 1e-5f) * lng[z * 256 + j] + lnb[z * 256 + j];
    accv += wts[m * VV + v] * o;
  }
  size_t oi = (size_t)m * 256 + j;
  if (first) vsn[oi] = accv; else vsn[oi] += accv;
}

// ---------------- generic GRN epilogue ----------------
__global__ __launch_bounds__(256) void grn_epi_k(
    const ushort* __restrict__ G, const float* __restrict__ skip,
    const float* __restrict__ lng, const float* __restrict__ lnb,
    float* __restrict__ out) {
  int m = blockIdx.x, j = threadIdx.x;
  __shared__ float red4[4];
  float g1 = bf2f(G[(size_t)m * 512 + j]), g2 = bf2f(G[(size_t)m * 512 + 256 + j]);
  float s = g1 * sigmoidf_(g2) + skip[(size_t)m * 256 + j];
  float mean = bsum256(s, red4) * (1.f / 256.f);
  float d = s - mean;
  float var = bsum256(d * d, red4) * (1.f / 256.f);
  out[(size_t)m * 256 + j] = d * rsqrtf(var + 1e-5f) * lng[j] + lnb[j];
}

// ---------------- elementwise ----------------
__global__ void add2_k(const float* __restrict__ a, const float* __restrict__ b,
                       float* __restrict__ c, int n) {
  int i = blockIdx.x * 256 + threadIdx.x;
  if (i < n) c[i] = a[i] + b[i];
}

// ---------------- LSTM recurrence: fp8 MFMA, weights register-resident ----------------
// 16 blocks (2 batches each) x 256 threads (4 waves, 1 wave/SIMD -> 512-reg cap).
// wave w owns output cols [w*256, w*256+256): 16 N-tiles x 8 K-tiles of B-frags
// pinned in 128 longs. Per step: A-frags from LDS h8 (fp8, x16), 128 MFMAs,
// lanes 0..15 write gate preacts (x1024 scale) to LDS, gate phase on 256 threads.
#define DESC (1.f / 1024.f)
__global__ __launch_bounds__(256, 1) void lstm_recur_k(
    const float* __restrict__ xi,            // [B,T,1024] = xW^T + bih + bhh
    const unsigned char* __restrict__ wpk,   // fp8 frag-packed layer (262144 B)
    float* __restrict__ hout,                // [B,T,256]
    int T) {
  int bb = blockIdx.x;                        // batches 2bb, 2bb+1
  int tid = threadIdx.x;
  int wave = tid >> 6, lane = tid & 63;
  __shared__ __align__(16) unsigned char h8[16 * 256]; // A operand rows (fp8), rows 2..15 zero
  __shared__ __align__(16) float gl[1024 * 4];         // gate preacts [n][m(reg)]
  for (int i = tid; i < 1024; i += 256) ((uint*)h8)[i] = 0;

  long wr[16][8];
  {
    const ulong_* wp = (const ulong_*)wpk;
    #pragma unroll
    for (int nt = 0; nt < 16; nt++)
      #pragma unroll
      for (int kt = 0; kt < 8; kt++)
        wr[nt][kt] = (long)wp[((size_t)((wave * 16 + nt) * 8 + kt)) * 64 + lane];
  }
  float c0 = 0.f, c1 = 0.f;
  const float* xb0 = xi + ((size_t)(2 * bb) * T) * 1024 + tid;
  const float* xb1 = xi + ((size_t)(2 * bb + 1) * T) * 1024 + tid;
  float xq[8], xn[8] = {0.f, 0.f, 0.f, 0.f, 0.f, 0.f, 0.f, 0.f};
  #pragma unroll
  for (int g = 0; g < 4; g++) { xq[g] = xb0[g * 256]; xq[4 + g] = xb1[g * 256]; }
  int arow = (lane & 15) * 256 + (lane >> 4) * 8;
  __syncthreads();

  for (int t = 0; t < T; t++) {
    if (t + 1 < T) {
      #pragma unroll
      for (int g = 0; g < 4; g++) {
        xn[g]     = xb0[(size_t)(t + 1) * 1024 + g * 256];
        xn[4 + g] = xb1[(size_t)(t + 1) * 1024 + g * 256];
      }
    }
    long a[8];
    #pragma unroll
    for (int kt = 0; kt < 8; kt++) a[kt] = *(const long*)(h8 + arow + kt * 32);
    floatx4 acc[16];
    #pragma unroll
    for (int nt = 0; nt < 16; nt++) acc[nt] = (floatx4)0.f;
    #pragma unroll
    for (int kt = 0; kt < 8; kt++)
      #pragma unroll
      for (int nt = 0; nt < 16; nt++)
        acc[nt] = __builtin_amdgcn_mfma_f32_16x16x32_fp8_fp8(a[kt], wr[nt][kt], acc[nt], 0, 0, 0);
    if (lane < 16) {
      #pragma unroll
      for (int nt = 0; nt < 16; nt++) {
        int n = wave * 256 + nt * 16 + lane;
        *(floatx4*)&gl[n * 4] = acc[nt];
      }
    }
    __syncthreads();
    {
      const float4* glv = (const float4*)gl;
      float4 gi = glv[tid], gf = glv[256 + tid], gg = glv[512 + tid], go = glv[768 + tid];
      // batch 0 (C/D row 0 = .x)
      float pi = gi.x * DESC + xq[0], pf = gf.x * DESC + xq[1];
      float pg = gg.x * DESC + xq[2], po = go.x * DESC + xq[3];
      c0 = sigmoidf_(pf) * c0 + sigmoidf_(pi) * tanhf(pg);
      float h0 = sigmoidf_(po) * tanhf(c0);
      // batch 1 (row 1 = .y)
      pi = gi.y * DESC + xq[4]; pf = gf.y * DESC + xq[5];
      pg = gg.y * DESC + xq[6]; po = go.y * DESC + xq[7];
      c1 = sigmoidf_(pf) * c1 + sigmoidf_(pi) * tanhf(pg);
      float h1 = sigmoidf_(po) * tanhf(c1);
      __hip_fp8_e4m3 q0(h0 * 16.f), q1(h1 * 16.f);
      h8[tid] = q0.__x;
      h8[256 + tid] = q1.__x;
      hout[((size_t)(2 * bb) * T + t) * 256 + tid] = h0;
      hout[((size_t)(2 * bb + 1) * T + t) * 256 + tid] = h1;
      #pragma unroll
      for (int g = 0; g < 8; g++) xq[g] = xn[g];
    }
    __syncthreads();
  }
}

// ---------------- attention, decode-style (only query t = T-1) ----------------
__global__ __launch_bounds__(256) void attn_decode_k(const float* __restrict__ qkv,
                                                     float* __restrict__ o, int T) {
  int bh = blockIdx.x; int b = bh >> 2, h = bh & 3;
  int tid = threadIdx.x;
  __shared__ float q[64];
  __shared__ float p[512];
  __shared__ float red[256];
  if (tid < 64) q[tid] = qkv[((size_t)(b * T + T - 1)) * 768 + h * 64 + tid];
  __syncthreads();
  for (int t = tid; t < 512; t += 256) {
    const float* kv = qkv + ((size_t)(b * T + t)) * 768 + 256 + h * 64;
    float s = 0.f;
    #pragma unroll 16
    for (int d = 0; d < 64; d++) s += q[d] * kv[d];
    p[t] = s * 0.125f;
  }
  __syncthreads();
  red[tid] = fmaxf(p[tid], p[tid + 256]); __syncthreads();
  for (int st = 128; st > 0; st >>= 1) { if (tid < st) red[tid] = fmaxf(red[tid], red[tid + st]); __syncthreads(); }
  float mx = red[0]; __syncthreads();
  float e0 = expf(p[tid] - mx), e1 = expf(p[tid + 256] - mx);
  red[tid] = e0 + e1; __syncthreads();
  for (int st = 128; st > 0; st >>= 1) { if (tid < st) red[tid] += red[tid + st]; __syncthreads(); }
  float inv = 1.f / red[0];
  __syncthreads();
  p[tid] = e0; p[tid + 256] = e1;
  __syncthreads();
  int d = tid & 63, grp = tid >> 6;
  float acc = 0.f;
  for (int t = grp * 128; t < grp * 128 + 128; t++)
    acc += p[t] * qkv[((size_t)(b * T + t)) * 768 + 512 + h * 64 + d];
  red[tid] = acc; __syncthreads();
  if (grp == 0)
    o[(b * 4 + h) * 64 + d] = (red[tid] + red[tid + 64] + red[tid + 128] + red[tid + 192]) * inv;
}

// ---------------- attn out-proj + residual + LN (only t=T-1) ----------------
__global__ __launch_bounds__(256) void attn_proj_ln_k(
    const float* __restrict__ attnO, const float* __restrict__ W, const float* __restrict__ bias,
    const float* __restrict__ lstmF, const float* __restrict__ lng, const float* __restrict__ lnb,
    float* __restrict__ out, int T) {
  int bb = blockIdx.x, j = threadIdx.x;
  __shared__ float a[256];
  __shared__ float red[256];
  a[j] = attnO[bb * 256 + j];
  __syncthreads();
  float acc = bias[j];
  const float* wr = W + (size_t)j * 256;
  #pragma unroll 8
  for (int k = 0; k < 256; k += 4) {
    float4 w4 = *(const float4*)(wr + k);
    acc += a[k] * w4.x + a[k + 1] * w4.y + a[k + 2] * w4.z + a[k + 3] * w4.w;
  }
  float s = acc + lstmF[((size_t)(bb * T + T - 1)) * 256 + j];
  float mean = block_sum256(s, red) * (1.f / 256.f);
  float d = s - mean;
  float var = block_sum256(d * d, red) * (1.f / 256.f);
  out[bb * 256 + j] = d * rsqrtf(var + 1e-5f) * lng[j] + lnb[j];
}

// ---------------- final two GRNs (pa then fg), only t=T-1 ----------------
__global__ __launch_bounds__(256) void final_grns_k(
    const float* __restrict__ ain,
    const float* __restrict__ paw1, const float* __restrict__ pab1,
    const float* __restrict__ paw2, const float* __restrict__ pab2,
    const float* __restrict__ palg, const float* __restrict__ palb,
    const float* __restrict__ fgw1, const float* __restrict__ fgb1,
    const float* __restrict__ fgw2, const float* __restrict__ fgb2,
    const float* __restrict__ fglg, const float* __restrict__ fglb,
    float* __restrict__ out) {
  int bb = blockIdx.x, j = threadIdx.x;
  __shared__ float a[256];
  __shared__ float hbuf[1024];
  __shared__ float red[256];
  a[j] = ain[bb * 256 + j];
  __syncthreads();
  float acc = pab1[j];
  for (int k = 0; k < 256; k++) acc += a[k] * paw1[k * 256 + j];
  hbuf[j] = eluf_(acc);
  __syncthreads();
  float g1 = pab2[j], g2 = pab2[256 + j];
  for (int k = 0; k < 256; k++) { float hv = hbuf[k]; g1 += hv * paw2[k * 512 + j]; g2 += hv * paw2[k * 512 + 256 + j]; }
  float s = g1 * sigmoidf_(g2) + a[j];
  float mean = block_sum256(s, red) * (1.f / 256.f);
  float d = s - mean;
  float var = block_sum256(d * d, red) * (1.f / 256.f);
  float af = d * rsqrtf(var + 1e-5f) * palg[j] + palb[j];
  __syncthreads();
  a[j] = af;
  __syncthreads();
  float hh[4];
  #pragma unroll
  for (int q = 0; q < 4; q++) {
    int jj = j + q * 256;
    float ac = fgb1[jj];
    for (int k = 0; k < 256; k++) ac += a[k] * fgw1[k * 1024 + jj];
    hh[q] = eluf_(ac);
  }
  __syncthreads();
  #pragma unroll
  for (int q = 0; q < 4; q++) hbuf[j + q * 256] = hh[q];
  __syncthreads();
  float G1 = fgb2[j], G2 = fgb2[256 + j];
  for (int k = 0; k < 1024; k++) { float hv = hbuf[k]; G1 += hv * fgw2[k * 512 + j]; G2 += hv * fgw2[k * 512 + 256 + j]; }
  float s2 = G1 * sigmoidf_(G2) + a[j];
  mean = block_sum256(s2, red) * (1.f / 256.f);
  d = s2 - mean;
  var = block_sum256(d * d, red) * (1.f / 256.f);
  out[bb * 256 + j] = d * rsqrtf(var + 1e-5f) * fglg[j] + fglb[j];
}

extern "C" void kernel_launch(void* const* d_in, const int* in_sizes, int n_in,
                              void* d_out, int out_size, void* d_ws, size_t ws_size,
                              hipStream_t stream) {
  const float* x          = (const float*)d_in[0];
  const float* emb_w      = (const float*)d_in[1];
  const float* emb_b      = (const float*)d_in[2];
  const float* vg_fc1_w   = (const float*)d_in[3];
  const float* vg_fc1_b   = (const float*)d_in[4];
  const float* vg_fc2_w   = (const float*)d_in[5];
  const float* vg_fc2_b   = (const float*)d_in[6];
  const float* vg_ln_g    = (const float*)d_in[7];
  const float* vg_ln_b    = (const float*)d_in[8];
  const float* sel_fc1_w  = (const float*)d_in[9];
  const float* sel_fc1_b  = (const float*)d_in[10];
  const float* sel_fc2_w  = (const float*)d_in[11];
  const float* sel_fc2_b  = (const float*)d_in[12];
  const float* sel_skip_w = (const float*)d_in[13];
  const float* sel_skip_b = (const float*)d_in[14];
  const float* sel_ln_g   = (const float*)d_in[15];
  const float* sel_ln_b   = (const float*)d_in[16];
  const float* lstm_wih   = (const float*)d_in[17];
  const float* lstm_whh   = (const float*)d_in[18];
  const float* lstm_bih   = (const float*)d_in[19];
  const float* lstm_bhh   = (const float*)d_in[20];
  const float* pl_fc1_w   = (const float*)d_in[21];
  const float* pl_fc1_b   = (const float*)d_in[22];
  const float* pl_fc2_w   = (const float*)d_in[23];
  const float* pl_fc2_b   = (const float*)d_in[24];
  const float* pl_ln_g    = (const float*)d_in[25];
  const float* pl_ln_b    = (const float*)d_in[26];
  const float* attn_in_w  = (const float*)d_in[27];
  const float* attn_in_b  = (const float*)d_in[28];
  const float* attn_out_w = (const float*)d_in[29];
  const float* attn_out_b = (const float*)d_in[30];
  const float* attn_ln_g  = (const float*)d_in[31];
  const float* attn_ln_b  = (const float*)d_in[32];
  const float* pa_fc1_w   = (const float*)d_in[33];
  const float* pa_fc1_b   = (const float*)d_in[34];
  const float* pa_fc2_w   = (const float*)d_in[35];
  const float* pa_fc2_b   = (const float*)d_in[36];
  const float* pa_ln_g    = (const float*)d_in[37];
  const float* pa_ln_b    = (const float*)d_in[38];
  const float* fg_fc1_w   = (const float*)d_in[39];
  const float* fg_fc1_b   = (const float*)d_in[40];
  const float* fg_fc2_w   = (const float*)d_in[41];
  const float* fg_fc2_b   = (const float*)d_in[42];
  const float* fg_ln_g    = (const float*)d_in[43];
  const float* fg_ln_b    = (const float*)d_in[44];
  (void)in_sizes; (void)n_in; (void)out_size; (void)ws_size;

  float* out     = (float*)d_out;
  float* out_wts = out + BB * DD;

  // ---- workspace layout ----
  char* p = (char*)d_ws;
  ushort* wt_sel_fc1  = (ushort*)p;                 p += 1048576 * 2;
  ushort* wt_sel_skip = (ushort*)p;                 p += 65536 * 2;
  ushort* wt_sel_fc2  = (ushort*)p;                 p += 8192 * 2;
  ushort* wt_var_fc1  = (ushort*)p;                 p += 1048576 * 2;
  ushort* wt_var_fc2  = (ushort*)p;                 p += 2097152 * 2;
  ushort* wt_wih      = (ushort*)p;                 p += 524288 * 2;
  unsigned char* wt_whh_pk8 = (unsigned char*)p;    p += 524288;       // fp8 frag-packed whh (2 layers)
  ushort* wt_pl_fc1   = (ushort*)p;                 p += 65536 * 2;
  ushort* wt_pl_fc2   = (ushort*)p;                 p += 131072 * 2;
  ushort* wt_attn     = (ushort*)p;                 p += 196608 * 2;
  ushort* selH        = (ushort*)p;                 p += (size_t)BT * 256 * 2;
  float*  selSkip     = (float*)p;                  p += (size_t)BT * 16 * 4;
  float*  selG        = (float*)p;                  p += (size_t)BT * 32 * 4;
  float*  vsn         = (float*)p;                  p += (size_t)BT * 256 * 4;
  float*  hseq1       = (float*)p;                  p += (size_t)BT * 256 * 4;
  float*  hseq2       = (float*)p;                  p += (size_t)BT * 256 * 4;
  float*  cbias       = (float*)p;                  p += 4096 * 4;
  float*  attnO       = (float*)p;                  p += 8192 * 4;
  float*  attnLN      = (float*)p;                  p += 8192 * 4;
  char*   R           = p;
  ushort* bufA16 = (ushort*)R;
  ushort* bufG16 = (ushort*)(R + (((size_t)32) << 20));
  float*  xi     = (float*)R;
  float*  plA    = (float*)R;
  ushort* plH    = (ushort*)(R + (((size_t)16) << 20));
  ushort* plG    = (ushort*)(R + (((size_t)24) << 20));
  float*  lstmF  = (float*)(R + (((size_t)48) << 20));
  float*  qkv    = (float*)R;

  dim3 blk(256);

  // ---- weight prep ----
  wtT_k<<<dim3(8, 128, 1),  blk, 0, stream>>>(sel_fc1_w,  wt_sel_fc1,  4096, 256, 0, 0);
  wtT_k<<<dim3(1, 128, 1),  blk, 0, stream>>>(sel_skip_w, wt_sel_skip, 4096, 16,  0, 0);
  wtT_k<<<dim3(1, 8, 1),    blk, 0, stream>>>(sel_fc2_w,  wt_sel_fc2,  256,  32,  0, 0);
  wtT_k<<<dim3(8, 8, 16),   blk, 0, stream>>>(vg_fc1_w,   wt_var_fc1,  256,  256, 65536, 65536);
  wtT_k<<<dim3(16, 8, 16),  blk, 0, stream>>>(vg_fc2_w,   wt_var_fc2,  256,  512, 131072, 131072);
  wtT_k<<<dim3(8, 8, 1),    blk, 0, stream>>>(pl_fc1_w,   wt_pl_fc1,   256,  256, 0, 0);
  wtT_k<<<dim3(16, 8, 1),   blk, 0, stream>>>(pl_fc2_w,   wt_pl_fc2,   256,  512, 0, 0);
  cvt_k<<<2048, blk, 0, stream>>>(lstm_wih,  wt_wih, 524288);
  whh_pack8_k<<<256, blk, 0, stream>>>(lstm_whh, wt_whh_pk8);
  cvt_k<<<768,  blk, 0, stream>>>(attn_in_w, wt_attn, 196608);
  add2_k<<<8, blk, 0, stream>>>(lstm_bih, lstm_bhh, cbias, 4096);

  // ---- selection GRN -> softmax weights ----
  mgemm_k<2,1,1><<<dim3(2, 128, 1), blk, 0, stream>>>(x, 16, 0, wt_sel_fc1, 0, sel_fc1_b, 0,
      selH, 256, 0, 4096, 256, emb_w, emb_b, 0);
  mgemm_k<2,0,0><<<dim3(1, 128, 1), blk, 0, stream>>>(x, 16, 0, wt_sel_skip, 0, sel_skip_b, 0,
      selSkip, 16, 0, 4096, 16, emb_w, emb_b, 0);
  mgemm_k<1,0,0><<<dim3(1, 128, 1), blk, 0, stream>>>(selH, 256, 0, wt_sel_fc2, 0, sel_fc2_b, 0,
      selG, 32, 0, 256, 32, nullptr, nullptr, 0);
  sel_finish_k<<<64, blk, 0, stream>>>(selG, selSkip, sel_ln_g, sel_ln_b, out_wts, BT);

  // ---- per-variable GRNs (groups of 4) + weighted sum into vsn ----
  for (int g = 0; g < 4; g++) {
    mgemm_k<2,1,1><<<dim3(2, 128, 4), blk, 0, stream>>>(x, 16, 0,
        wt_var_fc1 + (size_t)g * 4 * 65536, 65536, vg_fc1_b + g * 1024, 256,
        bufA16, 256, (long)BT * 256, 256, 256, emb_w + g * 1024, emb_b + g * 1024, g * 4);
    mgemm_k<1,0,1><<<dim3(4, 128, 4), blk, 0, stream>>>(bufA16, 256, (long)BT * 256,
        wt_var_fc2 + (size_t)g * 4 * 131072, 131072, vg_fc2_b + g * 2048, 512,
        bufG16, 512, (long)BT * 512, 256, 512, nullptr, nullptr, 0);
    var_epi4_k<<<BT, blk, 0, stream>>>(bufG16, x, g * 4, emb_w + g * 1024, emb_b + g * 1024,
        vg_ln_g + g * 1024, vg_ln_b + g * 1024, out_wts, vsn, g == 0 ? 1 : 0);
  }

  // ---- LSTM (2 layers) ----
  mgemm_k<0,0,0><<<dim3(8, 128, 1), blk, 0, stream>>>(vsn, 256, 0, wt_wih, 0, cbias, 0,
      xi, 1024, 0, 256, 1024, nullptr, nullptr, 0);
  lstm_recur_k<<<16, blk, 0, stream>>>(xi, wt_whh_pk8, hseq1, TT);
  mgemm_k<0,0,0><<<dim3(8, 128, 1), blk, 0, stream>>>(hseq1, 256, 0, wt_wih + 1024 * 256, 0,
      cbias + 1024, 0, xi, 1024, 0, 256, 1024, nullptr, nullptr, 0);
  lstm_recur_k<<<16, blk, 0, stream>>>(xi, wt_whh_pk8 + 262144, hseq2, TT);

  // ---- post-LSTM gated residual (pl GRN) ----
  add2_k<<<BT, blk, 0, stream>>>(hseq2, vsn, plA, BT * 256);
  mgemm_k<0,1,1><<<dim3(2, 128, 1), blk, 0, stream>>>(plA, 256, 0, wt_pl_fc1, 0, pl_fc1_b, 0,
      plH, 256, 0, 256, 256, nullptr, nullptr, 0);
  mgemm_k<1,0,1><<<dim3(4, 128, 1), blk, 0, stream>>>(plH, 256, 0, wt_pl_fc2, 0, pl_fc2_b, 0,
      plG, 512, 0, 256, 512, nullptr, nullptr, 0);
  grn_epi_k<<<BT, blk, 0, stream>>>(plG, plA, pl_ln_g, pl_ln_b, lstmF);

  // ---- attention (decode at t=T-1 only) ----
  mgemm_k<0,0,0><<<dim3(6, 128, 1), blk, 0, stream>>>(lstmF, 256, 0, wt_attn, 0, attn_in_b, 0,
      qkv, 768, 0, 256, 768, nullptr, nullptr, 0);
  attn_decode_k<<<BB * 4, blk, 0, stream>>>(qkv, attnO, TT);
  attn_proj_ln_k<<<BB, blk, 0, stream>>>(attnO, attn_out_w, attn_out_b, lstmF,
                                         attn_ln_g, attn_ln_b, attnLN, TT);

  // ---- pa GRN + fg GRN (t=T-1 only) -> first output slice ----
  final_grns_k<<<BB, blk, 0, stream>>>(attnLN,
      pa_fc1_w, pa_fc1_b, pa_fc2_w, pa_fc2_b, pa_ln_g, pa_ln_b,
      fg_fc1_w, fg_fc1_b, fg_fc2_w, fg_fc2_b, fg_ln_g, fg_ln_b,
      out);
}

// Round 6
// 2954.556 us; speedup vs baseline: 11.5549x; 1.2938x over previous
//
#include <hip/hip_runtime.h>
#include <hip/hip_bf16.h>
#include <hip/hip_fp8.h>
#include <math.h>

// TFT: B=32, T=512, V=16, D=256, H=4, L=2.  BT = 16384.
// Round 6: LSTM fp8-MFMA recurrence refined:
//  - 16 blocks x 512 threads (8 waves, 2/SIMD, launch_bounds(512,2) -> 256-reg cap)
//  - wave owns 128 gate-cols: 64 weight-longs in regs, 64 MFMAs/step
//  - h8 rows padded to 264 B (4-way instead of 16-way A-read conflicts)
//  - gl as [n][{m0,m1}] pairs: conflict-free b64 writes, 2-way (free) gate reads
//  - fast sigmoid/tanh via __expf + v_rcp_f32
// GEMMs: bf16 MFMA 128x128 (unchanged). Attention decode-only at t=T-1.

#define BT 16384
#define TT 512
#define BB 32
#define VV 16
#define DD 256

typedef unsigned short ushort;
typedef unsigned int uint;
typedef unsigned long ulong_;
typedef __attribute__((ext_vector_type(8))) short short8;
typedef __attribute__((ext_vector_type(8))) unsigned short ushort8v;
typedef __attribute__((ext_vector_type(4))) float floatx4;

__device__ __forceinline__ float sigmoidf_(float x) { return 1.f / (1.f + expf(-x)); }
__device__ __forceinline__ float eluf_(float x)     { return x > 0.f ? x : expm1f(x); }
// fast device transcendentals (v_exp_f32 + v_rcp_f32); ~1e-6 rel err
__device__ __forceinline__ float fsig(float x) {
  return __builtin_amdgcn_rcpf(1.f + __expf(-x));
}
__device__ __forceinline__ float ftanh(float x) {
  float xc = fminf(fmaxf(x, -44.f), 44.f);
  float e = __expf(-2.f * xc);
  return (1.f - e) * __builtin_amdgcn_rcpf(1.f + e);
}
__device__ __forceinline__ ushort f2bf(float f) {
  unsigned int u = __float_as_uint(f);
  unsigned int r = u + 0x7fffu + ((u >> 16) & 1u);
  return (ushort)(r >> 16);
}
__device__ __forceinline__ float bf2f(ushort b) { return __uint_as_float(((unsigned int)b) << 16); }

// block-wide sum over 256 threads via wave shuffles + 4-slot LDS
__device__ __forceinline__ float bsum256(float v, float* red4) {
  #pragma unroll
  for (int m = 32; m > 0; m >>= 1) v += __shfl_xor(v, m, 64);
  int w = threadIdx.x >> 6;
  if ((threadIdx.x & 63) == 0) red4[w] = v;
  __syncthreads();
  float r = red4[0] + red4[1] + red4[2] + red4[3];
  __syncthreads();
  return r;
}

__device__ __forceinline__ float block_sum256(float v, float* red) {
  int j = threadIdx.x;
  red[j] = v; __syncthreads();
  #pragma unroll
  for (int st = 128; st > 0; st >>= 1) {
    if (j < st) red[j] += red[j + st];
    __syncthreads();
  }
  float r = red[0];
  __syncthreads();
  return r;
}

// ---------------- weight prep ----------------
__global__ void wtT_k(const float* __restrict__ src, ushort* __restrict__ dst,
                      int K, int N, long sStride, long dStride) {
  int b = blockIdx.z;
  src += (size_t)b * sStride; dst += (size_t)b * dStride;
  __shared__ float t[32][33];
  int k0 = blockIdx.y * 32, n0 = blockIdx.x * 32;
  int tx = threadIdx.x & 31, ty = threadIdx.x >> 5;
  #pragma unroll
  for (int i = 0; i < 32; i += 8) {
    int k = k0 + ty + i, n = n0 + tx;
    t[ty + i][tx] = (k < K && n < N) ? src[(size_t)k * N + n] : 0.f;
  }
  __syncthreads();
  #pragma unroll
  for (int i = 0; i < 32; i += 8) {
    int n = n0 + ty + i, k = k0 + tx;
    if (n < N && k < K) dst[(size_t)n * K + k] = f2bf(t[tx][ty + i]);
  }
}

__global__ void cvt_k(const float* __restrict__ src, ushort* __restrict__ dst, int n) {
  int i = blockIdx.x * 256 + threadIdx.x;
  if (i < n) dst[i] = f2bf(src[i]);
}

// pack whh fp32 [2][1024][256] -> fp8 e4m3 (x64) in MFMA B-frag order:
// gid = layer*32768 + (ntg*8+kt)*64 + lane; 8 bytes = B[n=ntg*16+(lane&15)][k=kt*32+(lane>>4)*8 ..+8]
__global__ void whh_pack8_k(const float* __restrict__ whh, unsigned char* __restrict__ dst) {
  int gid = blockIdx.x * 256 + threadIdx.x;   // 65536 total
  int layer = gid >> 15;
  int rem = gid & 32767;
  int lane = rem & 63;
  int ntkt = rem >> 6;
  int kt = ntkt & 7, nt = ntkt >> 3;
  int n = nt * 16 + (lane & 15);
  int k = kt * 32 + (lane >> 4) * 8;
  const float* src = whh + (size_t)layer * 262144 + (size_t)n * 256 + k;
  ulong_ pack = 0;
  #pragma unroll
  for (int b = 0; b < 8; b++) {
    __hip_fp8_e4m3 q(src[b] * 64.f);
    pack |= ((ulong_)q.__x) << (8 * b);
  }
  *(ulong_*)(dst + (size_t)gid * 8) = pack;
}

// ---------------- bf16 MFMA GEMM (unchanged) ----------------
template<int ADT, int ACT, int CDT>
__global__ __launch_bounds__(256) void mgemm_k(
    const void* __restrict__ Aall, int lda, long aStride,
    const ushort* __restrict__ Ball, long bStride,
    const float* __restrict__ biasAll, long biasStride,
    void* __restrict__ Call, int ldc, long cStride,
    int K, int Nvalid,
    const float* __restrict__ embw, const float* __restrict__ embb, int xbase) {
  int z = blockIdx.z;
  const ushort* B = Ball + (size_t)z * bStride;
  const float* bias = biasAll ? biasAll + (size_t)z * biasStride : nullptr;
  int m0 = blockIdx.y * 128, n0 = blockIdx.x * 128;
  __shared__ ushort As[128][40];
  __shared__ ushort Bs[128][40];
  int tid = threadIdx.x;
  int r = tid >> 1, half = tid & 1;
  int wave = tid >> 6, lane = tid & 63;
  int wm = (wave >> 1) * 64, wn = (wave & 1) * 64;
  int lm = lane & 15, lq = lane >> 4;
  floatx4 acc[4][4];
  #pragma unroll
  for (int i = 0; i < 4; i++)
    #pragma unroll
    for (int j = 0; j < 4; j++) acc[i][j] = (floatx4)0.f;

  for (int k0 = 0; k0 < K; k0 += 32) {
    int kk = k0 + half * 16;
    {
      int gm = m0 + r;
      ushort tmp[16];
      if (ADT == 0) {
        const float* Af = (const float*)Aall + (size_t)z * aStride + (size_t)gm * lda + kk;
        #pragma unroll
        for (int q = 0; q < 4; q++) {
          float4 f = ((const float4*)Af)[q];
          tmp[q * 4 + 0] = f2bf(f.x); tmp[q * 4 + 1] = f2bf(f.y);
          tmp[q * 4 + 2] = f2bf(f.z); tmp[q * 4 + 3] = f2bf(f.w);
        }
      } else if (ADT == 1) {
        const ushort* Ab = (const ushort*)Aall + (size_t)z * aStride + (size_t)gm * lda + kk;
        *(ushort8v*)&tmp[0] = *(const ushort8v*)(Ab);
        *(ushort8v*)&tmp[8] = *(const ushort8v*)(Ab + 8);
      } else {
        const float* xp = (const float*)Aall;
        float xv = xp[(size_t)gm * lda + xbase + z + (kk >> 8)];
        const float4* ew = (const float4*)(embw + (size_t)z * 256 + kk);
        const float4* eb = (const float4*)(embb + (size_t)z * 256 + kk);
        #pragma unroll
        for (int q = 0; q < 4; q++) {
          float4 w4 = ew[q], b4 = eb[q];
          tmp[q * 4 + 0] = f2bf(xv * w4.x + b4.x); tmp[q * 4 + 1] = f2bf(xv * w4.y + b4.y);
          tmp[q * 4 + 2] = f2bf(xv * w4.z + b4.z); tmp[q * 4 + 3] = f2bf(xv * w4.w + b4.w);
        }
      }
      *(ushort8v*)&As[r][half * 16]     = *(ushort8v*)&tmp[0];
      *(ushort8v*)&As[r][half * 16 + 8] = *(ushort8v*)&tmp[8];
    }
    {
      int gn = n0 + r;
      ushort tmp[16];
      if (gn < Nvalid) {
        const ushort* Bp = B + (size_t)gn * K + kk;
        *(ushort8v*)&tmp[0] = *(const ushort8v*)(Bp);
        *(ushort8v*)&tmp[8] = *(const ushort8v*)(Bp + 8);
      } else {
        #pragma unroll
        for (int q = 0; q < 16; q++) tmp[q] = 0;
      }
      *(ushort8v*)&Bs[r][half * 16]     = *(ushort8v*)&tmp[0];
      *(ushort8v*)&Bs[r][half * 16 + 8] = *(ushort8v*)&tmp[8];
    }
    __syncthreads();
    short8 fa[4], fb[4];
    #pragma unroll
    for (int i = 0; i < 4; i++) fa[i] = *(const short8*)&As[wm + i * 16 + lm][lq * 8];
    #pragma unroll
    for (int j = 0; j < 4; j++) fb[j] = *(const short8*)&Bs[wn + j * 16 + lm][lq * 8];
    #pragma unroll
    for (int i = 0; i < 4; i++)
      #pragma unroll
      for (int j = 0; j < 4; j++)
        acc[i][j] = __builtin_amdgcn_mfma_f32_16x16x32_bf16(fa[i], fb[j], acc[i][j], 0, 0, 0);
    __syncthreads();
  }
  #pragma unroll
  for (int j = 0; j < 4; j++) {
    int gn = n0 + wn + j * 16 + lm;
    if (gn >= Nvalid) continue;
    float bv = bias ? bias[gn] : 0.f;
    #pragma unroll
    for (int i = 0; i < 4; i++) {
      #pragma unroll
      for (int rg = 0; rg < 4; rg++) {
        int gm = m0 + wm + i * 16 + lq * 4 + rg;
        float v = acc[i][j][rg] + bv;
        if (ACT == 1) v = eluf_(v);
        if (CDT == 0) ((float*)Call + (size_t)z * cStride)[(size_t)gm * ldc + gn] = v;
        else ((ushort*)Call + (size_t)z * cStride)[(size_t)gm * ldc + gn] = f2bf(v);
      }
    }
  }
}

// ---------------- selection GRN finish ----------------
__global__ void sel_finish_k(const float* __restrict__ selG, const float* __restrict__ selSkip,
                             const float* __restrict__ lng, const float* __restrict__ lnb,
                             float* __restrict__ wout, int M) {
  int m = blockIdx.x * 256 + threadIdx.x;
  if (m >= M) return;
  float s[16];
  float mean = 0.f;
  #pragma unroll
  for (int i = 0; i < 16; i++) {
    float h1 = selG[m * 32 + i], h2 = selG[m * 32 + 16 + i];
    float val = h1 * sigmoidf_(h2) + selSkip[m * 16 + i];
    s[i] = val; mean += val;
  }
  mean *= (1.f / 16.f);
  float var = 0.f;
  #pragma unroll
  for (int i = 0; i < 16; i++) { float d = s[i] - mean; var += d * d; }
  var *= (1.f / 16.f);
  float inv = rsqrtf(var + 1e-5f);
  float mx = -1e30f;
  #pragma unroll
  for (int i = 0; i < 16; i++) { s[i] = (s[i] - mean) * inv * lng[i] + lnb[i]; mx = fmaxf(mx, s[i]); }
  float sum = 0.f;
  #pragma unroll
  for (int i = 0; i < 16; i++) { s[i] = expf(s[i] - mx); sum += s[i]; }
  float isum = 1.f / sum;
  #pragma unroll
  for (int i = 0; i < 16; i++) wout[m * 16 + i] = s[i] * isum;
}

// ---------------- var-GRN epilogue, 4 variables per launch ----------------
__global__ __launch_bounds__(256) void var_epi4_k(
    const ushort* __restrict__ G16,
    const float* __restrict__ x, int vbase,
    const float* __restrict__ embw, const float* __restrict__ embb,
    const float* __restrict__ lng, const float* __restrict__ lnb,
    const float* __restrict__ wts, float* __restrict__ vsn, int first) {
  int m = blockIdx.x, j = threadIdx.x;
  __shared__ float red4[4];
  float accv = 0.f;
  #pragma unroll
  for (int z = 0; z < 4; z++) {
    int v = vbase + z;
    const ushort* Gp = G16 + ((size_t)z * BT + m) * 512;
    float g1 = bf2f(Gp[j]), g2 = bf2f(Gp[256 + j]);
    float e = x[m * VV + v] * embw[z * 256 + j] + embb[z * 256 + j];
    float s = g1 * sigmoidf_(g2) + e;
    float mean = bsum256(s, red4) * (1.f / 256.f);
    float d = s - mean;
    float var = bsum256(d * d, red4) * (1.f / 256.f);
    float o = d * rsqrtf(var + 1e-5f) * lng[z * 256 + j] + lnb[z * 256 + j];
    accv += wts[m * VV + v] * o;
  }
  size_t oi = (size_t)m * 256 + j;
  if (first) vsn[oi] = accv; else vsn[oi] += accv;
}

// ---------------- generic GRN epilogue ----------------
__global__ __launch_bounds__(256) void grn_epi_k(
    const ushort* __restrict__ G, const float* __restrict__ skip,
    const float* __restrict__ lng, const float* __restrict__ lnb,
    float* __restrict__ out) {
  int m = blockIdx.x, j = threadIdx.x;
  __shared__ float red4[4];
  float g1 = bf2f(G[(size_t)m * 512 + j]), g2 = bf2f(G[(size_t)m * 512 + 256 + j]);
  float s = g1 * sigmoidf_(g2) + skip[(size_t)m * 256 + j];
  float mean = bsum256(s, red4) * (1.f / 256.f);
  float d = s - mean;
  float var = bsum256(d * d, red4) * (1.f / 256.f);
  out[(size_t)m * 256 + j] = d * rsqrtf(var + 1e-5f) * lng[j] + lnb[j];
}

// ---------------- elementwise ----------------
__global__ void add2_k(const float* __restrict__ a, const float* __restrict__ b,
                       float* __restrict__ c, int n) {
  int i = blockIdx.x * 256 + threadIdx.x;
  if (i < n) c[i] = a[i] + b[i];
}

// ---------------- LSTM recurrence: fp8 MFMA, weights register-resident ----------------
// 16 blocks (2 batches each) x 512 threads (8 waves, 2/SIMD). Wave w owns gate
// cols [w*128, w*128+128): 8 N-tiles x 8 K-tiles = 64 longs pinned in regs, 64
// MFMAs/step. h8 rows padded to 264 B. gl[n] = {m0,m1} pairs.
#define DESC (1.f / 1024.f)
__global__ __launch_bounds__(512, 2) void lstm_recur_k(
    const float* __restrict__ xi,            // [B,T,1024] = xW^T + bih + bhh
    const unsigned char* __restrict__ wpk,   // fp8 frag-packed layer (262144 B)
    float* __restrict__ hout,                // [B,T,256]
    int T) {
  int bb = blockIdx.x;                        // batches 2bb, 2bb+1
  int tid = threadIdx.x;
  int wave = tid >> 6, lane = tid & 63;
  __shared__ __align__(16) unsigned char h8[16 * 264];   // A rows (fp8), padded stride
  __shared__ __align__(16) float gl[2048];               // [n][{m0,m1}] gate preacts
  for (int i = tid; i < (16 * 264) / 4; i += 512) ((uint*)h8)[i] = 0;

  long wr[8][8];
  {
    const ulong_* wp = (const ulong_*)wpk;
    #pragma unroll
    for (int nt = 0; nt < 8; nt++)
      #pragma unroll
      for (int kt = 0; kt < 8; kt++)
        wr[nt][kt] = (long)wp[((size_t)((wave * 8 + nt) * 8 + kt)) * 64 + lane];
  }
  int m = tid >> 8;            // batch-in-block 0/1
  int j = tid & 255;           // col
  float c = 0.f;
  const float* xr = xi + ((size_t)(2 * bb + m) * T) * 1024 + j;
  float xq[4], xn[4] = {0.f, 0.f, 0.f, 0.f};
  #pragma unroll
  for (int g = 0; g < 4; g++) xq[g] = xr[g * 256];
  int arow = (lane & 15) * 264 + (lane >> 4) * 8;
  __syncthreads();

  for (int t = 0; t < T; t++) {
    if (t + 1 < T) {
      #pragma unroll
      for (int g = 0; g < 4; g++) xn[g] = xr[(size_t)(t + 1) * 1024 + g * 256];
    }
    long a[8];
    #pragma unroll
    for (int kt = 0; kt < 8; kt++) a[kt] = *(const long*)(h8 + arow + kt * 32);
    floatx4 acc[8];
    #pragma unroll
    for (int nt = 0; nt < 8; nt++) acc[nt] = (floatx4)0.f;
    #pragma unroll
    for (int kt = 0; kt < 8; kt++)
      #pragma unroll
      for (int nt = 0; nt < 8; nt++)
        acc[nt] = __builtin_amdgcn_mfma_f32_16x16x32_fp8_fp8(a[kt], wr[nt][kt], acc[nt], 0, 0, 0);
    if (lane < 16) {
      #pragma unroll
      for (int nt = 0; nt < 8; nt++) {
        int n = wave * 128 + nt * 16 + lane;
        float2 v = make_float2(acc[nt].x, acc[nt].y);   // rows m=0,1
        *(float2*)&gl[n * 2] = v;                       // b64, lane-consecutive: conflict-free
      }
    }
    __syncthreads();
    {
      float pi = gl[(      j) * 2 + m] * DESC + xq[0];
      float pf = gl[(256 + j) * 2 + m] * DESC + xq[1];
      float pg = gl[(512 + j) * 2 + m] * DESC + xq[2];
      float po = gl[(768 + j) * 2 + m] * DESC + xq[3];
      c = fsig(pf) * c + fsig(pi) * ftanh(pg);
      float h = fsig(po) * ftanh(c);
      __hip_fp8_e4m3 q(h * 16.f);
      h8[m * 264 + j] = q.__x;
      hout[((size_t)(2 * bb + m) * T + t) * 256 + j] = h;
      #pragma unroll
      for (int g = 0; g < 4; g++) xq[g] = xn[g];
    }
    __syncthreads();
  }
}

// ---------------- attention, decode-style (only query t = T-1) ----------------
__global__ __launch_bounds__(256) void attn_decode_k(const float* __restrict__ qkv,
                                                     float* __restrict__ o, int T) {
  int bh = blockIdx.x; int b = bh >> 2, h = bh & 3;
  int tid = threadIdx.x;
  __shared__ float q[64];
  __shared__ float p[512];
  __shared__ float red[256];
  if (tid < 64) q[tid] = qkv[((size_t)(b * T + T - 1)) * 768 + h * 64 + tid];
  __syncthreads();
  for (int t = tid; t < 512; t += 256) {
    const float* kv = qkv + ((size_t)(b * T + t)) * 768 + 256 + h * 64;
    float s = 0.f;
    #pragma unroll 16
    for (int d = 0; d < 64; d++) s += q[d] * kv[d];
    p[t] = s * 0.125f;
  }
  __syncthreads();
  red[tid] = fmaxf(p[tid], p[tid + 256]); __syncthreads();
  for (int st = 128; st > 0; st >>= 1) { if (tid < st) red[tid] = fmaxf(red[tid], red[tid + st]); __syncthreads(); }
  float mx = red[0]; __syncthreads();
  float e0 = expf(p[tid] - mx), e1 = expf(p[tid + 256] - mx);
  red[tid] = e0 + e1; __syncthreads();
  for (int st = 128; st > 0; st >>= 1) { if (tid < st) red[tid] += red[tid + st]; __syncthreads(); }
  float inv = 1.f / red[0];
  __syncthreads();
  p[tid] = e0; p[tid + 256] = e1;
  __syncthreads();
  int d = tid & 63, grp = tid >> 6;
  float acc = 0.f;
  for (int t = grp * 128; t < grp * 128 + 128; t++)
    acc += p[t] * qkv[((size_t)(b * T + t)) * 768 + 512 + h * 64 + d];
  red[tid] = acc; __syncthreads();
  if (grp == 0)
    o[(b * 4 + h) * 64 + d] = (red[tid] + red[tid + 64] + red[tid + 128] + red[tid + 192]) * inv;
}

// ---------------- attn out-proj + residual + LN (only t=T-1) ----------------
__global__ __launch_bounds__(256) void attn_proj_ln_k(
    const float* __restrict__ attnO, const float* __restrict__ W, const float* __restrict__ bias,
    const float* __restrict__ lstmF, const float* __restrict__ lng, const float* __restrict__ lnb,
    float* __restrict__ out, int T) {
  int bb = blockIdx.x, j = threadIdx.x;
  __shared__ float a[256];
  __shared__ float red[256];
  a[j] = attnO[bb * 256 + j];
  __syncthreads();
  float acc = bias[j];
  const float* wr = W + (size_t)j * 256;
  #pragma unroll 8
  for (int k = 0; k < 256; k += 4) {
    float4 w4 = *(const float4*)(wr + k);
    acc += a[k] * w4.x + a[k + 1] * w4.y + a[k + 2] * w4.z + a[k + 3] * w4.w;
  }
  float s = acc + lstmF[((size_t)(bb * T + T - 1)) * 256 + j];
  float mean = block_sum256(s, red) * (1.f / 256.f);
  float d = s - mean;
  float var = block_sum256(d * d, red) * (1.f / 256.f);
  out[bb * 256 + j] = d * rsqrtf(var + 1e-5f) * lng[j] + lnb[j];
}

// ---------------- final two GRNs (pa then fg), only t=T-1 ----------------
__global__ __launch_bounds__(256) void final_grns_k(
    const float* __restrict__ ain,
    const float* __restrict__ paw1, const float* __restrict__ pab1,
    const float* __restrict__ paw2, const float* __restrict__ pab2,
    const float* __restrict__ palg, const float* __restrict__ palb,
    const float* __restrict__ fgw1, const float* __restrict__ fgb1,
    const float* __restrict__ fgw2, const float* __restrict__ fgb2,
    const float* __restrict__ fglg, const float* __restrict__ fglb,
    float* __restrict__ out) {
  int bb = blockIdx.x, j = threadIdx.x;
  __shared__ float a[256];
  __shared__ float hbuf[1024];
  __shared__ float red[256];
  a[j] = ain[bb * 256 + j];
  __syncthreads();
  float acc = pab1[j];
  for (int k = 0; k < 256; k++) acc += a[k] * paw1[k * 256 + j];
  hbuf[j] = eluf_(acc);
  __syncthreads();
  float g1 = pab2[j], g2 = pab2[256 + j];
  for (int k = 0; k < 256; k++) { float hv = hbuf[k]; g1 += hv * paw2[k * 512 + j]; g2 += hv * paw2[k * 512 + 256 + j]; }
  float s = g1 * sigmoidf_(g2) + a[j];
  float mean = block_sum256(s, red) * (1.f / 256.f);
  float d = s - mean;
  float var = block_sum256(d * d, red) * (1.f / 256.f);
  float af = d * rsqrtf(var + 1e-5f) * palg[j] + palb[j];
  __syncthreads();
  a[j] = af;
  __syncthreads();
  float hh[4];
  #pragma unroll
  for (int q = 0; q < 4; q++) {
    int jj = j + q * 256;
    float ac = fgb1[jj];
    for (int k = 0; k < 256; k++) ac += a[k] * fgw1[k * 1024 + jj];
    hh[q] = eluf_(ac);
  }
  __syncthreads();
  #pragma unroll
  for (int q = 0; q < 4; q++) hbuf[j + q * 256] = hh[q];
  __syncthreads();
  float G1 = fgb2[j], G2 = fgb2[256 + j];
  for (int k = 0; k < 1024; k++) { float hv = hbuf[k]; G1 += hv * fgw2[k * 512 + j]; G2 += hv * fgw2[k * 512 + 256 + j]; }
  float s2 = G1 * sigmoidf_(G2) + a[j];
  mean = block_sum256(s2, red) * (1.f / 256.f);
  d = s2 - mean;
  var = block_sum256(d * d, red) * (1.f / 256.f);
  out[bb * 256 + j] = d * rsqrtf(var + 1e-5f) * fglg[j] + fglb[j];
}

extern "C" void kernel_launch(void* const* d_in, const int* in_sizes, int n_in,
                              void* d_out, int out_size, void* d_ws, size_t ws_size,
                              hipStream_t stream) {
  const float* x          = (const float*)d_in[0];
  const float* emb_w      = (const float*)d_in[1];
  const float* emb_b      = (const float*)d_in[2];
  const float* vg_fc1_w   = (const float*)d_in[3];
  const float* vg_fc1_b   = (const float*)d_in[4];
  const float* vg_fc2_w   = (const float*)d_in[5];
  const float* vg_fc2_b   = (const float*)d_in[6];
  const float* vg_ln_g    = (const float*)d_in[7];
  const float* vg_ln_b    = (const float*)d_in[8];
  const float* sel_fc1_w  = (const float*)d_in[9];
  const float* sel_fc1_b  = (const float*)d_in[10];
  const float* sel_fc2_w  = (const float*)d_in[11];
  const float* sel_fc2_b  = (const float*)d_in[12];
  const float* sel_skip_w = (const float*)d_in[13];
  const float* sel_skip_b = (const float*)d_in[14];
  const float* sel_ln_g   = (const float*)d_in[15];
  const float* sel_ln_b   = (const float*)d_in[16];
  const float* lstm_wih   = (const float*)d_in[17];
  const float* lstm_whh   = (const float*)d_in[18];
  const float* lstm_bih   = (const float*)d_in[19];
  const float* lstm_bhh   = (const float*)d_in[20];
  const float* pl_fc1_w   = (const float*)d_in[21];
  const float* pl_fc1_b   = (const float*)d_in[22];
  const float* pl_fc2_w   = (const float*)d_in[23];
  const float* pl_fc2_b   = (const float*)d_in[24];
  const float* pl_ln_g    = (const float*)d_in[25];
  const float* pl_ln_b    = (const float*)d_in[26];
  const float* attn_in_w  = (const float*)d_in[27];
  const float* attn_in_b  = (const float*)d_in[28];
  const float* attn_out_w = (const float*)d_in[29];
  const float* attn_out_b = (const float*)d_in[30];
  const float* attn_ln_g  = (const float*)d_in[31];
  const float* attn_ln_b  = (const float*)d_in[32];
  const float* pa_fc1_w   = (const float*)d_in[33];
  const float* pa_fc1_b   = (const float*)d_in[34];
  const float* pa_fc2_w   = (const float*)d_in[35];
  const float* pa_fc2_b   = (const float*)d_in[36];
  const float* pa_ln_g    = (const float*)d_in[37];
  const float* pa_ln_b    = (const float*)d_in[38];
  const float* fg_fc1_w   = (const float*)d_in[39];
  const float* fg_fc1_b   = (const float*)d_in[40];
  const float* fg_fc2_w   = (const float*)d_in[41];
  const float* fg_fc2_b   = (const float*)d_in[42];
  const float* fg_ln_g    = (const float*)d_in[43];
  const float* fg_ln_b    = (const float*)d_in[44];
  (void)in_sizes; (void)n_in; (void)out_size; (void)ws_size;

  float* out     = (float*)d_out;
  float* out_wts = out + BB * DD;

  // ---- workspace layout ----
  char* p = (char*)d_ws;
  ushort* wt_sel_fc1  = (ushort*)p;                 p += 1048576 * 2;
  ushort* wt_sel_skip = (ushort*)p;                 p += 65536 * 2;
  ushort* wt_sel_fc2  = (ushort*)p;                 p += 8192 * 2;
  ushort* wt_var_fc1  = (ushort*)p;                 p += 1048576 * 2;
  ushort* wt_var_fc2  = (ushort*)p;                 p += 2097152 * 2;
  ushort* wt_wih      = (ushort*)p;                 p += 524288 * 2;
  unsigned char* wt_whh_pk8 = (unsigned char*)p;    p += 524288;
  ushort* wt_pl_fc1   = (ushort*)p;                 p += 65536 * 2;
  ushort* wt_pl_fc2   = (ushort*)p;                 p += 131072 * 2;
  ushort* wt_attn     = (ushort*)p;                 p += 196608 * 2;
  ushort* selH        = (ushort*)p;                 p += (size_t)BT * 256 * 2;
  float*  selSkip     = (float*)p;                  p += (size_t)BT * 16 * 4;
  float*  selG        = (float*)p;                  p += (size_t)BT * 32 * 4;
  float*  vsn         = (float*)p;                  p += (size_t)BT * 256 * 4;
  float*  hseq1       = (float*)p;                  p += (size_t)BT * 256 * 4;
  float*  hseq2       = (float*)p;                  p += (size_t)BT * 256 * 4;
  float*  cbias       = (float*)p;                  p += 4096 * 4;
  float*  attnO       = (float*)p;                  p += 8192 * 4;
  float*  attnLN      = (float*)p;                  p += 8192 * 4;
  char*   R           = p;
  ushort* bufA16 = (ushort*)R;
  ushort* bufG16 = (ushort*)(R + (((size_t)32) << 20));
  float*  xi     = (float*)R;
  float*  plA    = (float*)R;
  ushort* plH    = (ushort*)(R + (((size_t)16) << 20));
  ushort* plG    = (ushort*)(R + (((size_t)24) << 20));
  float*  lstmF  = (float*)(R + (((size_t)48) << 20));
  float*  qkv    = (float*)R;

  dim3 blk(256);

  // ---- weight prep ----
  wtT_k<<<dim3(8, 128, 1),  blk, 0, stream>>>(sel_fc1_w,  wt_sel_fc1,  4096, 256, 0, 0);
  wtT_k<<<dim3(1, 128, 1),  blk, 0, stream>>>(sel_skip_w, wt_sel_skip, 4096, 16,  0, 0);
  wtT_k<<<dim3(1, 8, 1),    blk, 0, stream>>>(sel_fc2_w,  wt_sel_fc2,  256,  32,  0, 0);
  wtT_k<<<dim3(8, 8, 16),   blk, 0, stream>>>(vg_fc1_w,   wt_var_fc1,  256,  256, 65536, 65536);
  wtT_k<<<dim3(16, 8, 16),  blk, 0, stream>>>(vg_fc2_w,   wt_var_fc2,  256,  512, 131072, 131072);
  wtT_k<<<dim3(8, 8, 1),    blk, 0, stream>>>(pl_fc1_w,   wt_pl_fc1,   256,  256, 0, 0);
  wtT_k<<<dim3(16, 8, 1),   blk, 0, stream>>>(pl_fc2_w,   wt_pl_fc2,   256,  512, 0, 0);
  cvt_k<<<2048, blk, 0, stream>>>(lstm_wih,  wt_wih, 524288);
  whh_pack8_k<<<256, blk, 0, stream>>>(lstm_whh, wt_whh_pk8);
  cvt_k<<<768,  blk, 0, stream>>>(attn_in_w, wt_attn, 196608);
  add2_k<<<8, blk, 0, stream>>>(lstm_bih, lstm_bhh, cbias, 4096);

  // ---- selection GRN -> softmax weights ----
  mgemm_k<2,1,1><<<dim3(2, 128, 1), blk, 0, stream>>>(x, 16, 0, wt_sel_fc1, 0, sel_fc1_b, 0,
      selH, 256, 0, 4096, 256, emb_w, emb_b, 0);
  mgemm_k<2,0,0><<<dim3(1, 128, 1), blk, 0, stream>>>(x, 16, 0, wt_sel_skip, 0, sel_skip_b, 0,
      selSkip, 16, 0, 4096, 16, emb_w, emb_b, 0);
  mgemm_k<1,0,0><<<dim3(1, 128, 1), blk, 0, stream>>>(selH, 256, 0, wt_sel_fc2, 0, sel_fc2_b, 0,
      selG, 32, 0, 256, 32, nullptr, nullptr, 0);
  sel_finish_k<<<64, blk, 0, stream>>>(selG, selSkip, sel_ln_g, sel_ln_b, out_wts, BT);

  // ---- per-variable GRNs (groups of 4) + weighted sum into vsn ----
  for (int g = 0; g < 4; g++) {
    mgemm_k<2,1,1><<<dim3(2, 128, 4), blk, 0, stream>>>(x, 16, 0,
        wt_var_fc1 + (size_t)g * 4 * 65536, 65536, vg_fc1_b + g * 1024, 256,
        bufA16, 256, (long)BT * 256, 256, 256, emb_w + g * 1024, emb_b + g * 1024, g * 4);
    mgemm_k<1,0,1><<<dim3(4, 128, 4), blk, 0, stream>>>(bufA16, 256, (long)BT * 256,
        wt_var_fc2 + (size_t)g * 4 * 131072, 131072, vg_fc2_b + g * 2048, 512,
        bufG16, 512, (long)BT * 512, 256, 512, nullptr, nullptr, 0);
    var_epi4_k<<<BT, blk, 0, stream>>>(bufG16, x, g * 4, emb_w + g * 1024, emb_b + g * 1024,
        vg_ln_g + g * 1024, vg_ln_b + g * 1024, out_wts, vsn, g == 0 ? 1 : 0);
  }

  // ---- LSTM (2 layers) ----
  mgemm_k<0,0,0><<<dim3(8, 128, 1), blk, 0, stream>>>(vsn, 256, 0, wt_wih, 0, cbias, 0,
      xi, 1024, 0, 256, 1024, nullptr, nullptr, 0);
  lstm_recur_k<<<16, 512, 0, stream>>>(xi, wt_whh_pk8, hseq1, TT);
  mgemm_k<0,0,0><<<dim3(8, 128, 1), blk, 0, stream>>>(hseq1, 256, 0, wt_wih + 1024 * 256, 0,
      cbias + 1024, 0, xi, 1024, 0, 256, 1024, nullptr, nullptr, 0);
  lstm_recur_k<<<16, 512, 0, stream>>>(xi, wt_whh_pk8 + 262144, hseq2, TT);

  // ---- post-LSTM gated residual (pl GRN) ----
  add2_k<<<BT, blk, 0, stream>>>(hseq2, vsn, plA, BT * 256);
  mgemm_k<0,1,1><<<dim3(2, 128, 1), blk, 0, stream>>>(plA, 256, 0, wt_pl_fc1, 0, pl_fc1_b, 0,
      plH, 256, 0, 256, 256, nullptr, nullptr, 0);
  mgemm_k<1,0,1><<<dim3(4, 128, 1), blk, 0, stream>>>(plH, 256, 0, wt_pl_fc2, 0, pl_fc2_b, 0,
      plG, 512, 0, 256, 512, nullptr, nullptr, 0);
  grn_epi_k<<<BT, blk, 0, stream>>>(plG, plA, pl_ln_g, pl_ln_b, lstmF);

  // ---- attention (decode at t=T-1 only) ----
  mgemm_k<0,0,0><<<dim3(6, 128, 1), blk, 0, stream>>>(lstmF, 256, 0, wt_attn, 0, attn_in_b, 0,
      qkv, 768, 0, 256, 768, nullptr, nullptr, 0);
  attn_decode_k<<<BB * 4, blk, 0, stream>>>(qkv, attnO, TT);
  attn_proj_ln_k<<<BB, blk, 0, stream>>>(attnO, attn_out_w, attn_out_b, lstmF,
                                         attn_ln_g, attn_ln_b, attnLN, TT);

  // ---- pa GRN + fg GRN (t=T-1 only) -> first output slice ----
  final_grns_k<<<BB, blk, 0, stream>>>(attnLN,
      pa_fc1_w, pa_fc1_b, pa_fc2_w, pa_fc2_b, pa_ln_g, pa_ln_b,
      fg_fc1_w, fg_fc1_b, fg_fc2_w, fg_fc2_b, fg_ln_g, fg_ln_b,
      out);
}

// Round 7
// 2946.922 us; speedup vs baseline: 11.5849x; 1.0026x over previous
//
#include <hip/hip_runtime.h>
#include <hip/hip_bf16.h>
#include <hip/hip_fp8.h>
#include <math.h>

// TFT: B=32, T=512, V=16, D=256, H=4, L=2.  BT = 16384.
// Round 7: LSTM recurrence restructured around K=128 scaled fp8 MFMA:
//  - 16 mfma_scale_f32_16x16x128_f8f6f4 per wave per step (scales = 1.0)
//  - wave owns cols {g*256 + w*32 + ts*16 + c}: all 4 gates of an h-unit land in
//    one lane -> gate phase on registers, no gl LDS round-trip, ONE barrier/step
//  - double-buffered h8 (fp8 h state) and xbuf (xi staged by all 512 threads)
// GEMMs: bf16 MFMA 128x128 (unchanged). Attention decode-only at t=T-1.

#define BT 16384
#define TT 512
#define BB 32
#define VV 16
#define DD 256

typedef unsigned short ushort;
typedef unsigned int uint;
typedef unsigned long ulong_;
typedef __attribute__((ext_vector_type(8))) short short8;
typedef __attribute__((ext_vector_type(8))) unsigned short ushort8v;
typedef __attribute__((ext_vector_type(4))) float floatx4;
typedef __attribute__((ext_vector_type(8))) int int8v;

__device__ __forceinline__ float sigmoidf_(float x) { return 1.f / (1.f + expf(-x)); }
__device__ __forceinline__ float eluf_(float x)     { return x > 0.f ? x : expm1f(x); }
__device__ __forceinline__ float fsig(float x) {
  return __builtin_amdgcn_rcpf(1.f + __expf(-x));
}
__device__ __forceinline__ float ftanh(float x) {
  float xc = fminf(fmaxf(x, -44.f), 44.f);
  float e = __expf(-2.f * xc);
  return (1.f - e) * __builtin_amdgcn_rcpf(1.f + e);
}
__device__ __forceinline__ ushort f2bf(float f) {
  unsigned int u = __float_as_uint(f);
  unsigned int r = u + 0x7fffu + ((u >> 16) & 1u);
  return (ushort)(r >> 16);
}
__device__ __forceinline__ float bf2f(ushort b) { return __uint_as_float(((unsigned int)b) << 16); }

__device__ __forceinline__ float bsum256(float v, float* red4) {
  #pragma unroll
  for (int m = 32; m > 0; m >>= 1) v += __shfl_xor(v, m, 64);
  int w = threadIdx.x >> 6;
  if ((threadIdx.x & 63) == 0) red4[w] = v;
  __syncthreads();
  float r = red4[0] + red4[1] + red4[2] + red4[3];
  __syncthreads();
  return r;
}

__device__ __forceinline__ float block_sum256(float v, float* red) {
  int j = threadIdx.x;
  red[j] = v; __syncthreads();
  #pragma unroll
  for (int st = 128; st > 0; st >>= 1) {
    if (j < st) red[j] += red[j + st];
    __syncthreads();
  }
  float r = red[0];
  __syncthreads();
  return r;
}

// ---------------- weight prep ----------------
__global__ void wtT_k(const float* __restrict__ src, ushort* __restrict__ dst,
                      int K, int N, long sStride, long dStride) {
  int b = blockIdx.z;
  src += (size_t)b * sStride; dst += (size_t)b * dStride;
  __shared__ float t[32][33];
  int k0 = blockIdx.y * 32, n0 = blockIdx.x * 32;
  int tx = threadIdx.x & 31, ty = threadIdx.x >> 5;
  #pragma unroll
  for (int i = 0; i < 32; i += 8) {
    int k = k0 + ty + i, n = n0 + tx;
    t[ty + i][tx] = (k < K && n < N) ? src[(size_t)k * N + n] : 0.f;
  }
  __syncthreads();
  #pragma unroll
  for (int i = 0; i < 32; i += 8) {
    int n = n0 + ty + i, k = k0 + tx;
    if (n < N && k < K) dst[(size_t)n * K + k] = f2bf(t[tx][ty + i]);
  }
}

__global__ void cvt_k(const float* __restrict__ src, ushort* __restrict__ dst, int n) {
  int i = blockIdx.x * 256 + threadIdx.x;
  if (i < n) dst[i] = f2bf(src[i]);
}

// pack whh fp32 [2][1024][256] -> fp8 e4m3 (x64) in K=128 B-frag order.
// gid = layer*8192 + wave*1024 + f*64 + lane; thread emits 32 bytes:
//   f = (g*2+ts)*2+kt2; n = g*256 + wave*32 + ts*16 + (lane&15);
//   k0 = kt2*128 + (lane>>4)*32;  bytes = fp8(whh[n][k0..k0+32) * 64)
__global__ void whh_pack8_k(const float* __restrict__ whh, unsigned char* __restrict__ dst) {
  int gid = blockIdx.x * 256 + threadIdx.x;   // 16384 total
  int layer = gid >> 13;
  int rem = gid & 8191;
  int lane = rem & 63;
  int f = (rem >> 6) & 15;
  int wave = rem >> 10;
  int kt2 = f & 1, ts = (f >> 1) & 1, g = f >> 2;
  int n = g * 256 + wave * 32 + ts * 16 + (lane & 15);
  int k0 = kt2 * 128 + (lane >> 4) * 32;
  const float* src = whh + (size_t)layer * 262144 + (size_t)n * 256 + k0;
  unsigned char* d = dst + (size_t)gid * 32;
  #pragma unroll
  for (int b = 0; b < 32; b++) {
    __hip_fp8_e4m3 q(src[b] * 64.f);
    d[b] = q.__x;
  }
}

// ---------------- bf16 MFMA GEMM (unchanged) ----------------
template<int ADT, int ACT, int CDT>
__global__ __launch_bounds__(256) void mgemm_k(
    const void* __restrict__ Aall, int lda, long aStride,
    const ushort* __restrict__ Ball, long bStride,
    const float* __restrict__ biasAll, long biasStride,
    void* __restrict__ Call, int ldc, long cStride,
    int K, int Nvalid,
    const float* __restrict__ embw, const float* __restrict__ embb, int xbase) {
  int z = blockIdx.z;
  const ushort* B = Ball + (size_t)z * bStride;
  const float* bias = biasAll ? biasAll + (size_t)z * biasStride : nullptr;
  int m0 = blockIdx.y * 128, n0 = blockIdx.x * 128;
  __shared__ ushort As[128][40];
  __shared__ ushort Bs[128][40];
  int tid = threadIdx.x;
  int r = tid >> 1, half = tid & 1;
  int wave = tid >> 6, lane = tid & 63;
  int wm = (wave >> 1) * 64, wn = (wave & 1) * 64;
  int lm = lane & 15, lq = lane >> 4;
  floatx4 acc[4][4];
  #pragma unroll
  for (int i = 0; i < 4; i++)
    #pragma unroll
    for (int j = 0; j < 4; j++) acc[i][j] = (floatx4)0.f;

  for (int k0 = 0; k0 < K; k0 += 32) {
    int kk = k0 + half * 16;
    {
      int gm = m0 + r;
      ushort tmp[16];
      if (ADT == 0) {
        const float* Af = (const float*)Aall + (size_t)z * aStride + (size_t)gm * lda + kk;
        #pragma unroll
        for (int q = 0; q < 4; q++) {
          float4 f = ((const float4*)Af)[q];
          tmp[q * 4 + 0] = f2bf(f.x); tmp[q * 4 + 1] = f2bf(f.y);
          tmp[q * 4 + 2] = f2bf(f.z); tmp[q * 4 + 3] = f2bf(f.w);
        }
      } else if (ADT == 1) {
        const ushort* Ab = (const ushort*)Aall + (size_t)z * aStride + (size_t)gm * lda + kk;
        *(ushort8v*)&tmp[0] = *(const ushort8v*)(Ab);
        *(ushort8v*)&tmp[8] = *(const ushort8v*)(Ab + 8);
      } else {
        const float* xp = (const float*)Aall;
        float xv = xp[(size_t)gm * lda + xbase + z + (kk >> 8)];
        const float4* ew = (const float4*)(embw + (size_t)z * 256 + kk);
        const float4* eb = (const float4*)(embb + (size_t)z * 256 + kk);
        #pragma unroll
        for (int q = 0; q < 4; q++) {
          float4 w4 = ew[q], b4 = eb[q];
          tmp[q * 4 + 0] = f2bf(xv * w4.x + b4.x); tmp[q * 4 + 1] = f2bf(xv * w4.y + b4.y);
          tmp[q * 4 + 2] = f2bf(xv * w4.z + b4.z); tmp[q * 4 + 3] = f2bf(xv * w4.w + b4.w);
        }
      }
      *(ushort8v*)&As[r][half * 16]     = *(ushort8v*)&tmp[0];
      *(ushort8v*)&As[r][half * 16 + 8] = *(ushort8v*)&tmp[8];
    }
    {
      int gn = n0 + r;
      ushort tmp[16];
      if (gn < Nvalid) {
        const ushort* Bp = B + (size_t)gn * K + kk;
        *(ushort8v*)&tmp[0] = *(const ushort8v*)(Bp);
        *(ushort8v*)&tmp[8] = *(const ushort8v*)(Bp + 8);
      } else {
        #pragma unroll
        for (int q = 0; q < 16; q++) tmp[q] = 0;
      }
      *(ushort8v*)&Bs[r][half * 16]     = *(ushort8v*)&tmp[0];
      *(ushort8v*)&Bs[r][half * 16 + 8] = *(ushort8v*)&tmp[8];
    }
    __syncthreads();
    short8 fa[4], fb[4];
    #pragma unroll
    for (int i = 0; i < 4; i++) fa[i] = *(const short8*)&As[wm + i * 16 + lm][lq * 8];
    #pragma unroll
    for (int j = 0; j < 4; j++) fb[j] = *(const short8*)&Bs[wn + j * 16 + lm][lq * 8];
    #pragma unroll
    for (int i = 0; i < 4; i++)
      #pragma unroll
      for (int j = 0; j < 4; j++)
        acc[i][j] = __builtin_amdgcn_mfma_f32_16x16x32_bf16(fa[i], fb[j], acc[i][j], 0, 0, 0);
    __syncthreads();
  }
  #pragma unroll
  for (int j = 0; j < 4; j++) {
    int gn = n0 + wn + j * 16 + lm;
    if (gn >= Nvalid) continue;
    float bv = bias ? bias[gn] : 0.f;
    #pragma unroll
    for (int i = 0; i < 4; i++) {
      #pragma unroll
      for (int rg = 0; rg < 4; rg++) {
        int gm = m0 + wm + i * 16 + lq * 4 + rg;
        float v = acc[i][j][rg] + bv;
        if (ACT == 1) v = eluf_(v);
        if (CDT == 0) ((float*)Call + (size_t)z * cStride)[(size_t)gm * ldc + gn] = v;
        else ((ushort*)Call + (size_t)z * cStride)[(size_t)gm * ldc + gn] = f2bf(v);
      }
    }
  }
}

// ---------------- selection GRN finish ----------------
__global__ void sel_finish_k(const float* __restrict__ selG, const float* __restrict__ selSkip,
                             const float* __restrict__ lng, const float* __restrict__ lnb,
                             float* __restrict__ wout, int M) {
  int m = blockIdx.x * 256 + threadIdx.x;
  if (m >= M) return;
  float s[16];
  float mean = 0.f;
  #pragma unroll
  for (int i = 0; i < 16; i++) {
    float h1 = selG[m * 32 + i], h2 = selG[m * 32 + 16 + i];
    float val = h1 * sigmoidf_(h2) + selSkip[m * 16 + i];
    s[i] = val; mean += val;
  }
  mean *= (1.f / 16.f);
  float var = 0.f;
  #pragma unroll
  for (int i = 0; i < 16; i++) { float d = s[i] - mean; var += d * d; }
  var *= (1.f / 16.f);
  float inv = rsqrtf(var + 1e-5f);
  float mx = -1e30f;
  #pragma unroll
  for (int i = 0; i < 16; i++) { s[i] = (s[i] - mean) * inv * lng[i] + lnb[i]; mx = fmaxf(mx, s[i]); }
  float sum = 0.f;
  #pragma unroll
  for (int i = 0; i < 16; i++) { s[i] = expf(s[i] - mx); sum += s[i]; }
  float isum = 1.f / sum;
  #pragma unroll
  for (int i = 0; i < 16; i++) wout[m * 16 + i] = s[i] * isum;
}

// ---------------- var-GRN epilogue, 4 variables per launch ----------------
__global__ __launch_bounds__(256) void var_epi4_k(
    const ushort* __restrict__ G16,
    const float* __restrict__ x, int vbase,
    const float* __restrict__ embw, const float* __restrict__ embb,
    const float* __restrict__ lng, const float* __restrict__ lnb,
    const float* __restrict__ wts, float* __restrict__ vsn, int first) {
  int m = blockIdx.x, j = threadIdx.x;
  __shared__ float red4[4];
  float accv = 0.f;
  #pragma unroll
  for (int z = 0; z < 4; z++) {
    int v = vbase + z;
    const ushort* Gp = G16 + ((size_t)z * BT + m) * 512;
    float g1 = bf2f(Gp[j]), g2 = bf2f(Gp[256 + j]);
    float e = x[m * VV + v] * embw[z * 256 + j] + embb[z * 256 + j];
    float s = g1 * sigmoidf_(g2) + e;
    float mean = bsum256(s, red4) * (1.f / 256.f);
    float d = s - mean;
    float var = bsum256(d * d, red4) * (1.f / 256.f);
    float o = d * rsqrtf(var + 1e-5f) * lng[z * 256 + j] + lnb[z * 256 + j];
    accv += wts[m * VV + v] * o;
  }
  size_t oi = (size_t)m * 256 + j;
  if (first) vsn[oi] = accv; else vsn[oi] += accv;
}

// ---------------- generic GRN epilogue ----------------
__global__ __launch_bounds__(256) void grn_epi_k(
    const ushort* __restrict__ G, const float* __restrict__ skip,
    const float* __restrict__ lng, const float* __restrict__ lnb,
    float* __restrict__ out) {
  int m = blockIdx.x, j = threadIdx.x;
  __shared__ float red4[4];
  float g1 = bf2f(G[(size_t)m * 512 + j]), g2 = bf2f(G[(size_t)m * 512 + 256 + j]);
  float s = g1 * sigmoidf_(g2) + skip[(size_t)m * 256 + j];
  float mean = bsum256(s, red4) * (1.f / 256.f);
  float d = s - mean;
  float var = bsum256(d * d, red4) * (1.f / 256.f);
  out[(size_t)m * 256 + j] = d * rsqrtf(var + 1e-5f) * lng[j] + lnb[j];
}

// ---------------- elementwise ----------------
__global__ void add2_k(const float* __restrict__ a, const float* __restrict__ b,
                       float* __restrict__ c, int n) {
  int i = blockIdx.x * 256 + threadIdx.x;
  if (i < n) c[i] = a[i] + b[i];
}

// ---------------- LSTM recurrence: K=128 scaled fp8 MFMA, 1 barrier/step ----------------
// 16 blocks (2 batches each) x 512 threads (8 waves). Wave w owns cols
// {g*256 + w*32 + ts*16 + c : g,ts}: 16 B-frags (128 VGPRs), 16 MFMAs/step.
// All 4 gates of h-unit j land in lane (j&15)'s acc -> gate phase on regs
// (lanes 0-15, 4 units each), writes h8[next] fp8; ONE __syncthreads per step.
#define DESC (1.f / 1024.f)
#define H8S 272
__global__ __launch_bounds__(512, 2) void lstm_recur_k(
    const float* __restrict__ xi,            // [B,T,1024] = xW^T + bih + bhh
    const unsigned char* __restrict__ wpk,   // fp8 K128-frag-packed layer (262144 B)
    float* __restrict__ hout,                // [B,T,256]
    int T) {
  int bb = blockIdx.x;                        // batches 2bb, 2bb+1
  int tid = threadIdx.x;
  int wave = tid >> 6, lane = tid & 63;
  int lm = lane & 15, lq = lane >> 4;
  __shared__ __align__(16) unsigned char h8[2][16 * H8S];  // fp8 h rows (rows 2..15 zero)
  __shared__ __align__(16) float xb[2][2][1024];           // staged xi [buf][m][g*256+j]
  for (int i = tid; i < 2 * 16 * H8S / 4; i += 512) ((uint*)h8)[i] = 0;

  int8v wr[16];
  {
    const int8v* wp = (const int8v*)wpk;
    #pragma unroll
    for (int f = 0; f < 16; f++) wr[f] = wp[(wave * 16 + f) * 64 + lane];
  }
  int m = tid >> 8;            // staging batch-in-block 0/1
  int j = tid & 255;           // staging col
  const float* xr = xi + ((size_t)(2 * bb + m) * T) * 1024 + j;
  #pragma unroll
  for (int g = 0; g < 4; g++) xb[0][m][g * 256 + j] = xr[g * 256];
  float cst[2][2] = {{0.f, 0.f}, {0.f, 0.f}};   // [ts][mm]
  int arow = lm * H8S + lq * 32;
  __syncthreads();

  for (int t = 0; t < T; t++) {
    int cur = t & 1, nxt = cur ^ 1;
    if (t + 1 < T) {
      #pragma unroll
      for (int g = 0; g < 4; g++)
        xb[nxt][m][g * 256 + j] = xr[(size_t)(t + 1) * 1024 + g * 256];
    }
    int8v a[2];
    #pragma unroll
    for (int kt = 0; kt < 2; kt++)
      a[kt] = *(const int8v*)&h8[cur][arow + kt * 128];
    floatx4 acc[8];                 // [g*2+ts]
    #pragma unroll
    for (int f = 0; f < 8; f++) acc[f] = (floatx4)0.f;
    #pragma unroll
    for (int kt = 0; kt < 2; kt++)
      #pragma unroll
      for (int f = 0; f < 8; f++)
        acc[f] = __builtin_amdgcn_mfma_scale_f32_16x16x128_f8f6f4(
            a[kt], wr[f * 2 + kt], acc[f], 0, 0, 0, 0x7f7f7f7f, 0, 0x7f7f7f7f);
    if (lq == 0) {
      #pragma unroll
      for (int ts = 0; ts < 2; ts++) {
        int jj = wave * 32 + ts * 16 + lm;
        #pragma unroll
        for (int mm = 0; mm < 2; mm++) {
          float pi = acc[0 + ts][mm] * DESC + xb[cur][mm][jj];
          float pf = acc[2 + ts][mm] * DESC + xb[cur][mm][256 + jj];
          float pg = acc[4 + ts][mm] * DESC + xb[cur][mm][512 + jj];
          float po = acc[6 + ts][mm] * DESC + xb[cur][mm][768 + jj];
          float c = fsig(pf) * cst[ts][mm] + fsig(pi) * ftanh(pg);
          cst[ts][mm] = c;
          float h = fsig(po) * ftanh(c);
          __hip_fp8_e4m3 q(h * 16.f);
          h8[nxt][mm * H8S + jj] = q.__x;
          hout[((size_t)(2 * bb + mm) * T + t) * 256 + jj] = h;
        }
      }
    }
    __syncthreads();
  }
}

// ---------------- attention, decode-style (only query t = T-1) ----------------
__global__ __launch_bounds__(256) void attn_decode_k(const float* __restrict__ qkv,
                                                     float* __restrict__ o, int T) {
  int bh = blockIdx.x; int b = bh >> 2, h = bh & 3;
  int tid = threadIdx.x;
  __shared__ float q[64];
  __shared__ float p[512];
  __shared__ float red[256];
  if (tid < 64) q[tid] = qkv[((size_t)(b * T + T - 1)) * 768 + h * 64 + tid];
  __syncthreads();
  for (int t = tid; t < 512; t += 256) {
    const float* kv = qkv + ((size_t)(b * T + t)) * 768 + 256 + h * 64;
    float s = 0.f;
    #pragma unroll 16
    for (int d = 0; d < 64; d++) s += q[d] * kv[d];
    p[t] = s * 0.125f;
  }
  __syncthreads();
  red[tid] = fmaxf(p[tid], p[tid + 256]); __syncthreads();
  for (int st = 128; st > 0; st >>= 1) { if (tid < st) red[tid] = fmaxf(red[tid], red[tid + st]); __syncthreads(); }
  float mx = red[0]; __syncthreads();
  float e0 = expf(p[tid] - mx), e1 = expf(p[tid + 256] - mx);
  red[tid] = e0 + e1; __syncthreads();
  for (int st = 128; st > 0; st >>= 1) { if (tid < st) red[tid] += red[tid + st]; __syncthreads(); }
  float inv = 1.f / red[0];
  __syncthreads();
  p[tid] = e0; p[tid + 256] = e1;
  __syncthreads();
  int d = tid & 63, grp = tid >> 6;
  float acc = 0.f;
  for (int t = grp * 128; t < grp * 128 + 128; t++)
    acc += p[t] * qkv[((size_t)(b * T + t)) * 768 + 512 + h * 64 + d];
  red[tid] = acc; __syncthreads();
  if (grp == 0)
    o[(b * 4 + h) * 64 + d] = (red[tid] + red[tid + 64] + red[tid + 128] + red[tid + 192]) * inv;
}

// ---------------- attn out-proj + residual + LN (only t=T-1) ----------------
__global__ __launch_bounds__(256) void attn_proj_ln_k(
    const float* __restrict__ attnO, const float* __restrict__ W, const float* __restrict__ bias,
    const float* __restrict__ lstmF, const float* __restrict__ lng, const float* __restrict__ lnb,
    float* __restrict__ out, int T) {
  int bb = blockIdx.x, j = threadIdx.x;
  __shared__ float a[256];
  __shared__ float red[256];
  a[j] = attnO[bb * 256 + j];
  __syncthreads();
  float acc = bias[j];
  const float* wr = W + (size_t)j * 256;
  #pragma unroll 8
  for (int k = 0; k < 256; k += 4) {
    float4 w4 = *(const float4*)(wr + k);
    acc += a[k] * w4.x + a[k + 1] * w4.y + a[k + 2] * w4.z + a[k + 3] * w4.w;
  }
  float s = acc + lstmF[((size_t)(bb * T + T - 1)) * 256 + j];
  float mean = block_sum256(s, red) * (1.f / 256.f);
  float d = s - mean;
  float var = block_sum256(d * d, red) * (1.f / 256.f);
  out[bb * 256 + j] = d * rsqrtf(var + 1e-5f) * lng[j] + lnb[j];
}

// ---------------- final two GRNs (pa then fg), only t=T-1 ----------------
__global__ __launch_bounds__(256) void final_grns_k(
    const float* __restrict__ ain,
    const float* __restrict__ paw1, const float* __restrict__ pab1,
    const float* __restrict__ paw2, const float* __restrict__ pab2,
    const float* __restrict__ palg, const float* __restrict__ palb,
    const float* __restrict__ fgw1, const float* __restrict__ fgb1,
    const float* __restrict__ fgw2, const float* __restrict__ fgb2,
    const float* __restrict__ fglg, const float* __restrict__ fglb,
    float* __restrict__ out) {
  int bb = blockIdx.x, j = threadIdx.x;
  __shared__ float a[256];
  __shared__ float hbuf[1024];
  __shared__ float red[256];
  a[j] = ain[bb * 256 + j];
  __syncthreads();
  float acc = pab1[j];
  for (int k = 0; k < 256; k++) acc += a[k] * paw1[k * 256 + j];
  hbuf[j] = eluf_(acc);
  __syncthreads();
  float g1 = pab2[j], g2 = pab2[256 + j];
  for (int k = 0; k < 256; k++) { float hv = hbuf[k]; g1 += hv * paw2[k * 512 + j]; g2 += hv * paw2[k * 512 + 256 + j]; }
  float s = g1 * sigmoidf_(g2) + a[j];
  float mean = block_sum256(s, red) * (1.f / 256.f);
  float d = s - mean;
  float var = block_sum256(d * d, red) * (1.f / 256.f);
  float af = d * rsqrtf(var + 1e-5f) * palg[j] + palb[j];
  __syncthreads();
  a[j] = af;
  __syncthreads();
  float hh[4];
  #pragma unroll
  for (int q = 0; q < 4; q++) {
    int jj = j + q * 256;
    float ac = fgb1[jj];
    for (int k = 0; k < 256; k++) ac += a[k] * fgw1[k * 1024 + jj];
    hh[q] = eluf_(ac);
  }
  __syncthreads();
  #pragma unroll
  for (int q = 0; q < 4; q++) hbuf[j + q * 256] = hh[q];
  __syncthreads();
  float G1 = fgb2[j], G2 = fgb2[256 + j];
  for (int k = 0; k < 1024; k++) { float hv = hbuf[k]; G1 += hv * fgw2[k * 512 + j]; G2 += hv * fgw2[k * 512 + 256 + j]; }
  float s2 = G1 * sigmoidf_(G2) + a[j];
  mean = block_sum256(s2, red) * (1.f / 256.f);
  d = s2 - mean;
  var = block_sum256(d * d, red) * (1.f / 256.f);
  out[bb * 256 + j] = d * rsqrtf(var + 1e-5f) * fglg[j] + fglb[j];
}

extern "C" void kernel_launch(void* const* d_in, const int* in_sizes, int n_in,
                              void* d_out, int out_size, void* d_ws, size_t ws_size,
                              hipStream_t stream) {
  const float* x          = (const float*)d_in[0];
  const float* emb_w      = (const float*)d_in[1];
  const float* emb_b      = (const float*)d_in[2];
  const float* vg_fc1_w   = (const float*)d_in[3];
  const float* vg_fc1_b   = (const float*)d_in[4];
  const float* vg_fc2_w   = (const float*)d_in[5];
  const float* vg_fc2_b   = (const float*)d_in[6];
  const float* vg_ln_g    = (const float*)d_in[7];
  const float* vg_ln_b    = (const float*)d_in[8];
  const float* sel_fc1_w  = (const float*)d_in[9];
  const float* sel_fc1_b  = (const float*)d_in[10];
  const float* sel_fc2_w  = (const float*)d_in[11];
  const float* sel_fc2_b  = (const float*)d_in[12];
  const float* sel_skip_w = (const float*)d_in[13];
  const float* sel_skip_b = (const float*)d_in[14];
  const float* sel_ln_g   = (const float*)d_in[15];
  const float* sel_ln_b   = (const float*)d_in[16];
  const float* lstm_wih   = (const float*)d_in[17];
  const float* lstm_whh   = (const float*)d_in[18];
  const float* lstm_bih   = (const float*)d_in[19];
  const float* lstm_bhh   = (const float*)d_in[20];
  const float* pl_fc1_w   = (const float*)d_in[21];
  const float* pl_fc1_b   = (const float*)d_in[22];
  const float* pl_fc2_w   = (const float*)d_in[23];
  const float* pl_fc2_b   = (const float*)d_in[24];
  const float* pl_ln_g    = (const float*)d_in[25];
  const float* pl_ln_b    = (const float*)d_in[26];
  const float* attn_in_w  = (const float*)d_in[27];
  const float* attn_in_b  = (const float*)d_in[28];
  const float* attn_out_w = (const float*)d_in[29];
  const float* attn_out_b = (const float*)d_in[30];
  const float* attn_ln_g  = (const float*)d_in[31];
  const float* attn_ln_b  = (const float*)d_in[32];
  const float* pa_fc1_w   = (const float*)d_in[33];
  const float* pa_fc1_b   = (const float*)d_in[34];
  const float* pa_fc2_w   = (const float*)d_in[35];
  const float* pa_fc2_b   = (const float*)d_in[36];
  const float* pa_ln_g    = (const float*)d_in[37];
  const float* pa_ln_b    = (const float*)d_in[38];
  const float* fg_fc1_w   = (const float*)d_in[39];
  const float* fg_fc1_b   = (const float*)d_in[40];
  const float* fg_fc2_w   = (const float*)d_in[41];
  const float* fg_fc2_b   = (const float*)d_in[42];
  const float* fg_ln_g    = (const float*)d_in[43];
  const float* fg_ln_b    = (const float*)d_in[44];
  (void)in_sizes; (void)n_in; (void)out_size; (void)ws_size;

  float* out     = (float*)d_out;
  float* out_wts = out + BB * DD;

  // ---- workspace layout ----
  char* p = (char*)d_ws;
  ushort* wt_sel_fc1  = (ushort*)p;                 p += 1048576 * 2;
  ushort* wt_sel_skip = (ushort*)p;                 p += 65536 * 2;
  ushort* wt_sel_fc2  = (ushort*)p;                 p += 8192 * 2;
  ushort* wt_var_fc1  = (ushort*)p;                 p += 1048576 * 2;
  ushort* wt_var_fc2  = (ushort*)p;                 p += 2097152 * 2;
  ushort* wt_wih      = (ushort*)p;                 p += 524288 * 2;
  unsigned char* wt_whh_pk8 = (unsigned char*)p;    p += 524288;
  ushort* wt_pl_fc1   = (ushort*)p;                 p += 65536 * 2;
  ushort* wt_pl_fc2   = (ushort*)p;                 p += 131072 * 2;
  ushort* wt_attn     = (ushort*)p;                 p += 196608 * 2;
  ushort* selH        = (ushort*)p;                 p += (size_t)BT * 256 * 2;
  float*  selSkip     = (float*)p;                  p += (size_t)BT * 16 * 4;
  float*  selG        = (float*)p;                  p += (size_t)BT * 32 * 4;
  float*  vsn         = (float*)p;                  p += (size_t)BT * 256 * 4;
  float*  hseq1       = (float*)p;                  p += (size_t)BT * 256 * 4;
  float*  hseq2       = (float*)p;                  p += (size_t)BT * 256 * 4;
  float*  cbias       = (float*)p;                  p += 4096 * 4;
  float*  attnO       = (float*)p;                  p += 8192 * 4;
  float*  attnLN      = (float*)p;                  p += 8192 * 4;
  char*   R           = p;
  ushort* bufA16 = (ushort*)R;
  ushort* bufG16 = (ushort*)(R + (((size_t)32) << 20));
  float*  xi     = (float*)R;
  float*  plA    = (float*)R;
  ushort* plH    = (ushort*)(R + (((size_t)16) << 20));
  ushort* plG    = (ushort*)(R + (((size_t)24) << 20));
  float*  lstmF  = (float*)(R + (((size_t)48) << 20));
  float*  qkv    = (float*)R;

  dim3 blk(256);

  // ---- weight prep ----
  wtT_k<<<dim3(8, 128, 1),  blk, 0, stream>>>(sel_fc1_w,  wt_sel_fc1,  4096, 256, 0, 0);
  wtT_k<<<dim3(1, 128, 1),  blk, 0, stream>>>(sel_skip_w, wt_sel_skip, 4096, 16,  0, 0);
  wtT_k<<<dim3(1, 8, 1),    blk, 0, stream>>>(sel_fc2_w,  wt_sel_fc2,  256,  32,  0, 0);
  wtT_k<<<dim3(8, 8, 16),   blk, 0, stream>>>(vg_fc1_w,   wt_var_fc1,  256,  256, 65536, 65536);
  wtT_k<<<dim3(16, 8, 16),  blk, 0, stream>>>(vg_fc2_w,   wt_var_fc2,  256,  512, 131072, 131072);
  wtT_k<<<dim3(8, 8, 1),    blk, 0, stream>>>(pl_fc1_w,   wt_pl_fc1,   256,  256, 0, 0);
  wtT_k<<<dim3(16, 8, 1),   blk, 0, stream>>>(pl_fc2_w,   wt_pl_fc2,   256,  512, 0, 0);
  cvt_k<<<2048, blk, 0, stream>>>(lstm_wih,  wt_wih, 524288);
  whh_pack8_k<<<64, blk, 0, stream>>>(lstm_whh, wt_whh_pk8);
  cvt_k<<<768,  blk, 0, stream>>>(attn_in_w, wt_attn, 196608);
  add2_k<<<8, blk, 0, stream>>>(lstm_bih, lstm_bhh, cbias, 4096);

  // ---- selection GRN -> softmax weights ----
  mgemm_k<2,1,1><<<dim3(2, 128, 1), blk, 0, stream>>>(x, 16, 0, wt_sel_fc1, 0, sel_fc1_b, 0,
      selH, 256, 0, 4096, 256, emb_w, emb_b, 0);
  mgemm_k<2,0,0><<<dim3(1, 128, 1), blk, 0, stream>>>(x, 16, 0, wt_sel_skip, 0, sel_skip_b, 0,
      selSkip, 16, 0, 4096, 16, emb_w, emb_b, 0);
  mgemm_k<1,0,0><<<dim3(1, 128, 1), blk, 0, stream>>>(selH, 256, 0, wt_sel_fc2, 0, sel_fc2_b, 0,
      selG, 32, 0, 256, 32, nullptr, nullptr, 0);
  sel_finish_k<<<64, blk, 0, stream>>>(selG, selSkip, sel_ln_g, sel_ln_b, out_wts, BT);

  // ---- per-variable GRNs (groups of 4) + weighted sum into vsn ----
  for (int g = 0; g < 4; g++) {
    mgemm_k<2,1,1><<<dim3(2, 128, 4), blk, 0, stream>>>(x, 16, 0,
        wt_var_fc1 + (size_t)g * 4 * 65536, 65536, vg_fc1_b + g * 1024, 256,
        bufA16, 256, (long)BT * 256, 256, 256, emb_w + g * 1024, emb_b + g * 1024, g * 4);
    mgemm_k<1,0,1><<<dim3(4, 128, 4), blk, 0, stream>>>(bufA16, 256, (long)BT * 256,
        wt_var_fc2 + (size_t)g * 4 * 131072, 131072, vg_fc2_b + g * 2048, 512,
        bufG16, 512, (long)BT * 512, 256, 512, nullptr, nullptr, 0);
    var_epi4_k<<<BT, blk, 0, stream>>>(bufG16, x, g * 4, emb_w + g * 1024, emb_b + g * 1024,
        vg_ln_g + g * 1024, vg_ln_b + g * 1024, out_wts, vsn, g == 0 ? 1 : 0);
  }

  // ---- LSTM (2 layers) ----
  mgemm_k<0,0,0><<<dim3(8, 128, 1), blk, 0, stream>>>(vsn, 256, 0, wt_wih, 0, cbias, 0,
      xi, 1024, 0, 256, 1024, nullptr, nullptr, 0);
  lstm_recur_k<<<16, 512, 0, stream>>>(xi, wt_whh_pk8, hseq1, TT);
  mgemm_k<0,0,0><<<dim3(8, 128, 1), blk, 0, stream>>>(hseq1, 256, 0, wt_wih + 1024 * 256, 0,
      cbias + 1024, 0, xi, 1024, 0, 256, 1024, nullptr, nullptr, 0);
  lstm_recur_k<<<16, 512, 0, stream>>>(xi, wt_whh_pk8 + 262144, hseq2, TT);

  // ---- post-LSTM gated residual (pl GRN) ----
  add2_k<<<BT, blk, 0, stream>>>(hseq2, vsn, plA, BT * 256);
  mgemm_k<0,1,1><<<dim3(2, 128, 1), blk, 0, stream>>>(plA, 256, 0, wt_pl_fc1, 0, pl_fc1_b, 0,
      plH, 256, 0, 256, 256, nullptr, nullptr, 0);
  mgemm_k<1,0,1><<<dim3(4, 128, 1), blk, 0, stream>>>(plH, 256, 0, wt_pl_fc2, 0, pl_fc2_b, 0,
      plG, 512, 0, 256, 512, nullptr, nullptr, 0);
  grn_epi_k<<<BT, blk, 0, stream>>>(plG, plA, pl_ln_g, pl_ln_b, lstmF);

  // ---- attention (decode at t=T-1 only) ----
  mgemm_k<0,0,0><<<dim3(6, 128, 1), blk, 0, stream>>>(lstmF, 256, 0, wt_attn, 0, attn_in_b, 0,
      qkv, 768, 0, 256, 768, nullptr, nullptr, 0);
  attn_decode_k<<<BB * 4, blk, 0, stream>>>(qkv, attnO, TT);
  attn_proj_ln_k<<<BB, blk, 0, stream>>>(attnO, attn_out_w, attn_out_b, lstmF,
                                         attn_ln_g, attn_ln_b, attnLN, TT);

  // ---- pa GRN + fg GRN (t=T-1 only) -> first output slice ----
  final_grns_k<<<BB, blk, 0, stream>>>(attnLN,
      pa_fc1_w, pa_fc1_b, pa_fc2_w, pa_fc2_b, pa_ln_g, pa_ln_b,
      fg_fc1_w, fg_fc1_b, fg_fc2_w, fg_fc2_b, fg_ln_g, fg_ln_b,
      out);
}

// Round 8
// 2468.666 us; speedup vs baseline: 13.8292x; 1.1937x over previous
//
#include <hip/hip_runtime.h>
#include <hip/hip_bf16.h>
#include <hip/hip_fp8.h>
#include <math.h>

// TFT: B=32, T=512, V=16, D=256, H=4, L=2.  BT = 16384.
// Round 8: LSTM recurrence latency surgery (structure from R7 kept):
//  - 32 blocks (1 batch each) x 512 threads; K=128 scaled fp8 MFMA, weights in regs
//  - hout buffered in registers, flushed every 8 steps (amortize vmcnt store drain)
//  - xi prefetched direct to active-lane registers (no xb LDS staging)
//  - h-state fp8 write via hardware v_cvt_pk_fp8_f32 (fallback: __hip_fp8_e4m3)
// GEMMs: bf16 MFMA 128x128 (unchanged). Attention decode-only at t=T-1.

#define BT 16384
#define TT 512
#define BB 32
#define VV 16
#define DD 256

typedef unsigned short ushort;
typedef unsigned int uint;
typedef unsigned long ulong_;
typedef __attribute__((ext_vector_type(8))) short short8;
typedef __attribute__((ext_vector_type(8))) unsigned short ushort8v;
typedef __attribute__((ext_vector_type(4))) float floatx4;
typedef __attribute__((ext_vector_type(8))) int int8v;

#if __has_builtin(__builtin_amdgcn_cvt_pk_fp8_f32)
#define HW_FP8_CVT 1
#endif

__device__ __forceinline__ float sigmoidf_(float x) { return 1.f / (1.f + expf(-x)); }
__device__ __forceinline__ float eluf_(float x)     { return x > 0.f ? x : expm1f(x); }
__device__ __forceinline__ float fsig(float x) {
  return __builtin_amdgcn_rcpf(1.f + __expf(-x));
}
__device__ __forceinline__ float ftanh(float x) {
  float xc = fminf(fmaxf(x, -44.f), 44.f);
  float e = __expf(-2.f * xc);
  return (1.f - e) * __builtin_amdgcn_rcpf(1.f + e);
}
__device__ __forceinline__ ushort f2bf(float f) {
  unsigned int u = __float_as_uint(f);
  unsigned int r = u + 0x7fffu + ((u >> 16) & 1u);
  return (ushort)(r >> 16);
}
__device__ __forceinline__ float bf2f(ushort b) { return __uint_as_float(((unsigned int)b) << 16); }

__device__ __forceinline__ float bsum256(float v, float* red4) {
  #pragma unroll
  for (int m = 32; m > 0; m >>= 1) v += __shfl_xor(v, m, 64);
  int w = threadIdx.x >> 6;
  if ((threadIdx.x & 63) == 0) red4[w] = v;
  __syncthreads();
  float r = red4[0] + red4[1] + red4[2] + red4[3];
  __syncthreads();
  return r;
}

__device__ __forceinline__ float block_sum256(float v, float* red) {
  int j = threadIdx.x;
  red[j] = v; __syncthreads();
  #pragma unroll
  for (int st = 128; st > 0; st >>= 1) {
    if (j < st) red[j] += red[j + st];
    __syncthreads();
  }
  float r = red[0];
  __syncthreads();
  return r;
}

// ---------------- weight prep ----------------
__global__ void wtT_k(const float* __restrict__ src, ushort* __restrict__ dst,
                      int K, int N, long sStride, long dStride) {
  int b = blockIdx.z;
  src += (size_t)b * sStride; dst += (size_t)b * dStride;
  __shared__ float t[32][33];
  int k0 = blockIdx.y * 32, n0 = blockIdx.x * 32;
  int tx = threadIdx.x & 31, ty = threadIdx.x >> 5;
  #pragma unroll
  for (int i = 0; i < 32; i += 8) {
    int k = k0 + ty + i, n = n0 + tx;
    t[ty + i][tx] = (k < K && n < N) ? src[(size_t)k * N + n] : 0.f;
  }
  __syncthreads();
  #pragma unroll
  for (int i = 0; i < 32; i += 8) {
    int n = n0 + ty + i, k = k0 + tx;
    if (n < N && k < K) dst[(size_t)n * K + k] = f2bf(t[tx][ty + i]);
  }
}

__global__ void cvt_k(const float* __restrict__ src, ushort* __restrict__ dst, int n) {
  int i = blockIdx.x * 256 + threadIdx.x;
  if (i < n) dst[i] = f2bf(src[i]);
}

// pack whh fp32 [2][1024][256] -> fp8 e4m3 (x64) in K=128 B-frag order.
__global__ void whh_pack8_k(const float* __restrict__ whh, unsigned char* __restrict__ dst) {
  int gid = blockIdx.x * 256 + threadIdx.x;   // 16384 total
  int layer = gid >> 13;
  int rem = gid & 8191;
  int lane = rem & 63;
  int f = (rem >> 6) & 15;
  int wave = rem >> 10;
  int kt2 = f & 1, ts = (f >> 1) & 1, g = f >> 2;
  int n = g * 256 + wave * 32 + ts * 16 + (lane & 15);
  int k0 = kt2 * 128 + (lane >> 4) * 32;
  const float* src = whh + (size_t)layer * 262144 + (size_t)n * 256 + k0;
  unsigned char* d = dst + (size_t)gid * 32;
  #pragma unroll
  for (int b = 0; b < 32; b++) {
    __hip_fp8_e4m3 q(src[b] * 64.f);
    d[b] = q.__x;
  }
}

// ---------------- bf16 MFMA GEMM (unchanged) ----------------
template<int ADT, int ACT, int CDT>
__global__ __launch_bounds__(256) void mgemm_k(
    const void* __restrict__ Aall, int lda, long aStride,
    const ushort* __restrict__ Ball, long bStride,
    const float* __restrict__ biasAll, long biasStride,
    void* __restrict__ Call, int ldc, long cStride,
    int K, int Nvalid,
    const float* __restrict__ embw, const float* __restrict__ embb, int xbase) {
  int z = blockIdx.z;
  const ushort* B = Ball + (size_t)z * bStride;
  const float* bias = biasAll ? biasAll + (size_t)z * biasStride : nullptr;
  int m0 = blockIdx.y * 128, n0 = blockIdx.x * 128;
  __shared__ ushort As[128][40];
  __shared__ ushort Bs[128][40];
  int tid = threadIdx.x;
  int r = tid >> 1, half = tid & 1;
  int wave = tid >> 6, lane = tid & 63;
  int wm = (wave >> 1) * 64, wn = (wave & 1) * 64;
  int lm = lane & 15, lq = lane >> 4;
  floatx4 acc[4][4];
  #pragma unroll
  for (int i = 0; i < 4; i++)
    #pragma unroll
    for (int j = 0; j < 4; j++) acc[i][j] = (floatx4)0.f;

  for (int k0 = 0; k0 < K; k0 += 32) {
    int kk = k0 + half * 16;
    {
      int gm = m0 + r;
      ushort tmp[16];
      if (ADT == 0) {
        const float* Af = (const float*)Aall + (size_t)z * aStride + (size_t)gm * lda + kk;
        #pragma unroll
        for (int q = 0; q < 4; q++) {
          float4 f = ((const float4*)Af)[q];
          tmp[q * 4 + 0] = f2bf(f.x); tmp[q * 4 + 1] = f2bf(f.y);
          tmp[q * 4 + 2] = f2bf(f.z); tmp[q * 4 + 3] = f2bf(f.w);
        }
      } else if (ADT == 1) {
        const ushort* Ab = (const ushort*)Aall + (size_t)z * aStride + (size_t)gm * lda + kk;
        *(ushort8v*)&tmp[0] = *(const ushort8v*)(Ab);
        *(ushort8v*)&tmp[8] = *(const ushort8v*)(Ab + 8);
      } else {
        const float* xp = (const float*)Aall;
        float xv = xp[(size_t)gm * lda + xbase + z + (kk >> 8)];
        const float4* ew = (const float4*)(embw + (size_t)z * 256 + kk);
        const float4* eb = (const float4*)(embb + (size_t)z * 256 + kk);
        #pragma unroll
        for (int q = 0; q < 4; q++) {
          float4 w4 = ew[q], b4 = eb[q];
          tmp[q * 4 + 0] = f2bf(xv * w4.x + b4.x); tmp[q * 4 + 1] = f2bf(xv * w4.y + b4.y);
          tmp[q * 4 + 2] = f2bf(xv * w4.z + b4.z); tmp[q * 4 + 3] = f2bf(xv * w4.w + b4.w);
        }
      }
      *(ushort8v*)&As[r][half * 16]     = *(ushort8v*)&tmp[0];
      *(ushort8v*)&As[r][half * 16 + 8] = *(ushort8v*)&tmp[8];
    }
    {
      int gn = n0 + r;
      ushort tmp[16];
      if (gn < Nvalid) {
        const ushort* Bp = B + (size_t)gn * K + kk;
        *(ushort8v*)&tmp[0] = *(const ushort8v*)(Bp);
        *(ushort8v*)&tmp[8] = *(const ushort8v*)(Bp + 8);
      } else {
        #pragma unroll
        for (int q = 0; q < 16; q++) tmp[q] = 0;
      }
      *(ushort8v*)&Bs[r][half * 16]     = *(ushort8v*)&tmp[0];
      *(ushort8v*)&Bs[r][half * 16 + 8] = *(ushort8v*)&tmp[8];
    }
    __syncthreads();
    short8 fa[4], fb[4];
    #pragma unroll
    for (int i = 0; i < 4; i++) fa[i] = *(const short8*)&As[wm + i * 16 + lm][lq * 8];
    #pragma unroll
    for (int j = 0; j < 4; j++) fb[j] = *(const short8*)&Bs[wn + j * 16 + lm][lq * 8];
    #pragma unroll
    for (int i = 0; i < 4; i++)
      #pragma unroll
      for (int j = 0; j < 4; j++)
        acc[i][j] = __builtin_amdgcn_mfma_f32_16x16x32_bf16(fa[i], fb[j], acc[i][j], 0, 0, 0);
    __syncthreads();
  }
  #pragma unroll
  for (int j = 0; j < 4; j++) {
    int gn = n0 + wn + j * 16 + lm;
    if (gn >= Nvalid) continue;
    float bv = bias ? bias[gn] : 0.f;
    #pragma unroll
    for (int i = 0; i < 4; i++) {
      #pragma unroll
      for (int rg = 0; rg < 4; rg++) {
        int gm = m0 + wm + i * 16 + lq * 4 + rg;
        float v = acc[i][j][rg] + bv;
        if (ACT == 1) v = eluf_(v);
        if (CDT == 0) ((float*)Call + (size_t)z * cStride)[(size_t)gm * ldc + gn] = v;
        else ((ushort*)Call + (size_t)z * cStride)[(size_t)gm * ldc + gn] = f2bf(v);
      }
    }
  }
}

// ---------------- selection GRN finish ----------------
__global__ void sel_finish_k(const float* __restrict__ selG, const float* __restrict__ selSkip,
                             const float* __restrict__ lng, const float* __restrict__ lnb,
                             float* __restrict__ wout, int M) {
  int m = blockIdx.x * 256 + threadIdx.x;
  if (m >= M) return;
  float s[16];
  float mean = 0.f;
  #pragma unroll
  for (int i = 0; i < 16; i++) {
    float h1 = selG[m * 32 + i], h2 = selG[m * 32 + 16 + i];
    float val = h1 * sigmoidf_(h2) + selSkip[m * 16 + i];
    s[i] = val; mean += val;
  }
  mean *= (1.f / 16.f);
  float var = 0.f;
  #pragma unroll
  for (int i = 0; i < 16; i++) { float d = s[i] - mean; var += d * d; }
  var *= (1.f / 16.f);
  float inv = rsqrtf(var + 1e-5f);
  float mx = -1e30f;
  #pragma unroll
  for (int i = 0; i < 16; i++) { s[i] = (s[i] - mean) * inv * lng[i] + lnb[i]; mx = fmaxf(mx, s[i]); }
  float sum = 0.f;
  #pragma unroll
  for (int i = 0; i < 16; i++) { s[i] = expf(s[i] - mx); sum += s[i]; }
  float isum = 1.f / sum;
  #pragma unroll
  for (int i = 0; i < 16; i++) wout[m * 16 + i] = s[i] * isum;
}

// ---------------- var-GRN epilogue, 4 variables per launch ----------------
__global__ __launch_bounds__(256) void var_epi4_k(
    const ushort* __restrict__ G16,
    const float* __restrict__ x, int vbase,
    const float* __restrict__ embw, const float* __restrict__ embb,
    const float* __restrict__ lng, const float* __restrict__ lnb,
    const float* __restrict__ wts, float* __restrict__ vsn, int first) {
  int m = blockIdx.x, j = threadIdx.x;
  __shared__ float red4[4];
  float accv = 0.f;
  #pragma unroll
  for (int z = 0; z < 4; z++) {
    int v = vbase + z;
    const ushort* Gp = G16 + ((size_t)z * BT + m) * 512;
    float g1 = bf2f(Gp[j]), g2 = bf2f(Gp[256 + j]);
    float e = x[m * VV + v] * embw[z * 256 + j] + embb[z * 256 + j];
    float s = g1 * sigmoidf_(g2) + e;
    float mean = bsum256(s, red4) * (1.f / 256.f);
    float d = s - mean;
    float var = bsum256(d * d, red4) * (1.f / 256.f);
    float o = d * rsqrtf(var + 1e-5f) * lng[z * 256 + j] + lnb[z * 256 + j];
    accv += wts[m * VV + v] * o;
  }
  size_t oi = (size_t)m * 256 + j;
  if (first) vsn[oi] = accv; else vsn[oi] += accv;
}

// ---------------- generic GRN epilogue ----------------
__global__ __launch_bounds__(256) void grn_epi_k(
    const ushort* __restrict__ G, const float* __restrict__ skip,
    const float* __restrict__ lng, const float* __restrict__ lnb,
    float* __restrict__ out) {
  int m = blockIdx.x, j = threadIdx.x;
  __shared__ float red4[4];
  float g1 = bf2f(G[(size_t)m * 512 + j]), g2 = bf2f(G[(size_t)m * 512 + 256 + j]);
  float s = g1 * sigmoidf_(g2) + skip[(size_t)m * 256 + j];
  float mean = bsum256(s, red4) * (1.f / 256.f);
  float d = s - mean;
  float var = bsum256(d * d, red4) * (1.f / 256.f);
  out[(size_t)m * 256 + j] = d * rsqrtf(var + 1e-5f) * lng[j] + lnb[j];
}

// ---------------- elementwise ----------------
__global__ void add2_k(const float* __restrict__ a, const float* __restrict__ b,
                       float* __restrict__ c, int n) {
  int i = blockIdx.x * 256 + threadIdx.x;
  if (i < n) c[i] = a[i] + b[i];
}

// ---------------- LSTM recurrence: K=128 scaled fp8 MFMA, latency-tuned ----------------
// 32 blocks (1 batch each) x 512 threads (8 waves). Wave w owns cols
// {g*256 + w*32 + ts*16 + lm}. Weights in regs (16 int8v). Gate phase on lanes
// lq==0 (2 units/lane). xi prefetched to active-lane regs; hout buffered 8 steps.
#define DESC (1.f / 1024.f)
#define H8S 272
__global__ __launch_bounds__(512, 2) void lstm_recur_k(
    const float* __restrict__ xi,            // [B,T,1024] = xW^T + bih + bhh
    const unsigned char* __restrict__ wpk,   // fp8 K128-frag-packed layer (262144 B)
    float* __restrict__ hout,                // [B,T,256]
    int T) {
  int bb = blockIdx.x;                        // one batch
  int tid = threadIdx.x;
  int wave = tid >> 6, lane = tid & 63;
  int lm = lane & 15, lq = lane >> 4;
  __shared__ __align__(16) unsigned char h8[2][16 * H8S];  // fp8 h rows; only row 0 used
  for (int i = tid; i < 2 * 16 * H8S / 4; i += 512) ((uint*)h8)[i] = 0;

  int8v wr[16];
  {
    const int8v* wp = (const int8v*)wpk;
    #pragma unroll
    for (int f = 0; f < 16; f++) wr[f] = wp[(wave * 16 + f) * 64 + lane];
  }
  bool act = (lq == 0);
  int jj = wave * 32 + lm;                   // ts adds +16
  const float* xg = xi + (size_t)bb * T * 1024;
  float xq[8], xn[8];
  if (act) {
    #pragma unroll
    for (int g = 0; g < 4; g++) {
      xq[2 * g]     = xg[g * 256 + jj];
      xq[2 * g + 1] = xg[g * 256 + jj + 16];
    }
  }
  float cst[2] = {0.f, 0.f};
  float hbf[2][8];
  int arow = lm * H8S + lq * 32;
  __syncthreads();

  for (int t = 0; t < T; t++) {
    int cur = t & 1, nxt = cur ^ 1;
    if (act && t + 1 < T) {
      const float* xp = xg + (size_t)(t + 1) * 1024;
      #pragma unroll
      for (int g = 0; g < 4; g++) {
        xn[2 * g]     = xp[g * 256 + jj];
        xn[2 * g + 1] = xp[g * 256 + jj + 16];
      }
    }
    int8v a[2];
    #pragma unroll
    for (int kt = 0; kt < 2; kt++)
      a[kt] = *(const int8v*)&h8[cur][arow + kt * 128];
    floatx4 acc[8];                 // f = g*2 + ts
    #pragma unroll
    for (int f = 0; f < 8; f++) acc[f] = (floatx4)0.f;
    #pragma unroll
    for (int kt = 0; kt < 2; kt++)
      #pragma unroll
      for (int f = 0; f < 8; f++)
        acc[f] = __builtin_amdgcn_mfma_scale_f32_16x16x128_f8f6f4(
            a[kt], wr[f * 2 + kt], acc[f], 0, 0, 0, 0x7f7f7f7f, 0, 0x7f7f7f7f);
    if (act) {
      int tb = t & 7;
      #pragma unroll
      for (int ts = 0; ts < 2; ts++) {
        float pi = acc[0 + ts][0] * DESC + xq[0 + ts];
        float pf = acc[2 + ts][0] * DESC + xq[2 + ts];
        float pg = acc[4 + ts][0] * DESC + xq[4 + ts];
        float po = acc[6 + ts][0] * DESC + xq[6 + ts];
        float c = fsig(pf) * cst[ts] + fsig(pi) * ftanh(pg);
        cst[ts] = c;
        hbf[ts][tb] = fsig(po) * ftanh(c);
      }
#ifdef HW_FP8_CVT
      int pk = __builtin_amdgcn_cvt_pk_fp8_f32(hbf[0][tb] * 16.f, hbf[1][tb] * 16.f, 0, false);
      h8[nxt][jj]      = (unsigned char)(pk & 0xff);
      h8[nxt][jj + 16] = (unsigned char)((pk >> 8) & 0xff);
#else
      __hip_fp8_e4m3 q0(hbf[0][tb] * 16.f), q1(hbf[1][tb] * 16.f);
      h8[nxt][jj]      = q0.__x;
      h8[nxt][jj + 16] = q1.__x;
#endif
      if (tb == 7) {
        #pragma unroll
        for (int q = 0; q < 8; q++) {
          size_t base = ((size_t)(bb * T + t - 7 + q)) * 256;
          hout[base + jj]      = hbf[0][q];
          hout[base + jj + 16] = hbf[1][q];
        }
      }
      #pragma unroll
      for (int g = 0; g < 8; g++) xq[g] = xn[g];
    }
    __syncthreads();
  }
}

// ---------------- attention, decode-style (only query t = T-1) ----------------
__global__ __launch_bounds__(256) void attn_decode_k(const float* __restrict__ qkv,
                                                     float* __restrict__ o, int T) {
  int bh = blockIdx.x; int b = bh >> 2, h = bh & 3;
  int tid = threadIdx.x;
  __shared__ float q[64];
  __shared__ float p[512];
  __shared__ float red[256];
  if (tid < 64) q[tid] = qkv[((size_t)(b * T + T - 1)) * 768 + h * 64 + tid];
  __syncthreads();
  for (int t = tid; t < 512; t += 256) {
    const float* kv = qkv + ((size_t)(b * T + t)) * 768 + 256 + h * 64;
    float s = 0.f;
    #pragma unroll 16
    for (int d = 0; d < 64; d++) s += q[d] * kv[d];
    p[t] = s * 0.125f;
  }
  __syncthreads();
  red[tid] = fmaxf(p[tid], p[tid + 256]); __syncthreads();
  for (int st = 128; st > 0; st >>= 1) { if (tid < st) red[tid] = fmaxf(red[tid], red[tid + st]); __syncthreads(); }
  float mx = red[0]; __syncthreads();
  float e0 = expf(p[tid] - mx), e1 = expf(p[tid + 256] - mx);
  red[tid] = e0 + e1; __syncthreads();
  for (int st = 128; st > 0; st >>= 1) { if (tid < st) red[tid] += red[tid + st]; __syncthreads(); }
  float inv = 1.f / red[0];
  __syncthreads();
  p[tid] = e0; p[tid + 256] = e1;
  __syncthreads();
  int d = tid & 63, grp = tid >> 6;
  float acc = 0.f;
  for (int t = grp * 128; t < grp * 128 + 128; t++)
    acc += p[t] * qkv[((size_t)(b * T + t)) * 768 + 512 + h * 64 + d];
  red[tid] = acc; __syncthreads();
  if (grp == 0)
    o[(b * 4 + h) * 64 + d] = (red[tid] + red[tid + 64] + red[tid + 128] + red[tid + 192]) * inv;
}

// ---------------- attn out-proj + residual + LN (only t=T-1) ----------------
__global__ __launch_bounds__(256) void attn_proj_ln_k(
    const float* __restrict__ attnO, const float* __restrict__ W, const float* __restrict__ bias,
    const float* __restrict__ lstmF, const float* __restrict__ lng, const float* __restrict__ lnb,
    float* __restrict__ out, int T) {
  int bb = blockIdx.x, j = threadIdx.x;
  __shared__ float a[256];
  __shared__ float red[256];
  a[j] = attnO[bb * 256 + j];
  __syncthreads();
  float acc = bias[j];
  const float* wr = W + (size_t)j * 256;
  #pragma unroll 8
  for (int k = 0; k < 256; k += 4) {
    float4 w4 = *(const float4*)(wr + k);
    acc += a[k] * w4.x + a[k + 1] * w4.y + a[k + 2] * w4.z + a[k + 3] * w4.w;
  }
  float s = acc + lstmF[((size_t)(bb * T + T - 1)) * 256 + j];
  float mean = block_sum256(s, red) * (1.f / 256.f);
  float d = s - mean;
  float var = block_sum256(d * d, red) * (1.f / 256.f);
  out[bb * 256 + j] = d * rsqrtf(var + 1e-5f) * lng[j] + lnb[j];
}

// ---------------- final two GRNs (pa then fg), only t=T-1 ----------------
__global__ __launch_bounds__(256) void final_grns_k(
    const float* __restrict__ ain,
    const float* __restrict__ paw1, const float* __restrict__ pab1,
    const float* __restrict__ paw2, const float* __restrict__ pab2,
    const float* __restrict__ palg, const float* __restrict__ palb,
    const float* __restrict__ fgw1, const float* __restrict__ fgb1,
    const float* __restrict__ fgw2, const float* __restrict__ fgb2,
    const float* __restrict__ fglg, const float* __restrict__ fglb,
    float* __restrict__ out) {
  int bb = blockIdx.x, j = threadIdx.x;
  __shared__ float a[256];
  __shared__ float hbuf[1024];
  __shared__ float red[256];
  a[j] = ain[bb * 256 + j];
  __syncthreads();
  float acc = pab1[j];
  for (int k = 0; k < 256; k++) acc += a[k] * paw1[k * 256 + j];
  hbuf[j] = eluf_(acc);
  __syncthreads();
  float g1 = pab2[j], g2 = pab2[256 + j];
  for (int k = 0; k < 256; k++) { float hv = hbuf[k]; g1 += hv * paw2[k * 512 + j]; g2 += hv * paw2[k * 512 + 256 + j]; }
  float s = g1 * sigmoidf_(g2) + a[j];
  float mean = block_sum256(s, red) * (1.f / 256.f);
  float d = s - mean;
  float var = block_sum256(d * d, red) * (1.f / 256.f);
  float af = d * rsqrtf(var + 1e-5f) * palg[j] + palb[j];
  __syncthreads();
  a[j] = af;
  __syncthreads();
  float hh[4];
  #pragma unroll
  for (int q = 0; q < 4; q++) {
    int jj = j + q * 256;
    float ac = fgb1[jj];
    for (int k = 0; k < 256; k++) ac += a[k] * fgw1[k * 1024 + jj];
    hh[q] = eluf_(ac);
  }
  __syncthreads();
  #pragma unroll
  for (int q = 0; q < 4; q++) hbuf[j + q * 256] = hh[q];
  __syncthreads();
  float G1 = fgb2[j], G2 = fgb2[256 + j];
  for (int k = 0; k < 1024; k++) { float hv = hbuf[k]; G1 += hv * fgw2[k * 512 + j]; G2 += hv * fgw2[k * 512 + 256 + j]; }
  float s2 = G1 * sigmoidf_(G2) + a[j];
  mean = block_sum256(s2, red) * (1.f / 256.f);
  d = s2 - mean;
  var = block_sum256(d * d, red) * (1.f / 256.f);
  out[bb * 256 + j] = d * rsqrtf(var + 1e-5f) * fglg[j] + fglb[j];
}

extern "C" void kernel_launch(void* const* d_in, const int* in_sizes, int n_in,
                              void* d_out, int out_size, void* d_ws, size_t ws_size,
                              hipStream_t stream) {
  const float* x          = (const float*)d_in[0];
  const float* emb_w      = (const float*)d_in[1];
  const float* emb_b      = (const float*)d_in[2];
  const float* vg_fc1_w   = (const float*)d_in[3];
  const float* vg_fc1_b   = (const float*)d_in[4];
  const float* vg_fc2_w   = (const float*)d_in[5];
  const float* vg_fc2_b   = (const float*)d_in[6];
  const float* vg_ln_g    = (const float*)d_in[7];
  const float* vg_ln_b    = (const float*)d_in[8];
  const float* sel_fc1_w  = (const float*)d_in[9];
  const float* sel_fc1_b  = (const float*)d_in[10];
  const float* sel_fc2_w  = (const float*)d_in[11];
  const float* sel_fc2_b  = (const float*)d_in[12];
  const float* sel_skip_w = (const float*)d_in[13];
  const float* sel_skip_b = (const float*)d_in[14];
  const float* sel_ln_g   = (const float*)d_in[15];
  const float* sel_ln_b   = (const float*)d_in[16];
  const float* lstm_wih   = (const float*)d_in[17];
  const float* lstm_whh   = (const float*)d_in[18];
  const float* lstm_bih   = (const float*)d_in[19];
  const float* lstm_bhh   = (const float*)d_in[20];
  const float* pl_fc1_w   = (const float*)d_in[21];
  const float* pl_fc1_b   = (const float*)d_in[22];
  const float* pl_fc2_w   = (const float*)d_in[23];
  const float* pl_fc2_b   = (const float*)d_in[24];
  const float* pl_ln_g    = (const float*)d_in[25];
  const float* pl_ln_b    = (const float*)d_in[26];
  const float* attn_in_w  = (const float*)d_in[27];
  const float* attn_in_b  = (const float*)d_in[28];
  const float* attn_out_w = (const float*)d_in[29];
  const float* attn_out_b = (const float*)d_in[30];
  const float* attn_ln_g  = (const float*)d_in[31];
  const float* attn_ln_b  = (const float*)d_in[32];
  const float* pa_fc1_w   = (const float*)d_in[33];
  const float* pa_fc1_b   = (const float*)d_in[34];
  const float* pa_fc2_w   = (const float*)d_in[35];
  const float* pa_fc2_b   = (const float*)d_in[36];
  const float* pa_ln_g    = (const float*)d_in[37];
  const float* pa_ln_b    = (const float*)d_in[38];
  const float* fg_fc1_w   = (const float*)d_in[39];
  const float* fg_fc1_b   = (const float*)d_in[40];
  const float* fg_fc2_w   = (const float*)d_in[41];
  const float* fg_fc2_b   = (const float*)d_in[42];
  const float* fg_ln_g    = (const float*)d_in[43];
  const float* fg_ln_b    = (const float*)d_in[44];
  (void)in_sizes; (void)n_in; (void)out_size; (void)ws_size;

  float* out     = (float*)d_out;
  float* out_wts = out + BB * DD;

  // ---- workspace layout ----
  char* p = (char*)d_ws;
  ushort* wt_sel_fc1  = (ushort*)p;                 p += 1048576 * 2;
  ushort* wt_sel_skip = (ushort*)p;                 p += 65536 * 2;
  ushort* wt_sel_fc2  = (ushort*)p;                 p += 8192 * 2;
  ushort* wt_var_fc1  = (ushort*)p;                 p += 1048576 * 2;
  ushort* wt_var_fc2  = (ushort*)p;                 p += 2097152 * 2;
  ushort* wt_wih      = (ushort*)p;                 p += 524288 * 2;
  unsigned char* wt_whh_pk8 = (unsigned char*)p;    p += 524288;
  ushort* wt_pl_fc1   = (ushort*)p;                 p += 65536 * 2;
  ushort* wt_pl_fc2   = (ushort*)p;                 p += 131072 * 2;
  ushort* wt_attn     = (ushort*)p;                 p += 196608 * 2;
  ushort* selH        = (ushort*)p;                 p += (size_t)BT * 256 * 2;
  float*  selSkip     = (float*)p;                  p += (size_t)BT * 16 * 4;
  float*  selG        = (float*)p;                  p += (size_t)BT * 32 * 4;
  float*  vsn         = (float*)p;                  p += (size_t)BT * 256 * 4;
  float*  hseq1       = (float*)p;                  p += (size_t)BT * 256 * 4;
  float*  hseq2       = (float*)p;                  p += (size_t)BT * 256 * 4;
  float*  cbias       = (float*)p;                  p += 4096 * 4;
  float*  attnO       = (float*)p;                  p += 8192 * 4;
  float*  attnLN      = (float*)p;                  p += 8192 * 4;
  char*   R           = p;
  ushort* bufA16 = (ushort*)R;
  ushort* bufG16 = (ushort*)(R + (((size_t)32) << 20));
  float*  xi     = (float*)R;
  float*  plA    = (float*)R;
  ushort* plH    = (ushort*)(R + (((size_t)16) << 20));
  ushort* plG    = (ushort*)(R + (((size_t)24) << 20));
  float*  lstmF  = (float*)(R + (((size_t)48) << 20));
  float*  qkv    = (float*)R;

  dim3 blk(256);

  // ---- weight prep ----
  wtT_k<<<dim3(8, 128, 1),  blk, 0, stream>>>(sel_fc1_w,  wt_sel_fc1,  4096, 256, 0, 0);
  wtT_k<<<dim3(1, 128, 1),  blk, 0, stream>>>(sel_skip_w, wt_sel_skip, 4096, 16,  0, 0);
  wtT_k<<<dim3(1, 8, 1),    blk, 0, stream>>>(sel_fc2_w,  wt_sel_fc2,  256,  32,  0, 0);
  wtT_k<<<dim3(8, 8, 16),   blk, 0, stream>>>(vg_fc1_w,   wt_var_fc1,  256,  256, 65536, 65536);
  wtT_k<<<dim3(16, 8, 16),  blk, 0, stream>>>(vg_fc2_w,   wt_var_fc2,  256,  512, 131072, 131072);
  wtT_k<<<dim3(8, 8, 1),    blk, 0, stream>>>(pl_fc1_w,   wt_pl_fc1,   256,  256, 0, 0);
  wtT_k<<<dim3(16, 8, 1),   blk, 0, stream>>>(pl_fc2_w,   wt_pl_fc2,   256,  512, 0, 0);
  cvt_k<<<2048, blk, 0, stream>>>(lstm_wih,  wt_wih, 524288);
  whh_pack8_k<<<64, blk, 0, stream>>>(lstm_whh, wt_whh_pk8);
  cvt_k<<<768,  blk, 0, stream>>>(attn_in_w, wt_attn, 196608);
  add2_k<<<8, blk, 0, stream>>>(lstm_bih, lstm_bhh, cbias, 4096);

  // ---- selection GRN -> softmax weights ----
  mgemm_k<2,1,1><<<dim3(2, 128, 1), blk, 0, stream>>>(x, 16, 0, wt_sel_fc1, 0, sel_fc1_b, 0,
      selH, 256, 0, 4096, 256, emb_w, emb_b, 0);
  mgemm_k<2,0,0><<<dim3(1, 128, 1), blk, 0, stream>>>(x, 16, 0, wt_sel_skip, 0, sel_skip_b, 0,
      selSkip, 16, 0, 4096, 16, emb_w, emb_b, 0);
  mgemm_k<1,0,0><<<dim3(1, 128, 1), blk, 0, stream>>>(selH, 256, 0, wt_sel_fc2, 0, sel_fc2_b, 0,
      selG, 32, 0, 256, 32, nullptr, nullptr, 0);
  sel_finish_k<<<64, blk, 0, stream>>>(selG, selSkip, sel_ln_g, sel_ln_b, out_wts, BT);

  // ---- per-variable GRNs (groups of 4) + weighted sum into vsn ----
  for (int g = 0; g < 4; g++) {
    mgemm_k<2,1,1><<<dim3(2, 128, 4), blk, 0, stream>>>(x, 16, 0,
        wt_var_fc1 + (size_t)g * 4 * 65536, 65536, vg_fc1_b + g * 1024, 256,
        bufA16, 256, (long)BT * 256, 256, 256, emb_w + g * 1024, emb_b + g * 1024, g * 4);
    mgemm_k<1,0,1><<<dim3(4, 128, 4), blk, 0, stream>>>(bufA16, 256, (long)BT * 256,
        wt_var_fc2 + (size_t)g * 4 * 131072, 131072, vg_fc2_b + g * 2048, 512,
        bufG16, 512, (long)BT * 512, 256, 512, nullptr, nullptr, 0);
    var_epi4_k<<<BT, blk, 0, stream>>>(bufG16, x, g * 4, emb_w + g * 1024, emb_b + g * 1024,
        vg_ln_g + g * 1024, vg_ln_b + g * 1024, out_wts, vsn, g == 0 ? 1 : 0);
  }

  // ---- LSTM (2 layers) ----
  mgemm_k<0,0,0><<<dim3(8, 128, 1), blk, 0, stream>>>(vsn, 256, 0, wt_wih, 0, cbias, 0,
      xi, 1024, 0, 256, 1024, nullptr, nullptr, 0);
  lstm_recur_k<<<32, 512, 0, stream>>>(xi, wt_whh_pk8, hseq1, TT);
  mgemm_k<0,0,0><<<dim3(8, 128, 1), blk, 0, stream>>>(hseq1, 256, 0, wt_wih + 1024 * 256, 0,
      cbias + 1024, 0, xi, 1024, 0, 256, 1024, nullptr, nullptr, 0);
  lstm_recur_k<<<32, 512, 0, stream>>>(xi, wt_whh_pk8 + 262144, hseq2, TT);

  // ---- post-LSTM gated residual (pl GRN) ----
  add2_k<<<BT, blk, 0, stream>>>(hseq2, vsn, plA, BT * 256);
  mgemm_k<0,1,1><<<dim3(2, 128, 1), blk, 0, stream>>>(plA, 256, 0, wt_pl_fc1, 0, pl_fc1_b, 0,
      plH, 256, 0, 256, 256, nullptr, nullptr, 0);
  mgemm_k<1,0,1><<<dim3(4, 128, 1), blk, 0, stream>>>(plH, 256, 0, wt_pl_fc2, 0, pl_fc2_b, 0,
      plG, 512, 0, 256, 512, nullptr, nullptr, 0);
  grn_epi_k<<<BT, blk, 0, stream>>>(plG, plA, pl_ln_g, pl_ln_b, lstmF);

  // ---- attention (decode at t=T-1 only) ----
  mgemm_k<0,0,0><<<dim3(6, 128, 1), blk, 0, stream>>>(lstmF, 256, 0, wt_attn, 0, attn_in_b, 0,
      qkv, 768, 0, 256, 768, nullptr, nullptr, 0);
  attn_decode_k<<<BB * 4, blk, 0, stream>>>(qkv, attnO, TT);
  attn_proj_ln_k<<<BB, blk, 0, stream>>>(attnO, attn_out_w, attn_out_b, lstmF,
                                         attn_ln_g, attn_ln_b, attnLN, TT);

  // ---- pa GRN + fg GRN (t=T-1 only) -> first output slice ----
  final_grns_k<<<BB, blk, 0, stream>>>(attnLN,
      pa_fc1_w, pa_fc1_b, pa_fc2_w, pa_fc2_b, pa_ln_g, pa_ln_b,
      fg_fc1_w, fg_fc1_b, fg_fc2_w, fg_fc2_b, fg_ln_g, fg_ln_b,
      out);
}